// Round 3
// baseline (15256.189 us; speedup 1.0000x reference)
//
#include <hip/hip_runtime.h>
#include <math.h>

#define B_ 64
#define T_ 12
#define N_ 307
#define I_ 3
#define R_ 64
#define D_ 10
#define M_ (B_*N_)      // 19648
#define TM_ (T_*M_)     // 235776

__device__ __forceinline__ float sigm(float x){ return 1.f/(1.f+__expf(-x)); }

// ---------------- stage A: x-embedding MLP + feature gram + fc1 MLP -> g1_in [T][M][10]
__global__ __launch_bounds__(256) void k_stageA(
    const float* __restrict__ x,
    const float* __restrict__ xw1, const float* __restrict__ xb1,
    const float* __restrict__ xw2, const float* __restrict__ xb2,
    const float* __restrict__ xw3, const float* __restrict__ xb3,
    const float* __restrict__ fw1, const float* __restrict__ fb1,
    const float* __restrict__ fw2, const float* __restrict__ fb2,
    const float* __restrict__ fw3, const float* __restrict__ fb3,
    float* __restrict__ g1)
{
  int idx = blockIdx.x*256 + threadIdx.x;      // t*M + m, exact grid
  int t = idx / M_;
  int m = idx - t*M_;
  int b = m / N_;
  int n = m - b*N_;
  const float* xp = x + (((size_t)b*T_ + t)*N_ + n)*I_;
  float xv[3] = {xp[0], xp[1], xp[2]};
  float e[3][10];
  #pragma unroll
  for (int i=0;i<3;++i){
    float h1[16];
    #pragma unroll
    for (int u=0;u<16;++u) h1[u] = sigm(xv[i]*xw1[u] + xb1[u]);
    float h2[2];
    #pragma unroll
    for (int v=0;v<2;++v){
      float a = xb2[v];
      #pragma unroll
      for (int u=0;u<16;++u) a += h1[u]*xw2[v*16+u];
      h2[v] = sigm(a);
    }
    #pragma unroll
    for (int d=0;d<10;++d) e[i][d] = xb3[d] + h2[0]*xw3[d*2] + h2[1]*xw3[d*2+1];
  }
  float in1[3];
  #pragma unroll
  for (int j=0;j<3;++j){
    float acc = 0.f;
    #pragma unroll
    for (int i=0;i<3;++i){
      float s = 0.f;
      #pragma unroll
      for (int d=0;d<10;++d) s += e[j][d]*e[i][d];
      s = fmaxf(s, 0.f);
      acc += s*xv[i];
    }
    in1[j] = xv[j] + acc;
  }
  float h1[16];
  #pragma unroll
  for (int u=0;u<16;++u)
    h1[u] = sigm(fb1[u] + in1[0]*fw1[u*3] + in1[1]*fw1[u*3+1] + in1[2]*fw1[u*3+2]);
  float h2[2];
  #pragma unroll
  for (int v=0;v<2;++v){
    float a = fb2[v];
    #pragma unroll
    for (int u=0;u<16;++u) a += h1[u]*fw2[v*16+u];
    h2[v] = sigm(a);
  }
  float* gp = g1 + (size_t)idx*10;
  #pragma unroll
  for (int d=0;d<10;++d) gp[d] = fb3[d] + h2[0]*fw3[d*2] + h2[1]*fw3[d*2+1];
}

// ---------------- per-node mixing matrices: Wn [N][c*64+r], bn [N][64]
__global__ __launch_bounds__(256) void k_wn(
    const float* __restrict__ emb2, const float* __restrict__ wpool,
    const float* __restrict__ bpool, float* __restrict__ Wn, float* __restrict__ bn)
{
  int n = blockIdx.x; int tid = threadIdx.x;
  __shared__ float e_s[10];
  if (tid < 10) e_s[tid] = emb2[n*10 + tid];
  __syncthreads();
  #pragma unroll
  for (int e=0;e<16;++e){
    int i = e*256 + tid;            // 0..4095
    float a = 0.f;
    #pragma unroll
    for (int d=0;d<10;++d) a += e_s[d]*wpool[(size_t)d*4096 + i];
    Wn[(size_t)n*4096 + i] = a;
  }
  if (tid < 64){
    float a = 0.f;
    #pragma unroll
    for (int d=0;d<10;++d) a += e_s[d]*bpool[d*64 + tid];
    bn[n*64 + tid] = a;
  }
}

// ---------------- GRU step, unit-split: grid (4 usplits, M/64 rowblocks)
// block: 64 rows x 16 units (x3 gates). thread (tr=tid&15 -> 4 rows, tc=tid>>4 -> 1 unit)
// A_s[k][row] (stride 68): k<64 = hprev^T, k>=64 = x^T (zero-padded to XK)
// W_s[wr][k] (stride KS): wr = g*16+tc maps to global W-row g*64 + usplit*16 + tc
template<int DIN, int KP, int KS, bool WSEQ, bool WFIN>
__global__ __launch_bounds__(256) void k_gruS(
    const float* __restrict__ xin, const float* __restrict__ hprev,
    float* __restrict__ hnext,
    const float* __restrict__ wih, const float* __restrict__ whh,
    const float* __restrict__ bih, const float* __restrict__ bhh,
    float* __restrict__ oseq, float* __restrict__ ofin, int t)
{
  __shared__ __align__(16) float W_s[48*KS];
  __shared__ __align__(16) float A_s[KP*68];
  const int tid = threadIdx.x;
  const int usplit = blockIdx.x;       // 0..3
  const int row0 = blockIdx.y * 64;
  const int ub = usplit * 16;

  // stage W rows for this unit-split (48 rows of [whh|wih], zero-padded K)
  for (int idx = tid; idx < 48*KP; idx += 256) {
    int wr = idx / KP, k = idx - wr*KP;
    int gw = (wr >> 4)*64 + ub + (wr & 15);
    float v = 0.f;
    if (k < 64) v = whh[gw*64 + k];
    else if (k - 64 < DIN) v = wih[gw*DIN + (k-64)];
    W_s[wr*KS + k] = v;
  }
  // stage hprev^T
  for (int idx = tid; idx < 64*64; idx += 256) {
    int row = idx >> 6, k = idx & 63;
    A_s[k*68 + row] = hprev[(size_t)(row0+row)*64 + k];
  }
  // stage x^T (zero-pad to XK)
  constexpr int XK = KP - 64;
  for (int idx = tid; idx < 64*XK; idx += 256) {
    int row = idx / XK, kk = idx - row*XK;
    float v = (kk < DIN) ? xin[(size_t)(row0+row)*DIN + kk] : 0.f;
    A_s[(64+kk)*68 + row] = v;
  }
  __syncthreads();

  const int tr = tid & 15, tc = tid >> 4;
  const int r4 = tr * 4;

  float acc_h[4][3];
  float acc_x[4][3];
  #pragma unroll
  for (int rr=0;rr<4;++rr)
    #pragma unroll
    for (int g=0;g<3;++g){ acc_h[rr][g]=0.f; acc_x[rr][g]=0.f; }

  for (int k=0; k<64; k+=4) {
    float4 a0 = *(const float4*)&A_s[(k+0)*68 + r4];
    float4 a1 = *(const float4*)&A_s[(k+1)*68 + r4];
    float4 a2 = *(const float4*)&A_s[(k+2)*68 + r4];
    float4 a3 = *(const float4*)&A_s[(k+3)*68 + r4];
    #pragma unroll
    for (int g=0;g<3;++g){
      float4 w = *(const float4*)&W_s[(g*16+tc)*KS + k];
      acc_h[0][g] += a0.x*w.x + a1.x*w.y + a2.x*w.z + a3.x*w.w;
      acc_h[1][g] += a0.y*w.x + a1.y*w.y + a2.y*w.z + a3.y*w.w;
      acc_h[2][g] += a0.z*w.x + a1.z*w.y + a2.z*w.z + a3.z*w.w;
      acc_h[3][g] += a0.w*w.x + a1.w*w.y + a2.w*w.z + a3.w*w.w;
    }
  }
  for (int k=64; k<KP; k+=4) {
    float4 a0 = *(const float4*)&A_s[(k+0)*68 + r4];
    float4 a1 = *(const float4*)&A_s[(k+1)*68 + r4];
    float4 a2 = *(const float4*)&A_s[(k+2)*68 + r4];
    float4 a3 = *(const float4*)&A_s[(k+3)*68 + r4];
    #pragma unroll
    for (int g=0;g<3;++g){
      float4 w = *(const float4*)&W_s[(g*16+tc)*KS + k];
      acc_x[0][g] += a0.x*w.x + a1.x*w.y + a2.x*w.z + a3.x*w.w;
      acc_x[1][g] += a0.y*w.x + a1.y*w.y + a2.y*w.z + a3.y*w.w;
      acc_x[2][g] += a0.z*w.x + a1.z*w.y + a2.z*w.z + a3.z*w.w;
      acc_x[3][g] += a0.w*w.x + a1.w*w.y + a2.w*w.z + a3.w*w.w;
    }
  }

  const int u = ub + tc;               // global unit 0..63
  const float bi_r = bih[u],     bh_r = bhh[u];
  const float bi_z = bih[64+u],  bh_z = bhh[64+u];
  const float bi_n = bih[128+u], bh_n = bhh[128+u];
  #pragma unroll
  for (int rr=0; rr<4; ++rr) {
    int row = r4 + rr; int grow = row0 + row;
    float rg = sigm(acc_x[rr][0] + bi_r + acc_h[rr][0] + bh_r);
    float zg = sigm(acc_x[rr][1] + bi_z + acc_h[rr][1] + bh_z);
    float ng = tanhf(acc_x[rr][2] + bi_n + rg*(acc_h[rr][2] + bh_n));
    float hp = A_s[u*68 + row];
    float o = (1.f - zg)*ng + zg*hp;
    hnext[(size_t)grow*64 + u] = o;
    if (WSEQ) oseq[(size_t)grow*64 + u] = o;
    if (WFIN) {
      int bb = grow / N_;
      int nn = grow - bb*N_;
      ofin[(((size_t)bb*T_ + t)*N_ + nn)*64 + u] = o;
    }
  }
}

// ---------------- stage C: fc2 MLP over out1 rows + nodevec = tanh(emb1*filt)
__global__ __launch_bounds__(256) void k_stageC(
    const float* __restrict__ out1, const float* __restrict__ emb1,
    const float* __restrict__ w1, const float* __restrict__ b1,
    const float* __restrict__ w2, const float* __restrict__ b2,
    const float* __restrict__ w3, const float* __restrict__ b3,
    float* __restrict__ ndv)
{
  int idx = blockIdx.x*256 + threadIdx.x;
  int m = idx % M_;
  int n = m % N_;
  float rv[64];
  const float4* r4 = (const float4*)(out1 + (size_t)idx*64);
  #pragma unroll
  for (int q=0;q<16;++q){ float4 v=r4[q]; rv[q*4]=v.x; rv[q*4+1]=v.y; rv[q*4+2]=v.z; rv[q*4+3]=v.w; }
  float h1[16];
  for (int u=0;u<16;++u){
    float a = b1[u];
    const float* wr = w1 + u*64;
    #pragma unroll
    for (int c=0;c<64;++c) a += rv[c]*wr[c];
    h1[u] = sigm(a);
  }
  float h2[2];
  #pragma unroll
  for (int v=0;v<2;++v){
    float a = b2[v];
    #pragma unroll
    for (int u=0;u<16;++u) a += h1[u]*w2[v*16+u];
    h2[v] = sigm(a);
  }
  #pragma unroll
  for (int d=0;d<10;++d){
    float f = b3[d] + h2[0]*w3[d*2] + h2[1]*w3[d*2+1];
    ndv[(size_t)idx*10 + d] = tanhf(emb1[n*10+d]*f);
  }
}

// ---------------- stage D: x_g = out1 + relu(V V^T) @ out1 per (t,b)
__global__ __launch_bounds__(256) void k_stageD(
    const float* __restrict__ ndv, const float* __restrict__ out1, float* __restrict__ xg)
{
  int tb = blockIdx.y;
  int tile = blockIdx.x;               // 0..4
  int tid = threadIdx.x;
  __shared__ __align__(16) float V_s[320*12];
  __shared__ __align__(16) float o_s[64*68];
  __shared__ __align__(16) float s_s[64*68];   // s_s[m][row-within-tile]

  for (int i = tid; i < 320*12; i += 256) {
    int n = i / 12, d = i - n*12;
    V_s[i] = (n < N_ && d < 10) ? ndv[((size_t)tb*N_ + n)*10 + d] : 0.f;
  }
  __syncthreads();

  const int sr  = tid & 63;            // s-phase: row within tile
  const int smg = tid >> 6;            // s-phase: m-group (16 m's)
  float vr[10];
  {
    const float* vp = &V_s[(tile*64 + sr)*12];
    #pragma unroll
    for (int d = 0; d < 10; ++d) vr[d] = vp[d];
  }
  const int rq = tid & 15, cq = tid >> 4;
  const int r4 = rq*4, c4 = cq*4;
  float acc[4][4];
  #pragma unroll
  for (int a=0;a<4;++a)
    #pragma unroll
    for (int b=0;b<4;++b) acc[a][b]=0.f;

  for (int mc = 0; mc < 320; mc += 64) {
    __syncthreads();
    for (int i = tid; i < 1024; i += 256) {
      int row = i >> 4, f4 = i & 15;
      int gm = mc + row;
      float4 v = make_float4(0.f,0.f,0.f,0.f);
      if (gm < N_) v = *(const float4*)&out1[((size_t)tb*N_ + gm)*64 + f4*4];
      *(float4*)&o_s[row*68 + f4*4] = v;
    }
    #pragma unroll
    for (int j = 0; j < 16; ++j) {
      int m = smg*16 + j;
      const float* vm = &V_s[(mc + m)*12];
      float s = vr[0]*vm[0] + vr[1]*vm[1] + vr[2]*vm[2] + vr[3]*vm[3] + vr[4]*vm[4]
              + vr[5]*vm[5] + vr[6]*vm[6] + vr[7]*vm[7] + vr[8]*vm[8] + vr[9]*vm[9];
      s_s[m*68 + sr] = fmaxf(s, 0.f);
    }
    __syncthreads();
    #pragma unroll 8
    for (int m = 0; m < 64; ++m) {
      float4 sv = *(const float4*)&s_s[m*68 + r4];
      float4 ov = *(const float4*)&o_s[m*68 + c4];
      acc[0][0] += sv.x*ov.x; acc[0][1] += sv.x*ov.y; acc[0][2] += sv.x*ov.z; acc[0][3] += sv.x*ov.w;
      acc[1][0] += sv.y*ov.x; acc[1][1] += sv.y*ov.y; acc[1][2] += sv.y*ov.z; acc[1][3] += sv.y*ov.w;
      acc[2][0] += sv.z*ov.x; acc[2][1] += sv.z*ov.y; acc[2][2] += sv.z*ov.z; acc[2][3] += sv.z*ov.w;
      acc[3][0] += sv.w*ov.x; acc[3][1] += sv.w*ov.y; acc[3][2] += sv.w*ov.z; acc[3][3] += sv.w*ov.w;
    }
  }

  #pragma unroll
  for (int rr = 0; rr < 4; ++rr) {
    int nrow = tile*64 + r4 + rr;
    if (nrow < N_) {
      size_t base = ((size_t)tb*N_ + nrow)*64 + c4;
      float4 o = *(const float4*)&out1[base];
      *(float4*)&xg[base] = make_float4(o.x+acc[rr][0], o.y+acc[rr][1],
                                        o.z+acc[rr][2], o.w+acc[rr][3]);
    }
  }
}

// ---------------- stage E: diff1 = x_g @ Wn + bn ; g2_in = [out1,diff1] @ diff_w^T + diff_b
// thread map (r = tid>>3, ug = tid&7): per-wave row reads are 8 distinct float4
// (full bank sweep) x 8-way broadcast -> conflict-free.
__global__ __launch_bounds__(256) void k_stageE(
    const float* xg_in, const float* __restrict__ out1,
    const float* __restrict__ Wn, const float* __restrict__ bn,
    const float* __restrict__ dw, const float* __restrict__ db,
    float* xg_out)
{
  int n = blockIdx.y;
  int tile = blockIdx.x;     // 24 tiles of 32 tb-rows
  int tid = threadIdx.x;
  int r = tid >> 3, ug = tid & 7;
  __shared__ __align__(16) float x_s[32*68];
  __shared__ __align__(16) float o_s[32*68];
  __shared__ __align__(16) float W_s[64*68];    // transposed: [r_out][c]
  __shared__ __align__(16) float dw_s[64*132];
  __shared__ __align__(16) float d1_s[32*68];
  for (int idx=tid; idx<32*64; idx+=256){
    int row=idx>>6, c=idx&63;
    size_t g = ((size_t)(tile*32+row)*N_ + n)*64 + c;
    x_s[row*68+c] = xg_in[g];
    o_s[row*68+c] = out1[g];
  }
  for (int idx=tid; idx<4096; idx+=256){
    int c=idx>>6, u=idx&63;
    W_s[u*68+c] = Wn[(size_t)n*4096 + c*64 + u];
  }
  for (int idx=tid; idx<64*128; idx+=256){
    int u=idx>>7, c=idx&127;
    dw_s[u*132+c] = dw[u*128+c];
  }
  __syncthreads();
  float d1[8];
  #pragma unroll
  for (int uu=0;uu<8;++uu) d1[uu] = bn[n*64 + ug + 8*uu];
  for (int c=0;c<64;c+=4){
    float4 xc = *(const float4*)&x_s[r*68+c];
    #pragma unroll
    for (int uu=0;uu<8;++uu){
      float4 w = *(const float4*)&W_s[(ug+8*uu)*68 + c];
      d1[uu] += xc.x*w.x + xc.y*w.y + xc.z*w.z + xc.w*w.w;
    }
  }
  #pragma unroll
  for (int uu=0;uu<8;++uu) d1_s[r*68 + ug + 8*uu] = d1[uu];
  __syncthreads();
  float g2[8];
  #pragma unroll
  for (int uu=0;uu<8;++uu) g2[uu] = db[ug + 8*uu];
  for (int c=0;c<64;c+=4){
    float4 oc = *(const float4*)&o_s[r*68+c];
    float4 dc = *(const float4*)&d1_s[r*68+c];
    #pragma unroll
    for (int uu=0;uu<8;++uu){
      int u = ug + 8*uu;
      float4 w0 = *(const float4*)&dw_s[u*132 + c];
      float4 w1 = *(const float4*)&dw_s[u*132 + 64 + c];
      g2[uu] += oc.x*w0.x + oc.y*w0.y + oc.z*w0.z + oc.w*w0.w
              + dc.x*w1.x + dc.y*w1.y + dc.z*w1.z + dc.w*w1.w;
    }
  }
  size_t base = ((size_t)(tile*32+r)*N_ + n)*64;
  #pragma unroll
  for (int uu=0;uu<8;++uu) xg_out[base + ug + 8*uu] = g2[uu];
}

extern "C" void kernel_launch(void* const* d_in, const int* in_sizes, int n_in,
                              void* d_out, int out_size, void* d_ws, size_t ws_size,
                              hipStream_t stream)
{
  (void)in_sizes; (void)n_in; (void)out_size;
  const float* x    = (const float*)d_in[0];
  const float* emb1 = (const float*)d_in[1];
  const float* emb2 = (const float*)d_in[2];
  const float* xw1  = (const float*)d_in[3];
  const float* xb1  = (const float*)d_in[4];
  const float* xw2  = (const float*)d_in[5];
  const float* xb2  = (const float*)d_in[6];
  const float* xw3  = (const float*)d_in[7];
  const float* xb3  = (const float*)d_in[8];
  const float* fw1  = (const float*)d_in[9];
  const float* fb1  = (const float*)d_in[10];
  const float* fw2  = (const float*)d_in[11];
  const float* fb2  = (const float*)d_in[12];
  const float* fw3  = (const float*)d_in[13];
  const float* fb3  = (const float*)d_in[14];
  const float* c2w1 = (const float*)d_in[15];
  const float* c2b1 = (const float*)d_in[16];
  const float* c2w2 = (const float*)d_in[17];
  const float* c2b2 = (const float*)d_in[18];
  const float* c2w3 = (const float*)d_in[19];
  const float* c2b3 = (const float*)d_in[20];
  const float* g1wih= (const float*)d_in[21];
  const float* g1whh= (const float*)d_in[22];
  const float* g1bih= (const float*)d_in[23];
  const float* g1bhh= (const float*)d_in[24];
  const float* g2wih= (const float*)d_in[25];
  const float* g2whh= (const float*)d_in[26];
  const float* g2bih= (const float*)d_in[27];
  const float* g2bhh= (const float*)d_in[28];
  const float* wpool= (const float*)d_in[29];
  const float* bpool= (const float*)d_in[30];
  const float* dww  = (const float*)d_in[31];
  const float* dwb  = (const float*)d_in[32];
  float* out = (float*)d_out;

  float* ws = (float*)d_ws;
  float* g1_in = ws;                          // 2,357,760
  float* out1  = g1_in + (size_t)TM_*10;      // 15,089,664
  float* ndv   = out1 + (size_t)TM_*64;       // 2,357,760
  float* xg    = ndv + (size_t)TM_*10;        // 15,089,664
  float* Wn    = xg + (size_t)TM_*64;         // 1,257,472
  float* bn    = Wn + (size_t)N_*4096;        // 19,648
  float* ha    = bn + (size_t)N_*64;          // 1,257,472
  float* hb    = ha + (size_t)M_*64;          // 1,257,472
  size_t need = ((size_t)(hb + (size_t)M_*64 - ws)) * 4;
  if (ws_size < need) return;

  k_stageA<<<TM_/256, 256, 0, stream>>>(x, xw1,xb1,xw2,xb2,xw3,xb3, fw1,fb1,fw2,fb2,fw3,fb3, g1_in);
  k_wn<<<N_, 256, 0, stream>>>(emb2, wpool, bpool, Wn, bn);

  hipMemsetAsync(ha, 0, (size_t)M_*64*sizeof(float), stream);
  {
    float* hc = ha; float* hn = hb;
    for (int t=0;t<T_;++t){
      k_gruS<10,76,80,true,false><<<dim3(4, M_/64), 256, 0, stream>>>(
          g1_in + (size_t)t*M_*10, hc, hn, g1wih, g1whh, g1bih, g1bhh,
          out1 + (size_t)t*M_*64, nullptr, t);
      float* tmp = hc; hc = hn; hn = tmp;
    }
  }

  k_stageC<<<TM_/256, 256, 0, stream>>>(out1, emb1, c2w1,c2b1,c2w2,c2b2,c2w3,c2b3, ndv);
  k_stageD<<<dim3(5, T_*B_), 256, 0, stream>>>(ndv, out1, xg);
  k_stageE<<<dim3((T_*B_)/32, N_), 256, 0, stream>>>(xg, out1, Wn, bn, dww, dwb, xg);

  hipMemsetAsync(ha, 0, (size_t)M_*64*sizeof(float), stream);
  {
    float* hc = ha; float* hn = hb;
    for (int t=0;t<T_;++t){
      k_gruS<64,128,132,false,true><<<dim3(4, M_/64), 256, 0, stream>>>(
          xg + (size_t)t*M_*64, hc, hn, g2wih, g2whh, g2bih, g2bhh,
          nullptr, out, t);
      float* tmp = hc; hc = hn; hn = tmp;
    }
  }
}

// Round 4
// 1290.848 us; speedup vs baseline: 11.8187x; 11.8187x over previous
//
#include <hip/hip_runtime.h>
#include <math.h>

#define B_ 64
#define T_ 12
#define N_ 307
#define I_ 3
#define R_ 64
#define D_ 10
#define M_ (B_*N_)      // 19648
#define TM_ (T_*M_)     // 235776

__device__ __forceinline__ float sigm(float x){ return 1.f/(1.f+__expf(-x)); }

// ---------------- stage A: x-embedding MLP + feature gram + fc1 MLP -> g1_in [T][M][10]
__global__ __launch_bounds__(256) void k_stageA(
    const float* __restrict__ x,
    const float* __restrict__ xw1, const float* __restrict__ xb1,
    const float* __restrict__ xw2, const float* __restrict__ xb2,
    const float* __restrict__ xw3, const float* __restrict__ xb3,
    const float* __restrict__ fw1, const float* __restrict__ fb1,
    const float* __restrict__ fw2, const float* __restrict__ fb2,
    const float* __restrict__ fw3, const float* __restrict__ fb3,
    float* __restrict__ g1)
{
  int idx = blockIdx.x*256 + threadIdx.x;      // t*M + m, exact grid
  int t = idx / M_;
  int m = idx - t*M_;
  int b = m / N_;
  int n = m - b*N_;
  const float* xp = x + (((size_t)b*T_ + t)*N_ + n)*I_;
  float xv[3] = {xp[0], xp[1], xp[2]};
  float e[3][10];
  #pragma unroll
  for (int i=0;i<3;++i){
    float h1[16];
    #pragma unroll
    for (int u=0;u<16;++u) h1[u] = sigm(xv[i]*xw1[u] + xb1[u]);
    float h2[2];
    #pragma unroll
    for (int v=0;v<2;++v){
      float a = xb2[v];
      #pragma unroll
      for (int u=0;u<16;++u) a += h1[u]*xw2[v*16+u];
      h2[v] = sigm(a);
    }
    #pragma unroll
    for (int d=0;d<10;++d) e[i][d] = xb3[d] + h2[0]*xw3[d*2] + h2[1]*xw3[d*2+1];
  }
  float in1[3];
  #pragma unroll
  for (int j=0;j<3;++j){
    float acc = 0.f;
    #pragma unroll
    for (int i=0;i<3;++i){
      float s = 0.f;
      #pragma unroll
      for (int d=0;d<10;++d) s += e[j][d]*e[i][d];
      s = fmaxf(s, 0.f);
      acc += s*xv[i];
    }
    in1[j] = xv[j] + acc;
  }
  float h1[16];
  #pragma unroll
  for (int u=0;u<16;++u)
    h1[u] = sigm(fb1[u] + in1[0]*fw1[u*3] + in1[1]*fw1[u*3+1] + in1[2]*fw1[u*3+2]);
  float h2[2];
  #pragma unroll
  for (int v=0;v<2;++v){
    float a = fb2[v];
    #pragma unroll
    for (int u=0;u<16;++u) a += h1[u]*fw2[v*16+u];
    h2[v] = sigm(a);
  }
  float* gp = g1 + (size_t)idx*10;
  #pragma unroll
  for (int d=0;d<10;++d) gp[d] = fb3[d] + h2[0]*fw3[d*2] + h2[1]*fw3[d*2+1];
}

// ---------------- per-node mixing matrices: Wn [N][c*64+r], bn [N][64]
__global__ __launch_bounds__(256) void k_wn(
    const float* __restrict__ emb2, const float* __restrict__ wpool,
    const float* __restrict__ bpool, float* __restrict__ Wn, float* __restrict__ bn)
{
  int n = blockIdx.x; int tid = threadIdx.x;
  __shared__ float e_s[10];
  if (tid < 10) e_s[tid] = emb2[n*10 + tid];
  __syncthreads();
  #pragma unroll
  for (int e=0;e<16;++e){
    int i = e*256 + tid;            // 0..4095
    float a = 0.f;
    #pragma unroll
    for (int d=0;d<10;++d) a += e_s[d]*wpool[(size_t)d*4096 + i];
    Wn[(size_t)n*4096 + i] = a;
  }
  if (tid < 64){
    float a = 0.f;
    #pragma unroll
    for (int d=0;d<10;++d) a += e_s[d]*bpool[d*64 + tid];
    bn[n*64 + tid] = a;
  }
}

// ---------------- persistent GRU scan: one block = 32 rows for ALL T steps.
// h lives in LDS A_s[k<64][row]; x_t staged per step into A_s[64+kk][row].
// Weights read from global (L2-resident, ~98KB reused by all 614 blocks).
// 128 threads: tr=tid&7 -> 4 rows, tc=tid>>3 -> 4 units (x3 gates).
// r/z gate accumulators merge x- and h-parts; n gate kept split (needs r*hn).
template<int DIN, bool WSEQ, bool WFIN>
__global__ __launch_bounds__(128, 3) void k_gruP(
    const float* __restrict__ xseq,   // [T][M][DIN]
    const float* __restrict__ wih,    // [192][DIN]
    const float* __restrict__ whh,    // [192][64]
    const float* __restrict__ bih, const float* __restrict__ bhh,
    float* __restrict__ oseq,         // [T][M][64]   (if WSEQ)
    float* __restrict__ ofin)         // [B][T][N][64] (if WFIN)
{
  constexpr int KP = 64 + ((DIN + 3) & ~3);
  __shared__ __align__(16) float A_s[KP*36];
  const int tid = threadIdx.x;
  const int row0 = blockIdx.x * 32;
  const int tr = tid & 7, tc = tid >> 3;
  const int r4 = tr*4, u0 = tc*4;

  // biases (merged for r,z)
  float brc[4], bzc[4], bxn[4], bhn[4];
  #pragma unroll
  for (int uu=0;uu<4;++uu){
    int u = u0+uu;
    brc[uu] = bih[u]       + bhh[u];
    bzc[uu] = bih[64+u]    + bhh[64+u];
    bxn[uu] = bih[128+u];
    bhn[uu] = bhh[128+u];
  }
  // per-row output bases (row fixed across t)
  size_t obase[4];
  #pragma unroll
  for (int rr=0;rr<4;++rr){
    int grow = row0 + r4 + rr;
    if (WFIN){
      int bb = grow / N_, nn = grow - bb*N_;
      obase[rr] = (((size_t)bb*T_)*N_ + nn)*64;
    } else {
      obase[rr] = (size_t)grow*64;
    }
  }

  // init h=0, stage x_0
  for (int i = tid; i < 64*36; i += 128) A_s[i] = 0.f;
  if (DIN == 64) {
    for (int idx = tid; idx < 32*64; idx += 128) {
      int row = idx >> 6, c = idx & 63;
      A_s[(64+c)*36 + row] = xseq[(size_t)(row0+row)*64 + c];
    }
  } else {
    for (int idx = tid; idx < 32*DIN; idx += 128) {
      int row = idx / DIN, kk = idx - row*DIN;
      A_s[(64+kk)*36 + row] = xseq[(size_t)(row0+row)*DIN + kk];
    }
  }
  __syncthreads();

  for (int t = 0; t < T_; ++t) {
    float arz[4][8], ahn[4][4], axn[4][4];
    #pragma unroll
    for (int rr=0;rr<4;++rr){
      #pragma unroll
      for (int q=0;q<8;++q) arz[rr][q]=0.f;
      #pragma unroll
      for (int q=0;q<4;++q){ ahn[rr][q]=0.f; axn[rr][q]=0.f; }
    }

    // ---- h part: k = 0..63, W = whh
    #pragma unroll 1
    for (int k=0; k<64; k+=4) {
      float4 a0 = *(const float4*)&A_s[(k+0)*36 + r4];
      float4 a1 = *(const float4*)&A_s[(k+1)*36 + r4];
      float4 a2 = *(const float4*)&A_s[(k+2)*36 + r4];
      float4 a3 = *(const float4*)&A_s[(k+3)*36 + r4];
      #pragma unroll
      for (int uu=0;uu<4;++uu){
        int u = u0+uu;
        float4 wr_ = *(const float4*)&whh[(size_t)u*64 + k];
        float4 wz_ = *(const float4*)&whh[(size_t)(64+u)*64 + k];
        float4 wn_ = *(const float4*)&whh[(size_t)(128+u)*64 + k];
        arz[0][uu]   += a0.x*wr_.x + a1.x*wr_.y + a2.x*wr_.z + a3.x*wr_.w;
        arz[1][uu]   += a0.y*wr_.x + a1.y*wr_.y + a2.y*wr_.z + a3.y*wr_.w;
        arz[2][uu]   += a0.z*wr_.x + a1.z*wr_.y + a2.z*wr_.z + a3.z*wr_.w;
        arz[3][uu]   += a0.w*wr_.x + a1.w*wr_.y + a2.w*wr_.z + a3.w*wr_.w;
        arz[0][4+uu] += a0.x*wz_.x + a1.x*wz_.y + a2.x*wz_.z + a3.x*wz_.w;
        arz[1][4+uu] += a0.y*wz_.x + a1.y*wz_.y + a2.y*wz_.z + a3.y*wz_.w;
        arz[2][4+uu] += a0.z*wz_.x + a1.z*wz_.y + a2.z*wz_.z + a3.z*wz_.w;
        arz[3][4+uu] += a0.w*wz_.x + a1.w*wz_.y + a2.w*wz_.z + a3.w*wz_.w;
        ahn[0][uu]   += a0.x*wn_.x + a1.x*wn_.y + a2.x*wn_.z + a3.x*wn_.w;
        ahn[1][uu]   += a0.y*wn_.x + a1.y*wn_.y + a2.y*wn_.z + a3.y*wn_.w;
        ahn[2][uu]   += a0.z*wn_.x + a1.z*wn_.y + a2.z*wn_.z + a3.z*wn_.w;
        ahn[3][uu]   += a0.w*wn_.x + a1.w*wn_.y + a2.w*wn_.z + a3.w*wn_.w;
      }
    }
    // ---- x part
    if (DIN == 64) {
      #pragma unroll 1
      for (int k=0; k<64; k+=4) {
        float4 a0 = *(const float4*)&A_s[(64+k+0)*36 + r4];
        float4 a1 = *(const float4*)&A_s[(64+k+1)*36 + r4];
        float4 a2 = *(const float4*)&A_s[(64+k+2)*36 + r4];
        float4 a3 = *(const float4*)&A_s[(64+k+3)*36 + r4];
        #pragma unroll
        for (int uu=0;uu<4;++uu){
          int u = u0+uu;
          float4 wr_ = *(const float4*)&wih[(size_t)u*64 + k];
          float4 wz_ = *(const float4*)&wih[(size_t)(64+u)*64 + k];
          float4 wn_ = *(const float4*)&wih[(size_t)(128+u)*64 + k];
          arz[0][uu]   += a0.x*wr_.x + a1.x*wr_.y + a2.x*wr_.z + a3.x*wr_.w;
          arz[1][uu]   += a0.y*wr_.x + a1.y*wr_.y + a2.y*wr_.z + a3.y*wr_.w;
          arz[2][uu]   += a0.z*wr_.x + a1.z*wr_.y + a2.z*wr_.z + a3.z*wr_.w;
          arz[3][uu]   += a0.w*wr_.x + a1.w*wr_.y + a2.w*wr_.z + a3.w*wr_.w;
          arz[0][4+uu] += a0.x*wz_.x + a1.x*wz_.y + a2.x*wz_.z + a3.x*wz_.w;
          arz[1][4+uu] += a0.y*wz_.x + a1.y*wz_.y + a2.y*wz_.z + a3.y*wz_.w;
          arz[2][4+uu] += a0.z*wz_.x + a1.z*wz_.y + a2.z*wz_.z + a3.z*wz_.w;
          arz[3][4+uu] += a0.w*wz_.x + a1.w*wz_.y + a2.w*wz_.z + a3.w*wz_.w;
          axn[0][uu]   += a0.x*wn_.x + a1.x*wn_.y + a2.x*wn_.z + a3.x*wn_.w;
          axn[1][uu]   += a0.y*wn_.x + a1.y*wn_.y + a2.y*wn_.z + a3.y*wn_.w;
          axn[2][uu]   += a0.z*wn_.x + a1.z*wn_.y + a2.z*wn_.z + a3.z*wn_.w;
          axn[3][uu]   += a0.w*wn_.x + a1.w*wn_.y + a2.w*wn_.z + a3.w*wn_.w;
        }
      }
    } else {
      #pragma unroll 1
      for (int kk=0; kk<DIN; ++kk) {
        float4 a = *(const float4*)&A_s[(64+kk)*36 + r4];
        #pragma unroll
        for (int uu=0;uu<4;++uu){
          int u = u0+uu;
          float wr_ = wih[(size_t)u*DIN + kk];
          float wz_ = wih[(size_t)(64+u)*DIN + kk];
          float wn_ = wih[(size_t)(128+u)*DIN + kk];
          arz[0][uu]   += a.x*wr_;  arz[1][uu]   += a.y*wr_;
          arz[2][uu]   += a.z*wr_;  arz[3][uu]   += a.w*wr_;
          arz[0][4+uu] += a.x*wz_;  arz[1][4+uu] += a.y*wz_;
          arz[2][4+uu] += a.z*wz_;  arz[3][4+uu] += a.w*wz_;
          axn[0][uu]   += a.x*wn_;  axn[1][uu]   += a.y*wn_;
          axn[2][uu]   += a.z*wn_;  axn[3][uu]   += a.w*wn_;
        }
      }
    }

    // ---- gates + output
    float o_new[4][4];
    #pragma unroll
    for (int rr=0;rr<4;++rr){
      #pragma unroll
      for (int uu=0;uu<4;++uu){
        float rg = sigm(arz[rr][uu]   + brc[uu]);
        float zg = sigm(arz[rr][4+uu] + bzc[uu]);
        float ng = tanhf(axn[rr][uu] + bxn[uu] + rg*(ahn[rr][uu] + bhn[uu]));
        float hp = A_s[(u0+uu)*36 + r4+rr];
        o_new[rr][uu] = (1.f - zg)*ng + zg*hp;
      }
    }
    __syncthreads();   // everyone done reading A_s (h and x zones)
    // write new h into LDS
    #pragma unroll
    for (int rr=0;rr<4;++rr)
      #pragma unroll
      for (int uu=0;uu<4;++uu)
        A_s[(u0+uu)*36 + r4+rr] = o_new[rr][uu];
    // stage x_{t+1}
    if (t+1 < T_) {
      if (DIN == 64) {
        for (int idx = tid; idx < 32*64; idx += 128) {
          int row = idx >> 6, c = idx & 63;
          A_s[(64+c)*36 + row] = xseq[((size_t)(t+1)*M_ + row0+row)*64 + c];
        }
      } else {
        for (int idx = tid; idx < 32*DIN; idx += 128) {
          int row = idx / DIN, kk = idx - row*DIN;
          A_s[(64+kk)*36 + row] = xseq[((size_t)(t+1)*M_ + row0+row)*DIN + kk];
        }
      }
    }
    // write output to global
    #pragma unroll
    for (int rr=0;rr<4;++rr){
      #pragma unroll
      for (int uu=0;uu<4;++uu){
        if (WSEQ) oseq[(size_t)t*M_*64 + obase[rr] + u0+uu] = o_new[rr][uu];
        if (WFIN) ofin[obase[rr] + (size_t)t*N_*64 + u0+uu] = o_new[rr][uu];
      }
    }
    __syncthreads();   // A_s (h and x) ready for next step
  }
}

// ---------------- stage C: fc2 MLP over out1 rows + nodevec = tanh(emb1*filt)
__global__ __launch_bounds__(256) void k_stageC(
    const float* __restrict__ out1, const float* __restrict__ emb1,
    const float* __restrict__ w1, const float* __restrict__ b1,
    const float* __restrict__ w2, const float* __restrict__ b2,
    const float* __restrict__ w3, const float* __restrict__ b3,
    float* __restrict__ ndv)
{
  int idx = blockIdx.x*256 + threadIdx.x;
  int m = idx % M_;
  int n = m % N_;
  float rv[64];
  const float4* r4 = (const float4*)(out1 + (size_t)idx*64);
  #pragma unroll
  for (int q=0;q<16;++q){ float4 v=r4[q]; rv[q*4]=v.x; rv[q*4+1]=v.y; rv[q*4+2]=v.z; rv[q*4+3]=v.w; }
  float h1[16];
  for (int u=0;u<16;++u){
    float a = b1[u];
    const float* wr = w1 + u*64;
    #pragma unroll
    for (int c=0;c<64;++c) a += rv[c]*wr[c];
    h1[u] = sigm(a);
  }
  float h2[2];
  #pragma unroll
  for (int v=0;v<2;++v){
    float a = b2[v];
    #pragma unroll
    for (int u=0;u<16;++u) a += h1[u]*w2[v*16+u];
    h2[v] = sigm(a);
  }
  #pragma unroll
  for (int d=0;d<10;++d){
    float f = b3[d] + h2[0]*w3[d*2] + h2[1]*w3[d*2+1];
    ndv[(size_t)idx*10 + d] = tanhf(emb1[n*10+d]*f);
  }
}

// ---------------- stage D: x_g = out1 + relu(V V^T) @ out1 per (t,b)
__global__ __launch_bounds__(256) void k_stageD(
    const float* __restrict__ ndv, const float* __restrict__ out1, float* __restrict__ xg)
{
  int tb = blockIdx.y;
  int tile = blockIdx.x;               // 0..4
  int tid = threadIdx.x;
  __shared__ __align__(16) float V_s[320*12];
  __shared__ __align__(16) float o_s[64*68];
  __shared__ __align__(16) float s_s[64*68];   // s_s[m][row-within-tile]

  for (int i = tid; i < 320*12; i += 256) {
    int n = i / 12, d = i - n*12;
    V_s[i] = (n < N_ && d < 10) ? ndv[((size_t)tb*N_ + n)*10 + d] : 0.f;
  }
  __syncthreads();

  const int sr  = tid & 63;            // s-phase: row within tile
  const int smg = tid >> 6;            // s-phase: m-group (16 m's)
  float vr[10];
  {
    const float* vp = &V_s[(tile*64 + sr)*12];
    #pragma unroll
    for (int d = 0; d < 10; ++d) vr[d] = vp[d];
  }
  const int rq = tid & 15, cq = tid >> 4;
  const int r4 = rq*4, c4 = cq*4;
  float acc[4][4];
  #pragma unroll
  for (int a=0;a<4;++a)
    #pragma unroll
    for (int b=0;b<4;++b) acc[a][b]=0.f;

  for (int mc = 0; mc < 320; mc += 64) {
    __syncthreads();
    for (int i = tid; i < 1024; i += 256) {
      int row = i >> 4, f4 = i & 15;
      int gm = mc + row;
      float4 v = make_float4(0.f,0.f,0.f,0.f);
      if (gm < N_) v = *(const float4*)&out1[((size_t)tb*N_ + gm)*64 + f4*4];
      *(float4*)&o_s[row*68 + f4*4] = v;
    }
    #pragma unroll
    for (int j = 0; j < 16; ++j) {
      int m = smg*16 + j;
      const float* vm = &V_s[(mc + m)*12];
      float s = vr[0]*vm[0] + vr[1]*vm[1] + vr[2]*vm[2] + vr[3]*vm[3] + vr[4]*vm[4]
              + vr[5]*vm[5] + vr[6]*vm[6] + vr[7]*vm[7] + vr[8]*vm[8] + vr[9]*vm[9];
      s_s[m*68 + sr] = fmaxf(s, 0.f);
    }
    __syncthreads();
    #pragma unroll 8
    for (int m = 0; m < 64; ++m) {
      float4 sv = *(const float4*)&s_s[m*68 + r4];
      float4 ov = *(const float4*)&o_s[m*68 + c4];
      acc[0][0] += sv.x*ov.x; acc[0][1] += sv.x*ov.y; acc[0][2] += sv.x*ov.z; acc[0][3] += sv.x*ov.w;
      acc[1][0] += sv.y*ov.x; acc[1][1] += sv.y*ov.y; acc[1][2] += sv.y*ov.z; acc[1][3] += sv.y*ov.w;
      acc[2][0] += sv.z*ov.x; acc[2][1] += sv.z*ov.y; acc[2][2] += sv.z*ov.z; acc[2][3] += sv.z*ov.w;
      acc[3][0] += sv.w*ov.x; acc[3][1] += sv.w*ov.y; acc[3][2] += sv.w*ov.z; acc[3][3] += sv.w*ov.w;
    }
  }

  #pragma unroll
  for (int rr = 0; rr < 4; ++rr) {
    int nrow = tile*64 + r4 + rr;
    if (nrow < N_) {
      size_t base = ((size_t)tb*N_ + nrow)*64 + c4;
      float4 o = *(const float4*)&out1[base];
      *(float4*)&xg[base] = make_float4(o.x+acc[rr][0], o.y+acc[rr][1],
                                        o.z+acc[rr][2], o.w+acc[rr][3]);
    }
  }
}

// ---------------- stage E: diff1 = x_g @ Wn + bn ; g2_in = [out1,diff1] @ diff_w^T + diff_b
// thread map (r = tid>>3, ug = tid&7): per-wave row reads are 8 distinct float4
// (full bank sweep) x 8-way broadcast -> conflict-free.
__global__ __launch_bounds__(256) void k_stageE(
    const float* xg_in, const float* __restrict__ out1,
    const float* __restrict__ Wn, const float* __restrict__ bn,
    const float* __restrict__ dw, const float* __restrict__ db,
    float* xg_out)
{
  int n = blockIdx.y;
  int tile = blockIdx.x;     // 24 tiles of 32 tb-rows
  int tid = threadIdx.x;
  int r = tid >> 3, ug = tid & 7;
  __shared__ __align__(16) float x_s[32*68];
  __shared__ __align__(16) float o_s[32*68];
  __shared__ __align__(16) float W_s[64*68];    // transposed: [r_out][c]
  __shared__ __align__(16) float dw_s[64*132];
  __shared__ __align__(16) float d1_s[32*68];
  for (int idx=tid; idx<32*64; idx+=256){
    int row=idx>>6, c=idx&63;
    size_t g = ((size_t)(tile*32+row)*N_ + n)*64 + c;
    x_s[row*68+c] = xg_in[g];
    o_s[row*68+c] = out1[g];
  }
  for (int idx=tid; idx<4096; idx+=256){
    int c=idx>>6, u=idx&63;
    W_s[u*68+c] = Wn[(size_t)n*4096 + c*64 + u];
  }
  for (int idx=tid; idx<64*128; idx+=256){
    int u=idx>>7, c=idx&127;
    dw_s[u*132+c] = dw[u*128+c];
  }
  __syncthreads();
  float d1[8];
  #pragma unroll
  for (int uu=0;uu<8;++uu) d1[uu] = bn[n*64 + ug + 8*uu];
  for (int c=0;c<64;c+=4){
    float4 xc = *(const float4*)&x_s[r*68+c];
    #pragma unroll
    for (int uu=0;uu<8;++uu){
      float4 w = *(const float4*)&W_s[(ug+8*uu)*68 + c];
      d1[uu] += xc.x*w.x + xc.y*w.y + xc.z*w.z + xc.w*w.w;
    }
  }
  #pragma unroll
  for (int uu=0;uu<8;++uu) d1_s[r*68 + ug + 8*uu] = d1[uu];
  __syncthreads();
  float g2[8];
  #pragma unroll
  for (int uu=0;uu<8;++uu) g2[uu] = db[ug + 8*uu];
  for (int c=0;c<64;c+=4){
    float4 oc = *(const float4*)&o_s[r*68+c];
    float4 dc = *(const float4*)&d1_s[r*68+c];
    #pragma unroll
    for (int uu=0;uu<8;++uu){
      int u = ug + 8*uu;
      float4 w0 = *(const float4*)&dw_s[u*132 + c];
      float4 w1 = *(const float4*)&dw_s[u*132 + 64 + c];
      g2[uu] += oc.x*w0.x + oc.y*w0.y + oc.z*w0.z + oc.w*w0.w
              + dc.x*w1.x + dc.y*w1.y + dc.z*w1.z + dc.w*w1.w;
    }
  }
  size_t base = ((size_t)(tile*32+r)*N_ + n)*64;
  #pragma unroll
  for (int uu=0;uu<8;++uu) xg_out[base + ug + 8*uu] = g2[uu];
}

extern "C" void kernel_launch(void* const* d_in, const int* in_sizes, int n_in,
                              void* d_out, int out_size, void* d_ws, size_t ws_size,
                              hipStream_t stream)
{
  (void)in_sizes; (void)n_in; (void)out_size;
  const float* x    = (const float*)d_in[0];
  const float* emb1 = (const float*)d_in[1];
  const float* emb2 = (const float*)d_in[2];
  const float* xw1  = (const float*)d_in[3];
  const float* xb1  = (const float*)d_in[4];
  const float* xw2  = (const float*)d_in[5];
  const float* xb2  = (const float*)d_in[6];
  const float* xw3  = (const float*)d_in[7];
  const float* xb3  = (const float*)d_in[8];
  const float* fw1  = (const float*)d_in[9];
  const float* fb1  = (const float*)d_in[10];
  const float* fw2  = (const float*)d_in[11];
  const float* fb2  = (const float*)d_in[12];
  const float* fw3  = (const float*)d_in[13];
  const float* fb3  = (const float*)d_in[14];
  const float* c2w1 = (const float*)d_in[15];
  const float* c2b1 = (const float*)d_in[16];
  const float* c2w2 = (const float*)d_in[17];
  const float* c2b2 = (const float*)d_in[18];
  const float* c2w3 = (const float*)d_in[19];
  const float* c2b3 = (const float*)d_in[20];
  const float* g1wih= (const float*)d_in[21];
  const float* g1whh= (const float*)d_in[22];
  const float* g1bih= (const float*)d_in[23];
  const float* g1bhh= (const float*)d_in[24];
  const float* g2wih= (const float*)d_in[25];
  const float* g2whh= (const float*)d_in[26];
  const float* g2bih= (const float*)d_in[27];
  const float* g2bhh= (const float*)d_in[28];
  const float* wpool= (const float*)d_in[29];
  const float* bpool= (const float*)d_in[30];
  const float* dww  = (const float*)d_in[31];
  const float* dwb  = (const float*)d_in[32];
  float* out = (float*)d_out;

  float* ws = (float*)d_ws;
  float* g1_in = ws;                          // TM*10
  float* out1  = g1_in + (size_t)TM_*10;      // TM*64
  float* ndv   = out1 + (size_t)TM_*64;       // TM*10
  float* xg    = ndv + (size_t)TM_*10;        // TM*64
  float* Wn    = xg + (size_t)TM_*64;         // N*4096
  float* bn    = Wn + (size_t)N_*4096;        // N*64
  size_t need = ((size_t)(bn + (size_t)N_*64 - ws)) * 4;
  if (ws_size < need) return;

  k_stageA<<<TM_/256, 256, 0, stream>>>(x, xw1,xb1,xw2,xb2,xw3,xb3, fw1,fb1,fw2,fb2,fw3,fb3, g1_in);
  k_wn<<<N_, 256, 0, stream>>>(emb2, wpool, bpool, Wn, bn);

  k_gruP<10,true,false><<<M_/32, 128, 0, stream>>>(
      g1_in, g1wih, g1whh, g1bih, g1bhh, out1, nullptr);

  k_stageC<<<TM_/256, 256, 0, stream>>>(out1, emb1, c2w1,c2b1,c2w2,c2b2,c2w3,c2b3, ndv);
  k_stageD<<<dim3(5, T_*B_), 256, 0, stream>>>(ndv, out1, xg);
  k_stageE<<<dim3((T_*B_)/32, N_), 256, 0, stream>>>(xg, out1, Wn, bn, dww, dwb, xg);

  k_gruP<64,false,true><<<M_/32, 128, 0, stream>>>(
      xg, g2wih, g2whh, g2bih, g2bhh, nullptr, out);
}

// Round 5
// 1023.663 us; speedup vs baseline: 14.9035x; 1.2610x over previous
//
#include <hip/hip_runtime.h>
#include <math.h>

#define B_ 64
#define T_ 12
#define N_ 307
#define I_ 3
#define R_ 64
#define D_ 10
#define M_ (B_*N_)      // 19648
#define TM_ (T_*M_)     // 235776

__device__ __forceinline__ float sigm(float x){ return 1.f/(1.f+__expf(-x)); }
__device__ __forceinline__ float bf2f(unsigned short h){ return __uint_as_float(((unsigned)h)<<16); }
__device__ __forceinline__ unsigned short f2bf(float v){
  unsigned ui = __float_as_uint(v);
  unsigned r = (ui + 0x7fffu + ((ui>>16)&1u)) >> 16;
  return (unsigned short)r;
}

// ---------------- stage A: x-embedding MLP + feature gram + fc1 MLP -> g1_in [T][M][10]
__global__ __launch_bounds__(256) void k_stageA(
    const float* __restrict__ x,
    const float* __restrict__ xw1, const float* __restrict__ xb1,
    const float* __restrict__ xw2, const float* __restrict__ xb2,
    const float* __restrict__ xw3, const float* __restrict__ xb3,
    const float* __restrict__ fw1, const float* __restrict__ fb1,
    const float* __restrict__ fw2, const float* __restrict__ fb2,
    const float* __restrict__ fw3, const float* __restrict__ fb3,
    float* __restrict__ g1)
{
  int idx = blockIdx.x*256 + threadIdx.x;      // t*M + m, exact grid
  int t = idx / M_;
  int m = idx - t*M_;
  int b = m / N_;
  int n = m - b*N_;
  const float* xp = x + (((size_t)b*T_ + t)*N_ + n)*I_;
  float xv[3] = {xp[0], xp[1], xp[2]};
  float e[3][10];
  #pragma unroll
  for (int i=0;i<3;++i){
    float h1[16];
    #pragma unroll
    for (int u=0;u<16;++u) h1[u] = sigm(xv[i]*xw1[u] + xb1[u]);
    float h2[2];
    #pragma unroll
    for (int v=0;v<2;++v){
      float a = xb2[v];
      #pragma unroll
      for (int u=0;u<16;++u) a += h1[u]*xw2[v*16+u];
      h2[v] = sigm(a);
    }
    #pragma unroll
    for (int d=0;d<10;++d) e[i][d] = xb3[d] + h2[0]*xw3[d*2] + h2[1]*xw3[d*2+1];
  }
  float in1[3];
  #pragma unroll
  for (int j=0;j<3;++j){
    float acc = 0.f;
    #pragma unroll
    for (int i=0;i<3;++i){
      float s = 0.f;
      #pragma unroll
      for (int d=0;d<10;++d) s += e[j][d]*e[i][d];
      s = fmaxf(s, 0.f);
      acc += s*xv[i];
    }
    in1[j] = xv[j] + acc;
  }
  float h1[16];
  #pragma unroll
  for (int u=0;u<16;++u)
    h1[u] = sigm(fb1[u] + in1[0]*fw1[u*3] + in1[1]*fw1[u*3+1] + in1[2]*fw1[u*3+2]);
  float h2[2];
  #pragma unroll
  for (int v=0;v<2;++v){
    float a = fb2[v];
    #pragma unroll
    for (int u=0;u<16;++u) a += h1[u]*fw2[v*16+u];
    h2[v] = sigm(a);
  }
  float* gp = g1 + (size_t)idx*10;
  #pragma unroll
  for (int d=0;d<10;++d) gp[d] = fb3[d] + h2[0]*fw3[d*2] + h2[1]*fw3[d*2+1];
}

// ---------------- per-node mixing matrices: Wn [N][c*64+r], bn [N][64]
__global__ __launch_bounds__(256) void k_wn(
    const float* __restrict__ emb2, const float* __restrict__ wpool,
    const float* __restrict__ bpool, float* __restrict__ Wn, float* __restrict__ bn)
{
  int n = blockIdx.x; int tid = threadIdx.x;
  __shared__ float e_s[10];
  if (tid < 10) e_s[tid] = emb2[n*10 + tid];
  __syncthreads();
  #pragma unroll
  for (int e=0;e<16;++e){
    int i = e*256 + tid;            // 0..4095
    float a = 0.f;
    #pragma unroll
    for (int d=0;d<10;++d) a += e_s[d]*wpool[(size_t)d*4096 + i];
    Wn[(size_t)n*4096 + i] = a;
  }
  if (tid < 64){
    float a = 0.f;
    #pragma unroll
    for (int d=0;d<10;++d) a += e_s[d]*bpool[d*64 + tid];
    bn[n*64 + tid] = a;
  }
}

// ---------------- persistent GRU scan, weights in LDS (bf16):
// 16 rows/block, grid M/16 = 1228. 256 threads: tr=tid&3 -> 4 rows, u=tid>>2 -> 1 unit.
// W_s[wr][WS] bf16: cols 0..63 = whh, 64..64+DIN-1 = wih (zero-pad to XPAD).
// h_s[k][row] fp32 stride 20; x_s[kk][row] fp32 stride 20, staged per step.
// r/z gates merge x+h accumulators; n gate split (needs r*hn).
template<int DIN, int XPAD, int WS, bool WSEQ, bool WFIN>
__global__ __launch_bounds__(256, 2) void k_gruT(
    const float* __restrict__ xseq,   // [T][M][DIN]
    const float* __restrict__ wih,    // [192][DIN]
    const float* __restrict__ whh,    // [192][64]
    const float* __restrict__ bih, const float* __restrict__ bhh,
    float* __restrict__ oseq,         // [T][M][64]   (if WSEQ)
    float* __restrict__ ofin)         // [B][T][N][64] (if WFIN)
{
  __shared__ __align__(16) unsigned short W_s[192*WS];
  __shared__ __align__(16) float h_s[64*20];
  __shared__ __align__(16) float x_s[XPAD*20];
  const int tid = threadIdx.x;
  const int row0 = blockIdx.x * 16;
  const int tr = tid & 3, u = tid >> 2;
  const int r4 = tr * 4;

  // stage weights (f32 -> bf16), zero-padded x columns
  for (int idx = tid; idx < 192*WS; idx += 256) {
    int wr = idx / WS, c = idx - wr*WS;
    float v = 0.f;
    if (c < 64) v = whh[wr*64 + c];
    else if (c - 64 < DIN) v = wih[wr*DIN + (c-64)];
    W_s[idx] = f2bf(v);
  }
  // h = 0
  for (int idx = tid; idx < 64*20; idx += 256) h_s[idx] = 0.f;

  // merged biases
  const float brc = bih[u]     + bhh[u];
  const float bzc = bih[64+u]  + bhh[64+u];
  const float bxn = bih[128+u];
  const float bhn = bhh[128+u];

  // per-row info
  int grow[4]; size_t obase[4];
  #pragma unroll
  for (int rr=0;rr<4;++rr){
    int g = row0 + r4 + rr;
    grow[rr] = g;
    if (WFIN){
      int bb = g / N_, nn = g - bb*N_;
      obase[rr] = (((size_t)bb*T_)*N_ + nn)*64;
    } else {
      obase[rr] = (size_t)g*64;
    }
  }
  __syncthreads();

  for (int t = 0; t < T_; ++t) {
    // stage x_t (transposed into x_s[kk][row])
    if (DIN == 64) {
      for (int idx = tid; idx < 16*64; idx += 256) {
        int row = idx >> 6, c = idx & 63;
        x_s[c*20 + row] = xseq[((size_t)t*M_ + row0+row)*64 + c];
      }
    } else {
      for (int idx = tid; idx < 16*XPAD; idx += 256) {
        int row = idx / XPAD, kk = idx - row*XPAD;
        x_s[kk*20 + row] = (kk < DIN) ? xseq[((size_t)t*M_ + row0+row)*DIN + kk] : 0.f;
      }
    }
    __syncthreads();

    float ar[4], az[4], anh[4], anx[4];
    #pragma unroll
    for (int rr=0;rr<4;++rr){ ar[rr]=0.f; az[rr]=0.f; anh[rr]=0.f; anx[rr]=0.f; }

    // ---- h part (K = 64)
    #pragma unroll 2
    for (int k=0; k<64; k+=4) {
      float4 a0 = *(const float4*)&h_s[(k+0)*20 + r4];
      float4 a1 = *(const float4*)&h_s[(k+1)*20 + r4];
      float4 a2 = *(const float4*)&h_s[(k+2)*20 + r4];
      float4 a3 = *(const float4*)&h_s[(k+3)*20 + r4];
      ushort4 wr4 = *(const ushort4*)&W_s[u*WS + k];
      ushort4 wz4 = *(const ushort4*)&W_s[(64+u)*WS + k];
      ushort4 wn4 = *(const ushort4*)&W_s[(128+u)*WS + k];
      float wrx=bf2f(wr4.x), wry=bf2f(wr4.y), wrz=bf2f(wr4.z), wrw=bf2f(wr4.w);
      float wzx=bf2f(wz4.x), wzy=bf2f(wz4.y), wzz=bf2f(wz4.z), wzw=bf2f(wz4.w);
      float wnx=bf2f(wn4.x), wny=bf2f(wn4.y), wnz=bf2f(wn4.z), wnw=bf2f(wn4.w);
      ar[0] += a0.x*wrx + a1.x*wry + a2.x*wrz + a3.x*wrw;
      ar[1] += a0.y*wrx + a1.y*wry + a2.y*wrz + a3.y*wrw;
      ar[2] += a0.z*wrx + a1.z*wry + a2.z*wrz + a3.z*wrw;
      ar[3] += a0.w*wrx + a1.w*wry + a2.w*wrz + a3.w*wrw;
      az[0] += a0.x*wzx + a1.x*wzy + a2.x*wzz + a3.x*wzw;
      az[1] += a0.y*wzx + a1.y*wzy + a2.y*wzz + a3.y*wzw;
      az[2] += a0.z*wzx + a1.z*wzy + a2.z*wzz + a3.z*wzw;
      az[3] += a0.w*wzx + a1.w*wzy + a2.w*wzz + a3.w*wzw;
      anh[0] += a0.x*wnx + a1.x*wny + a2.x*wnz + a3.x*wnw;
      anh[1] += a0.y*wnx + a1.y*wny + a2.y*wnz + a3.y*wnw;
      anh[2] += a0.z*wnx + a1.z*wny + a2.z*wnz + a3.z*wnw;
      anh[3] += a0.w*wnx + a1.w*wny + a2.w*wnz + a3.w*wnw;
    }
    // ---- x part (K = XPAD, zero-padded)
    #pragma unroll 2
    for (int k=0; k<XPAD; k+=4) {
      float4 a0 = *(const float4*)&x_s[(k+0)*20 + r4];
      float4 a1 = *(const float4*)&x_s[(k+1)*20 + r4];
      float4 a2 = *(const float4*)&x_s[(k+2)*20 + r4];
      float4 a3 = *(const float4*)&x_s[(k+3)*20 + r4];
      ushort4 wr4 = *(const ushort4*)&W_s[u*WS + 64 + k];
      ushort4 wz4 = *(const ushort4*)&W_s[(64+u)*WS + 64 + k];
      ushort4 wn4 = *(const ushort4*)&W_s[(128+u)*WS + 64 + k];
      float wrx=bf2f(wr4.x), wry=bf2f(wr4.y), wrz=bf2f(wr4.z), wrw=bf2f(wr4.w);
      float wzx=bf2f(wz4.x), wzy=bf2f(wz4.y), wzz=bf2f(wz4.z), wzw=bf2f(wz4.w);
      float wnx=bf2f(wn4.x), wny=bf2f(wn4.y), wnz=bf2f(wn4.z), wnw=bf2f(wn4.w);
      ar[0] += a0.x*wrx + a1.x*wry + a2.x*wrz + a3.x*wrw;
      ar[1] += a0.y*wrx + a1.y*wry + a2.y*wrz + a3.y*wrw;
      ar[2] += a0.z*wrx + a1.z*wry + a2.z*wrz + a3.z*wrw;
      ar[3] += a0.w*wrx + a1.w*wry + a2.w*wrz + a3.w*wrw;
      az[0] += a0.x*wzx + a1.x*wzy + a2.x*wzz + a3.x*wzw;
      az[1] += a0.y*wzx + a1.y*wzy + a2.y*wzz + a3.y*wzw;
      az[2] += a0.z*wzx + a1.z*wzy + a2.z*wzz + a3.z*wzw;
      az[3] += a0.w*wzx + a1.w*wzy + a2.w*wzz + a3.w*wzw;
      anx[0] += a0.x*wnx + a1.x*wny + a2.x*wnz + a3.x*wnw;
      anx[1] += a0.y*wnx + a1.y*wny + a2.y*wnz + a3.y*wnw;
      anx[2] += a0.z*wnx + a1.z*wny + a2.z*wnz + a3.z*wnw;
      anx[3] += a0.w*wnx + a1.w*wny + a2.w*wnz + a3.w*wnw;
    }

    // ---- gates
    float o_new[4];
    #pragma unroll
    for (int rr=0;rr<4;++rr){
      float rg = sigm(ar[rr] + brc);
      float zg = sigm(az[rr] + bzc);
      float ng = tanhf(anx[rr] + bxn + rg*(anh[rr] + bhn));
      float hp = h_s[u*20 + r4+rr];
      o_new[rr] = (1.f - zg)*ng + zg*hp;
    }
    __syncthreads();   // all reads of h_s/x_s done
    #pragma unroll
    for (int rr=0;rr<4;++rr){
      h_s[u*20 + r4+rr] = o_new[rr];
      if (WSEQ) oseq[(size_t)t*M_*64 + obase[rr] + u] = o_new[rr];
      if (WFIN) ofin[obase[rr] + (size_t)t*N_*64 + u] = o_new[rr];
    }
    __syncthreads();   // h_s ready; x_s free to restage
  }
}

// ---------------- stage C: fc2 MLP over out1 rows + nodevec = tanh(emb1*filt)
__global__ __launch_bounds__(256) void k_stageC(
    const float* __restrict__ out1, const float* __restrict__ emb1,
    const float* __restrict__ w1, const float* __restrict__ b1,
    const float* __restrict__ w2, const float* __restrict__ b2,
    const float* __restrict__ w3, const float* __restrict__ b3,
    float* __restrict__ ndv)
{
  int idx = blockIdx.x*256 + threadIdx.x;
  int m = idx % M_;
  int n = m % N_;
  float rv[64];
  const float4* r4 = (const float4*)(out1 + (size_t)idx*64);
  #pragma unroll
  for (int q=0;q<16;++q){ float4 v=r4[q]; rv[q*4]=v.x; rv[q*4+1]=v.y; rv[q*4+2]=v.z; rv[q*4+3]=v.w; }
  float h1[16];
  for (int u=0;u<16;++u){
    float a = b1[u];
    const float* wr = w1 + u*64;
    #pragma unroll
    for (int c=0;c<64;++c) a += rv[c]*wr[c];
    h1[u] = sigm(a);
  }
  float h2[2];
  #pragma unroll
  for (int v=0;v<2;++v){
    float a = b2[v];
    #pragma unroll
    for (int u=0;u<16;++u) a += h1[u]*w2[v*16+u];
    h2[v] = sigm(a);
  }
  #pragma unroll
  for (int d=0;d<10;++d){
    float f = b3[d] + h2[0]*w3[d*2] + h2[1]*w3[d*2+1];
    ndv[(size_t)idx*10 + d] = tanhf(emb1[n*10+d]*f);
  }
}

// ---------------- stage D: x_g = out1 + relu(V V^T) @ out1 per (t,b)
__global__ __launch_bounds__(256) void k_stageD(
    const float* __restrict__ ndv, const float* __restrict__ out1, float* __restrict__ xg)
{
  int tb = blockIdx.y;
  int tile = blockIdx.x;               // 0..4
  int tid = threadIdx.x;
  __shared__ __align__(16) float V_s[320*12];
  __shared__ __align__(16) float o_s[64*68];
  __shared__ __align__(16) float s_s[64*68];   // s_s[m][row-within-tile]

  for (int i = tid; i < 320*12; i += 256) {
    int n = i / 12, d = i - n*12;
    V_s[i] = (n < N_ && d < 10) ? ndv[((size_t)tb*N_ + n)*10 + d] : 0.f;
  }
  __syncthreads();

  const int sr  = tid & 63;            // s-phase: row within tile
  const int smg = tid >> 6;            // s-phase: m-group (16 m's)
  float vr[10];
  {
    const float* vp = &V_s[(tile*64 + sr)*12];
    #pragma unroll
    for (int d = 0; d < 10; ++d) vr[d] = vp[d];
  }
  const int rq = tid & 15, cq = tid >> 4;
  const int r4 = rq*4, c4 = cq*4;
  float acc[4][4];
  #pragma unroll
  for (int a=0;a<4;++a)
    #pragma unroll
    for (int b=0;b<4;++b) acc[a][b]=0.f;

  for (int mc = 0; mc < 320; mc += 64) {
    __syncthreads();
    for (int i = tid; i < 1024; i += 256) {
      int row = i >> 4, f4 = i & 15;
      int gm = mc + row;
      float4 v = make_float4(0.f,0.f,0.f,0.f);
      if (gm < N_) v = *(const float4*)&out1[((size_t)tb*N_ + gm)*64 + f4*4];
      *(float4*)&o_s[row*68 + f4*4] = v;
    }
    #pragma unroll
    for (int j = 0; j < 16; ++j) {
      int m = smg*16 + j;
      const float* vm = &V_s[(mc + m)*12];
      float s = vr[0]*vm[0] + vr[1]*vm[1] + vr[2]*vm[2] + vr[3]*vm[3] + vr[4]*vm[4]
              + vr[5]*vm[5] + vr[6]*vm[6] + vr[7]*vm[7] + vr[8]*vm[8] + vr[9]*vm[9];
      s_s[m*68 + sr] = fmaxf(s, 0.f);
    }
    __syncthreads();
    #pragma unroll 8
    for (int m = 0; m < 64; ++m) {
      float4 sv = *(const float4*)&s_s[m*68 + r4];
      float4 ov = *(const float4*)&o_s[m*68 + c4];
      acc[0][0] += sv.x*ov.x; acc[0][1] += sv.x*ov.y; acc[0][2] += sv.x*ov.z; acc[0][3] += sv.x*ov.w;
      acc[1][0] += sv.y*ov.x; acc[1][1] += sv.y*ov.y; acc[1][2] += sv.y*ov.z; acc[1][3] += sv.y*ov.w;
      acc[2][0] += sv.z*ov.x; acc[2][1] += sv.z*ov.y; acc[2][2] += sv.z*ov.z; acc[2][3] += sv.z*ov.w;
      acc[3][0] += sv.w*ov.x; acc[3][1] += sv.w*ov.y; acc[3][2] += sv.w*ov.z; acc[3][3] += sv.w*ov.w;
    }
  }

  #pragma unroll
  for (int rr = 0; rr < 4; ++rr) {
    int nrow = tile*64 + r4 + rr;
    if (nrow < N_) {
      size_t base = ((size_t)tb*N_ + nrow)*64 + c4;
      float4 o = *(const float4*)&out1[base];
      *(float4*)&xg[base] = make_float4(o.x+acc[rr][0], o.y+acc[rr][1],
                                        o.z+acc[rr][2], o.w+acc[rr][3]);
    }
  }
}

// ---------------- stage E: diff1 = x_g @ Wn + bn ; g2_in = [out1,diff1] @ diff_w^T + diff_b
__global__ __launch_bounds__(256) void k_stageE(
    const float* xg_in, const float* __restrict__ out1,
    const float* __restrict__ Wn, const float* __restrict__ bn,
    const float* __restrict__ dw, const float* __restrict__ db,
    float* xg_out)
{
  int n = blockIdx.y;
  int tile = blockIdx.x;     // 24 tiles of 32 tb-rows
  int tid = threadIdx.x;
  int r = tid >> 3, ug = tid & 7;
  __shared__ __align__(16) float x_s[32*68];
  __shared__ __align__(16) float o_s[32*68];
  __shared__ __align__(16) float W_s[64*68];    // transposed: [r_out][c]
  __shared__ __align__(16) float dw_s[64*132];
  __shared__ __align__(16) float d1_s[32*68];
  for (int idx=tid; idx<32*64; idx+=256){
    int row=idx>>6, c=idx&63;
    size_t g = ((size_t)(tile*32+row)*N_ + n)*64 + c;
    x_s[row*68+c] = xg_in[g];
    o_s[row*68+c] = out1[g];
  }
  for (int idx=tid; idx<4096; idx+=256){
    int c=idx>>6, u=idx&63;
    W_s[u*68+c] = Wn[(size_t)n*4096 + c*64 + u];
  }
  for (int idx=tid; idx<64*128; idx+=256){
    int u=idx>>7, c=idx&127;
    dw_s[u*132+c] = dw[u*128+c];
  }
  __syncthreads();
  float d1[8];
  #pragma unroll
  for (int uu=0;uu<8;++uu) d1[uu] = bn[n*64 + ug + 8*uu];
  for (int c=0;c<64;c+=4){
    float4 xc = *(const float4*)&x_s[r*68+c];
    #pragma unroll
    for (int uu=0;uu<8;++uu){
      float4 w = *(const float4*)&W_s[(ug+8*uu)*68 + c];
      d1[uu] += xc.x*w.x + xc.y*w.y + xc.z*w.z + xc.w*w.w;
    }
  }
  #pragma unroll
  for (int uu=0;uu<8;++uu) d1_s[r*68 + ug + 8*uu] = d1[uu];
  __syncthreads();
  float g2[8];
  #pragma unroll
  for (int uu=0;uu<8;++uu) g2[uu] = db[ug + 8*uu];
  for (int c=0;c<64;c+=4){
    float4 oc = *(const float4*)&o_s[r*68+c];
    float4 dc = *(const float4*)&d1_s[r*68+c];
    #pragma unroll
    for (int uu=0;uu<8;++uu){
      int u = ug + 8*uu;
      float4 w0 = *(const float4*)&dw_s[u*132 + c];
      float4 w1 = *(const float4*)&dw_s[u*132 + 64 + c];
      g2[uu] += oc.x*w0.x + oc.y*w0.y + oc.z*w0.z + oc.w*w0.w
              + dc.x*w1.x + dc.y*w1.y + dc.z*w1.z + dc.w*w1.w;
    }
  }
  size_t base = ((size_t)(tile*32+r)*N_ + n)*64;
  #pragma unroll
  for (int uu=0;uu<8;++uu) xg_out[base + ug + 8*uu] = g2[uu];
}

extern "C" void kernel_launch(void* const* d_in, const int* in_sizes, int n_in,
                              void* d_out, int out_size, void* d_ws, size_t ws_size,
                              hipStream_t stream)
{
  (void)in_sizes; (void)n_in; (void)out_size;
  const float* x    = (const float*)d_in[0];
  const float* emb1 = (const float*)d_in[1];
  const float* emb2 = (const float*)d_in[2];
  const float* xw1  = (const float*)d_in[3];
  const float* xb1  = (const float*)d_in[4];
  const float* xw2  = (const float*)d_in[5];
  const float* xb2  = (const float*)d_in[6];
  const float* xw3  = (const float*)d_in[7];
  const float* xb3  = (const float*)d_in[8];
  const float* fw1  = (const float*)d_in[9];
  const float* fb1  = (const float*)d_in[10];
  const float* fw2  = (const float*)d_in[11];
  const float* fb2  = (const float*)d_in[12];
  const float* fw3  = (const float*)d_in[13];
  const float* fb3  = (const float*)d_in[14];
  const float* c2w1 = (const float*)d_in[15];
  const float* c2b1 = (const float*)d_in[16];
  const float* c2w2 = (const float*)d_in[17];
  const float* c2b2 = (const float*)d_in[18];
  const float* c2w3 = (const float*)d_in[19];
  const float* c2b3 = (const float*)d_in[20];
  const float* g1wih= (const float*)d_in[21];
  const float* g1whh= (const float*)d_in[22];
  const float* g1bih= (const float*)d_in[23];
  const float* g1bhh= (const float*)d_in[24];
  const float* g2wih= (const float*)d_in[25];
  const float* g2whh= (const float*)d_in[26];
  const float* g2bih= (const float*)d_in[27];
  const float* g2bhh= (const float*)d_in[28];
  const float* wpool= (const float*)d_in[29];
  const float* bpool= (const float*)d_in[30];
  const float* dww  = (const float*)d_in[31];
  const float* dwb  = (const float*)d_in[32];
  float* out = (float*)d_out;

  float* ws = (float*)d_ws;
  float* g1_in = ws;                          // TM*10
  float* out1  = g1_in + (size_t)TM_*10;      // TM*64
  float* ndv   = out1 + (size_t)TM_*64;       // TM*10
  float* xg    = ndv + (size_t)TM_*10;        // TM*64
  float* Wn    = xg + (size_t)TM_*64;         // N*4096
  float* bn    = Wn + (size_t)N_*4096;        // N*64
  size_t need = ((size_t)(bn + (size_t)N_*64 - ws)) * 4;
  if (ws_size < need) return;

  k_stageA<<<TM_/256, 256, 0, stream>>>(x, xw1,xb1,xw2,xb2,xw3,xb3, fw1,fb1,fw2,fb2,fw3,fb3, g1_in);
  k_wn<<<N_, 256, 0, stream>>>(emb2, wpool, bpool, Wn, bn);

  // GRU1: DIN=10, XPAD=12, WS=84 (conflict-free bf16 stride)
  k_gruT<10,12,84,true,false><<<M_/16, 256, 0, stream>>>(
      g1_in, g1wih, g1whh, g1bih, g1bhh, out1, nullptr);

  k_stageC<<<TM_/256, 256, 0, stream>>>(out1, emb1, c2w1,c2b1,c2w2,c2b2,c2w3,c2b3, ndv);
  k_stageD<<<dim3(5, T_*B_), 256, 0, stream>>>(ndv, out1, xg);
  k_stageE<<<dim3((T_*B_)/32, N_), 256, 0, stream>>>(xg, out1, Wn, bn, dww, dwb, xg);

  // GRU2: DIN=64, XPAD=64, WS=132
  k_gruT<64,64,132,false,true><<<M_/16, 256, 0, stream>>>(
      xg, g2wih, g2whh, g2bih, g2bhh, nullptr, out);
}

// Round 6
// 671.609 us; speedup vs baseline: 22.7159x; 1.5242x over previous
//
#include <hip/hip_runtime.h>
#include <math.h>

#define B_ 64
#define T_ 12
#define N_ 307
#define I_ 3
#define R_ 64
#define D_ 10
#define M_ (B_*N_)      // 19648
#define TM_ (T_*M_)     // 235776

__device__ __forceinline__ float sigm(float x){ return 1.f/(1.f+__expf(-x)); }

// pack two f32 -> one dword of 2 bf16 (lo = a, hi = b)
__device__ __forceinline__ unsigned cvtpk(float a, float b){
  unsigned r;
  asm("v_cvt_pk_bf16_f32 %0, %1, %2" : "=v"(r) : "v"(a), "v"(b));
  return r;
}
// acc += a.lo*b.lo + a.hi*b.hi  (bf16 inputs, f32 accumulate)
__device__ __forceinline__ void dot2(float& acc, unsigned a, unsigned b){
  asm("v_dot2_f32_bf16 %0, %1, %2, %0" : "+v"(acc) : "v"(a), "v"(b));
}

// ---------------- stage A: x-embedding MLP + feature gram + fc1 MLP -> g1_in [T][M][10]
__global__ __launch_bounds__(256) void k_stageA(
    const float* __restrict__ x,
    const float* __restrict__ xw1, const float* __restrict__ xb1,
    const float* __restrict__ xw2, const float* __restrict__ xb2,
    const float* __restrict__ xw3, const float* __restrict__ xb3,
    const float* __restrict__ fw1, const float* __restrict__ fb1,
    const float* __restrict__ fw2, const float* __restrict__ fb2,
    const float* __restrict__ fw3, const float* __restrict__ fb3,
    float* __restrict__ g1)
{
  int idx = blockIdx.x*256 + threadIdx.x;      // t*M + m, exact grid
  int t = idx / M_;
  int m = idx - t*M_;
  int b = m / N_;
  int n = m - b*N_;
  const float* xp = x + (((size_t)b*T_ + t)*N_ + n)*I_;
  float xv[3] = {xp[0], xp[1], xp[2]};
  float e[3][10];
  #pragma unroll
  for (int i=0;i<3;++i){
    float h1[16];
    #pragma unroll
    for (int u=0;u<16;++u) h1[u] = sigm(xv[i]*xw1[u] + xb1[u]);
    float h2[2];
    #pragma unroll
    for (int v=0;v<2;++v){
      float a = xb2[v];
      #pragma unroll
      for (int u=0;u<16;++u) a += h1[u]*xw2[v*16+u];
      h2[v] = sigm(a);
    }
    #pragma unroll
    for (int d=0;d<10;++d) e[i][d] = xb3[d] + h2[0]*xw3[d*2] + h2[1]*xw3[d*2+1];
  }
  float in1[3];
  #pragma unroll
  for (int j=0;j<3;++j){
    float acc = 0.f;
    #pragma unroll
    for (int i=0;i<3;++i){
      float s = 0.f;
      #pragma unroll
      for (int d=0;d<10;++d) s += e[j][d]*e[i][d];
      s = fmaxf(s, 0.f);
      acc += s*xv[i];
    }
    in1[j] = xv[j] + acc;
  }
  float h1[16];
  #pragma unroll
  for (int u=0;u<16;++u)
    h1[u] = sigm(fb1[u] + in1[0]*fw1[u*3] + in1[1]*fw1[u*3+1] + in1[2]*fw1[u*3+2]);
  float h2[2];
  #pragma unroll
  for (int v=0;v<2;++v){
    float a = fb2[v];
    #pragma unroll
    for (int u=0;u<16;++u) a += h1[u]*fw2[v*16+u];
    h2[v] = sigm(a);
  }
  float* gp = g1 + (size_t)idx*10;
  #pragma unroll
  for (int d=0;d<10;++d) gp[d] = fb3[d] + h2[0]*fw3[d*2] + h2[1]*fw3[d*2+1];
}

// ---------------- per-node mixing matrices: Wn [N][c*64+r], bn [N][64]
__global__ __launch_bounds__(256) void k_wn(
    const float* __restrict__ emb2, const float* __restrict__ wpool,
    const float* __restrict__ bpool, float* __restrict__ Wn, float* __restrict__ bn)
{
  int n = blockIdx.x; int tid = threadIdx.x;
  __shared__ float e_s[10];
  if (tid < 10) e_s[tid] = emb2[n*10 + tid];
  __syncthreads();
  #pragma unroll
  for (int e=0;e<16;++e){
    int i = e*256 + tid;            // 0..4095
    float a = 0.f;
    #pragma unroll
    for (int d=0;d<10;++d) a += e_s[d]*wpool[(size_t)d*4096 + i];
    Wn[(size_t)n*4096 + i] = a;
  }
  if (tid < 64){
    float a = 0.f;
    #pragma unroll
    for (int d=0;d<10;++d) a += e_s[d]*bpool[d*64 + tid];
    bn[n*64 + tid] = a;
  }
}

// ---------------- pack GRU weights to bf16 pairs: Wpk[pair][192], pair p = (k=2p, 2p+1)
// k < 64 -> whh col k; k >= 64 -> wih col k-64 (zero-pad past DIN)
__global__ __launch_bounds__(256) void k_wpack(
    const float* __restrict__ wih2, const float* __restrict__ whh2,
    const float* __restrict__ wih1, const float* __restrict__ whh1,
    unsigned* __restrict__ Wpk2, unsigned* __restrict__ Wpk1)
{
  int i = blockIdx.x*256 + threadIdx.x;
  if (i < 64*192) {
    int p = i / 192, wr = i - (i/192)*192;
    int k0 = 2*p, k1 = 2*p + 1;
    float f0 = (k0 < 64) ? whh2[wr*64 + k0] : wih2[wr*64 + (k0-64)];
    float f1 = (k1 < 64) ? whh2[wr*64 + k1] : wih2[wr*64 + (k1-64)];
    Wpk2[i] = cvtpk(f0, f1);
  }
  int j = i - 64*192;
  if (j >= 0 && j < 38*192) {
    int p = j / 192, wr = j - (j/192)*192;
    int k0 = 2*p, k1 = 2*p + 1;
    float f0 = (k0 < 64) ? whh1[wr*64 + k0] : ((k0-64) < 10 ? wih1[wr*10 + (k0-64)] : 0.f);
    float f1 = (k1 < 64) ? whh1[wr*64 + k1] : ((k1-64) < 10 ? wih1[wr*10 + (k1-64)] : 0.f);
    Wpk1[j] = cvtpk(f0, f1);
  }
}

// ---------------- persistent GRU scan with packed-bf16 dot2 math.
// 16 rows/block, grid M/16. 256 threads: tr=tid&3 -> rows tr*4..+3, u=tid>>2 -> unit.
// W_s[pair][192] (prepacked); hp_s[pair][row] packed bf16 h; xp_s[pair][row] packed x.
// h recurrence (z*h blend) stays fp32 in registers; only matmul inputs are bf16.
template<int XP2, bool WSEQ, bool WFIN>
__global__ __launch_bounds__(256) void k_gruD(
    const float* __restrict__ xseq,   // [T][M][DIN] fp32
    const unsigned* __restrict__ Wpk, // [(32+XP2)*192]
    const float* __restrict__ bih, const float* __restrict__ bhh,
    float* __restrict__ oseq,         // [T][M][64]   (if WSEQ)
    float* __restrict__ ofin)         // [B][T][N][64] (if WFIN)
{
  constexpr int P2 = 32 + XP2;
  __shared__ __align__(16) unsigned W_s[P2*192];
  __shared__ __align__(16) unsigned hp_s[32*20];
  __shared__ __align__(16) unsigned xp_s[XP2*20];
  const int tid = threadIdx.x;
  const int row0 = blockIdx.x * 16;
  const int tr = tid & 3, u = tid >> 2;
  const int r4 = tr*4;

  // stage packed weights (coalesced, conflict-free)
  for (int i = tid; i < P2*192; i += 256) W_s[i] = Wpk[i];
  // h = 0
  for (int i = tid; i < 32*20; i += 256) hp_s[i] = 0u;

  const float brc = bih[u]     + bhh[u];
  const float bzc = bih[64+u]  + bhh[64+u];
  const float bxn = bih[128+u];
  const float bhn = bhh[128+u];

  size_t obase[4];
  #pragma unroll
  for (int rr=0;rr<4;++rr){
    int g = row0 + r4 + rr;
    if (WFIN){
      int bb = g / N_, nn = g - bb*N_;
      obase[rr] = (((size_t)bb*T_)*N_ + nn)*64;
    } else {
      obase[rr] = (size_t)g*64;
    }
  }
  float hreg[4] = {0.f, 0.f, 0.f, 0.f};

  // stage x_0
  if (XP2 == 32) {
    for (int idx = tid; idx < 512; idx += 256) {
      int row = idx >> 5, p = idx & 31;
      const float2 v = *(const float2*)&xseq[((size_t)(row0+row))*64 + 2*p];
      xp_s[p*20 + row] = cvtpk(v.x, v.y);
    }
  } else {
    if (tid < 16*XP2) {
      int row = tid / XP2, p = tid - (tid/XP2)*XP2;
      int k0 = 2*p, k1 = 2*p + 1;
      const float* xr = &xseq[((size_t)(row0+row))*10];
      float f0 = (k0 < 10) ? xr[k0] : 0.f;
      float f1 = (k1 < 10) ? xr[k1] : 0.f;
      xp_s[p*20 + row] = cvtpk(f0, f1);
    }
  }
  __syncthreads();

  for (int t = 0; t < T_; ++t) {
    float ar[4]={0,0,0,0}, az[4]={0,0,0,0}, anh[4]={0,0,0,0}, anx[4]={0,0,0,0};

    // ---- h part: 32 pairs
    #pragma unroll 4
    for (int p = 0; p < 32; ++p) {
      uint4 a = *(const uint4*)&hp_s[p*20 + r4];
      unsigned wr_ = W_s[p*192 + u];
      unsigned wz_ = W_s[p*192 + 64 + u];
      unsigned wn_ = W_s[p*192 + 128 + u];
      dot2(ar[0], a.x, wr_); dot2(ar[1], a.y, wr_); dot2(ar[2], a.z, wr_); dot2(ar[3], a.w, wr_);
      dot2(az[0], a.x, wz_); dot2(az[1], a.y, wz_); dot2(az[2], a.z, wz_); dot2(az[3], a.w, wz_);
      dot2(anh[0], a.x, wn_); dot2(anh[1], a.y, wn_); dot2(anh[2], a.z, wn_); dot2(anh[3], a.w, wn_);
    }
    // ---- x part: XP2 pairs
    #pragma unroll 4
    for (int p = 0; p < XP2; ++p) {
      uint4 a = *(const uint4*)&xp_s[p*20 + r4];
      unsigned wr_ = W_s[(32+p)*192 + u];
      unsigned wz_ = W_s[(32+p)*192 + 64 + u];
      unsigned wn_ = W_s[(32+p)*192 + 128 + u];
      dot2(ar[0], a.x, wr_); dot2(ar[1], a.y, wr_); dot2(ar[2], a.z, wr_); dot2(ar[3], a.w, wr_);
      dot2(az[0], a.x, wz_); dot2(az[1], a.y, wz_); dot2(az[2], a.z, wz_); dot2(az[3], a.w, wz_);
      dot2(anx[0], a.x, wn_); dot2(anx[1], a.y, wn_); dot2(anx[2], a.z, wn_); dot2(anx[3], a.w, wn_);
    }

    // ---- gates (fp32 recurrence in registers)
    float o_new[4];
    #pragma unroll
    for (int rr=0;rr<4;++rr){
      float rg = sigm(ar[rr] + brc);
      float zg = sigm(az[rr] + bzc);
      float ng = tanhf(anx[rr] + bxn + rg*(anh[rr] + bhn));
      o_new[rr] = (1.f - zg)*ng + zg*hreg[rr];
      hreg[rr] = o_new[rr];
    }
    // global writes
    #pragma unroll
    for (int rr=0;rr<4;++rr){
      if (WSEQ) oseq[(size_t)t*M_*64 + obase[rr] + u] = o_new[rr];
      if (WFIN) ofin[obase[rr] + (size_t)t*N_*64 + u] = o_new[rr];
    }
    // pack new h pairs via cross-lane (units u, u^1 live in lanes tid, tid^4)
    unsigned pk[4];
    #pragma unroll
    for (int rr=0;rr<4;++rr){
      float pr = __shfl_xor(o_new[rr], 4);
      pk[rr] = cvtpk(o_new[rr], pr);     // valid for even u: lo=u, hi=u+1
    }
    __syncthreads();   // all reads of hp_s / xp_s done
    if ((u & 1) == 0) {
      #pragma unroll
      for (int rr=0;rr<4;++rr) hp_s[(u>>1)*20 + r4 + rr] = pk[rr];
    }
    // stage x_{t+1}
    if (t+1 < T_) {
      if (XP2 == 32) {
        for (int idx = tid; idx < 512; idx += 256) {
          int row = idx >> 5, p = idx & 31;
          const float2 v = *(const float2*)&xseq[((size_t)(t+1)*M_ + row0+row)*64 + 2*p];
          xp_s[p*20 + row] = cvtpk(v.x, v.y);
        }
      } else {
        if (tid < 16*XP2) {
          int row = tid / XP2, p = tid - (tid/XP2)*XP2;
          int k0 = 2*p, k1 = 2*p + 1;
          const float* xr = &xseq[((size_t)(t+1)*M_ + row0+row)*10];
          float f0 = (k0 < 10) ? xr[k0] : 0.f;
          float f1 = (k1 < 10) ? xr[k1] : 0.f;
          xp_s[p*20 + row] = cvtpk(f0, f1);
        }
      }
    }
    __syncthreads();   // hp_s / xp_s ready for next step
  }
}

// ---------------- stage C: fc2 MLP over out1 rows + nodevec = tanh(emb1*filt)
__global__ __launch_bounds__(256) void k_stageC(
    const float* __restrict__ out1, const float* __restrict__ emb1,
    const float* __restrict__ w1, const float* __restrict__ b1,
    const float* __restrict__ w2, const float* __restrict__ b2,
    const float* __restrict__ w3, const float* __restrict__ b3,
    float* __restrict__ ndv)
{
  int idx = blockIdx.x*256 + threadIdx.x;
  int m = idx % M_;
  int n = m % N_;
  float rv[64];
  const float4* r4 = (const float4*)(out1 + (size_t)idx*64);
  #pragma unroll
  for (int q=0;q<16;++q){ float4 v=r4[q]; rv[q*4]=v.x; rv[q*4+1]=v.y; rv[q*4+2]=v.z; rv[q*4+3]=v.w; }
  float h1[16];
  for (int u=0;u<16;++u){
    float a = b1[u];
    const float* wr = w1 + u*64;
    #pragma unroll
    for (int c=0;c<64;++c) a += rv[c]*wr[c];
    h1[u] = sigm(a);
  }
  float h2[2];
  #pragma unroll
  for (int v=0;v<2;++v){
    float a = b2[v];
    #pragma unroll
    for (int u=0;u<16;++u) a += h1[u]*w2[v*16+u];
    h2[v] = sigm(a);
  }
  #pragma unroll
  for (int d=0;d<10;++d){
    float f = b3[d] + h2[0]*w3[d*2] + h2[1]*w3[d*2+1];
    ndv[(size_t)idx*10 + d] = tanhf(emb1[n*10+d]*f);
  }
}

// ---------------- stage D: x_g = out1 + relu(V V^T) @ out1 per (t,b)
__global__ __launch_bounds__(256) void k_stageD(
    const float* __restrict__ ndv, const float* __restrict__ out1, float* __restrict__ xg)
{
  int tb = blockIdx.y;
  int tile = blockIdx.x;               // 0..4
  int tid = threadIdx.x;
  __shared__ __align__(16) float V_s[320*12];
  __shared__ __align__(16) float o_s[64*68];
  __shared__ __align__(16) float s_s[64*68];   // s_s[m][row-within-tile]

  for (int i = tid; i < 320*12; i += 256) {
    int n = i / 12, d = i - n*12;
    V_s[i] = (n < N_ && d < 10) ? ndv[((size_t)tb*N_ + n)*10 + d] : 0.f;
  }
  __syncthreads();

  const int sr  = tid & 63;            // s-phase: row within tile
  const int smg = tid >> 6;            // s-phase: m-group (16 m's)
  float vr[10];
  {
    const float* vp = &V_s[(tile*64 + sr)*12];
    #pragma unroll
    for (int d = 0; d < 10; ++d) vr[d] = vp[d];
  }
  const int rq = tid & 15, cq = tid >> 4;
  const int r4 = rq*4, c4 = cq*4;
  float acc[4][4];
  #pragma unroll
  for (int a=0;a<4;++a)
    #pragma unroll
    for (int b=0;b<4;++b) acc[a][b]=0.f;

  for (int mc = 0; mc < 320; mc += 64) {
    __syncthreads();
    for (int i = tid; i < 1024; i += 256) {
      int row = i >> 4, f4 = i & 15;
      int gm = mc + row;
      float4 v = make_float4(0.f,0.f,0.f,0.f);
      if (gm < N_) v = *(const float4*)&out1[((size_t)tb*N_ + gm)*64 + f4*4];
      *(float4*)&o_s[row*68 + f4*4] = v;
    }
    #pragma unroll
    for (int j = 0; j < 16; ++j) {
      int m = smg*16 + j;
      const float* vm = &V_s[(mc + m)*12];
      float s = vr[0]*vm[0] + vr[1]*vm[1] + vr[2]*vm[2] + vr[3]*vm[3] + vr[4]*vm[4]
              + vr[5]*vm[5] + vr[6]*vm[6] + vr[7]*vm[7] + vr[8]*vm[8] + vr[9]*vm[9];
      s_s[m*68 + sr] = fmaxf(s, 0.f);
    }
    __syncthreads();
    #pragma unroll 8
    for (int m = 0; m < 64; ++m) {
      float4 sv = *(const float4*)&s_s[m*68 + r4];
      float4 ov = *(const float4*)&o_s[m*68 + c4];
      acc[0][0] += sv.x*ov.x; acc[0][1] += sv.x*ov.y; acc[0][2] += sv.x*ov.z; acc[0][3] += sv.x*ov.w;
      acc[1][0] += sv.y*ov.x; acc[1][1] += sv.y*ov.y; acc[1][2] += sv.y*ov.z; acc[1][3] += sv.y*ov.w;
      acc[2][0] += sv.z*ov.x; acc[2][1] += sv.z*ov.y; acc[2][2] += sv.z*ov.z; acc[2][3] += sv.z*ov.w;
      acc[3][0] += sv.w*ov.x; acc[3][1] += sv.w*ov.y; acc[3][2] += sv.w*ov.z; acc[3][3] += sv.w*ov.w;
    }
  }

  #pragma unroll
  for (int rr = 0; rr < 4; ++rr) {
    int nrow = tile*64 + r4 + rr;
    if (nrow < N_) {
      size_t base = ((size_t)tb*N_ + nrow)*64 + c4;
      float4 o = *(const float4*)&out1[base];
      *(float4*)&xg[base] = make_float4(o.x+acc[rr][0], o.y+acc[rr][1],
                                        o.z+acc[rr][2], o.w+acc[rr][3]);
    }
  }
}

// ---------------- stage E: diff1 = x_g @ Wn + bn ; g2_in = [out1,diff1] @ diff_w^T + diff_b
__global__ __launch_bounds__(256) void k_stageE(
    const float* xg_in, const float* __restrict__ out1,
    const float* __restrict__ Wn, const float* __restrict__ bn,
    const float* __restrict__ dw, const float* __restrict__ db,
    float* xg_out)
{
  int n = blockIdx.y;
  int tile = blockIdx.x;     // 24 tiles of 32 tb-rows
  int tid = threadIdx.x;
  int r = tid >> 3, ug = tid & 7;
  __shared__ __align__(16) float x_s[32*68];
  __shared__ __align__(16) float o_s[32*68];
  __shared__ __align__(16) float W_s[64*68];    // transposed: [r_out][c]
  __shared__ __align__(16) float dw_s[64*132];
  __shared__ __align__(16) float d1_s[32*68];
  for (int idx=tid; idx<32*64; idx+=256){
    int row=idx>>6, c=idx&63;
    size_t g = ((size_t)(tile*32+row)*N_ + n)*64 + c;
    x_s[row*68+c] = xg_in[g];
    o_s[row*68+c] = out1[g];
  }
  for (int idx=tid; idx<4096; idx+=256){
    int c=idx>>6, u=idx&63;
    W_s[u*68+c] = Wn[(size_t)n*4096 + c*64 + u];
  }
  for (int idx=tid; idx<64*128; idx+=256){
    int u=idx>>7, c=idx&127;
    dw_s[u*132+c] = dw[u*128+c];
  }
  __syncthreads();
  float d1[8];
  #pragma unroll
  for (int uu=0;uu<8;++uu) d1[uu] = bn[n*64 + ug + 8*uu];
  for (int c=0;c<64;c+=4){
    float4 xc = *(const float4*)&x_s[r*68+c];
    #pragma unroll
    for (int uu=0;uu<8;++uu){
      float4 w = *(const float4*)&W_s[(ug+8*uu)*68 + c];
      d1[uu] += xc.x*w.x + xc.y*w.y + xc.z*w.z + xc.w*w.w;
    }
  }
  #pragma unroll
  for (int uu=0;uu<8;++uu) d1_s[r*68 + ug + 8*uu] = d1[uu];
  __syncthreads();
  float g2[8];
  #pragma unroll
  for (int uu=0;uu<8;++uu) g2[uu] = db[ug + 8*uu];
  for (int c=0;c<64;c+=4){
    float4 oc = *(const float4*)&o_s[r*68+c];
    float4 dc = *(const float4*)&d1_s[r*68+c];
    #pragma unroll
    for (int uu=0;uu<8;++uu){
      int u = ug + 8*uu;
      float4 w0 = *(const float4*)&dw_s[u*132 + c];
      float4 w1 = *(const float4*)&dw_s[u*132 + 64 + c];
      g2[uu] += oc.x*w0.x + oc.y*w0.y + oc.z*w0.z + oc.w*w0.w
              + dc.x*w1.x + dc.y*w1.y + dc.z*w1.z + dc.w*w1.w;
    }
  }
  size_t base = ((size_t)(tile*32+r)*N_ + n)*64;
  #pragma unroll
  for (int uu=0;uu<8;++uu) xg_out[base + ug + 8*uu] = g2[uu];
}

extern "C" void kernel_launch(void* const* d_in, const int* in_sizes, int n_in,
                              void* d_out, int out_size, void* d_ws, size_t ws_size,
                              hipStream_t stream)
{
  (void)in_sizes; (void)n_in; (void)out_size;
  const float* x    = (const float*)d_in[0];
  const float* emb1 = (const float*)d_in[1];
  const float* emb2 = (const float*)d_in[2];
  const float* xw1  = (const float*)d_in[3];
  const float* xb1  = (const float*)d_in[4];
  const float* xw2  = (const float*)d_in[5];
  const float* xb2  = (const float*)d_in[6];
  const float* xw3  = (const float*)d_in[7];
  const float* xb3  = (const float*)d_in[8];
  const float* fw1  = (const float*)d_in[9];
  const float* fb1  = (const float*)d_in[10];
  const float* fw2  = (const float*)d_in[11];
  const float* fb2  = (const float*)d_in[12];
  const float* fw3  = (const float*)d_in[13];
  const float* fb3  = (const float*)d_in[14];
  const float* c2w1 = (const float*)d_in[15];
  const float* c2b1 = (const float*)d_in[16];
  const float* c2w2 = (const float*)d_in[17];
  const float* c2b2 = (const float*)d_in[18];
  const float* c2w3 = (const float*)d_in[19];
  const float* c2b3 = (const float*)d_in[20];
  const float* g1wih= (const float*)d_in[21];
  const float* g1whh= (const float*)d_in[22];
  const float* g1bih= (const float*)d_in[23];
  const float* g1bhh= (const float*)d_in[24];
  const float* g2wih= (const float*)d_in[25];
  const float* g2whh= (const float*)d_in[26];
  const float* g2bih= (const float*)d_in[27];
  const float* g2bhh= (const float*)d_in[28];
  const float* wpool= (const float*)d_in[29];
  const float* bpool= (const float*)d_in[30];
  const float* dww  = (const float*)d_in[31];
  const float* dwb  = (const float*)d_in[32];
  float* out = (float*)d_out;

  float* ws = (float*)d_ws;
  float* g1_in = ws;                          // TM*10
  float* out1  = g1_in + (size_t)TM_*10;      // TM*64
  float* ndv   = out1 + (size_t)TM_*64;       // TM*10
  float* xg    = ndv + (size_t)TM_*10;        // TM*64
  float* Wn    = xg + (size_t)TM_*64;         // N*4096
  float* bn    = Wn + (size_t)N_*4096;        // N*64
  unsigned* Wpk2 = (unsigned*)(bn + (size_t)N_*64);   // 64*192
  unsigned* Wpk1 = Wpk2 + 64*192;                     // 38*192
  size_t need = ((size_t)((float*)(Wpk1 + 38*192) - ws)) * 4;
  if (ws_size < need) return;

  k_stageA<<<TM_/256, 256, 0, stream>>>(x, xw1,xb1,xw2,xb2,xw3,xb3, fw1,fb1,fw2,fb2,fw3,fb3, g1_in);
  k_wn<<<N_, 256, 0, stream>>>(emb2, wpool, bpool, Wn, bn);
  k_wpack<<<(64*192 + 38*192 + 255)/256, 256, 0, stream>>>(g2wih, g2whh, g1wih, g1whh, Wpk2, Wpk1);

  // GRU1: DIN=10 -> XP2=6
  k_gruD<6,true,false><<<M_/16, 256, 0, stream>>>(
      g1_in, Wpk1, g1bih, g1bhh, out1, nullptr);

  k_stageC<<<TM_/256, 256, 0, stream>>>(out1, emb1, c2w1,c2b1,c2w2,c2b2,c2w3,c2b3, ndv);
  k_stageD<<<dim3(5, T_*B_), 256, 0, stream>>>(ndv, out1, xg);
  k_stageE<<<dim3((T_*B_)/32, N_), 256, 0, stream>>>(xg, out1, Wn, bn, dww, dwb, xg);

  // GRU2: DIN=64 -> XP2=32
  k_gruD<32,false,true><<<M_/16, 256, 0, stream>>>(
      xg, Wpk2, g2bih, g2bhh, nullptr, out);
}

// Round 7
// 585.968 us; speedup vs baseline: 26.0359x; 1.1462x over previous
//
#include <hip/hip_runtime.h>
#include <math.h>

#define B_ 64
#define T_ 12
#define N_ 307
#define I_ 3
#define R_ 64
#define D_ 10
#define M_ (B_*N_)      // 19648
#define TM_ (T_*M_)     // 235776

__device__ __forceinline__ float sigm(float x){ return 1.f/(1.f+__expf(-x)); }

// pack two f32 -> one dword of 2 bf16 (lo = a, hi = b)
__device__ __forceinline__ unsigned cvtpk(float a, float b){
  unsigned r;
  asm("v_cvt_pk_bf16_f32 %0, %1, %2" : "=v"(r) : "v"(a), "v"(b));
  return r;
}
// acc += a.lo*b.lo + a.hi*b.hi  (bf16 inputs, f32 accumulate)
__device__ __forceinline__ void dot2(float& acc, unsigned a, unsigned b){
  asm("v_dot2_f32_bf16 %0, %1, %2, %0" : "+v"(acc) : "v"(a), "v"(b));
}

// ---------------- stage A: x-embedding MLP + feature gram + fc1 MLP -> g1_in [T][M][10]
__global__ __launch_bounds__(256) void k_stageA(
    const float* __restrict__ x,
    const float* __restrict__ xw1, const float* __restrict__ xb1,
    const float* __restrict__ xw2, const float* __restrict__ xb2,
    const float* __restrict__ xw3, const float* __restrict__ xb3,
    const float* __restrict__ fw1, const float* __restrict__ fb1,
    const float* __restrict__ fw2, const float* __restrict__ fb2,
    const float* __restrict__ fw3, const float* __restrict__ fb3,
    float* __restrict__ g1)
{
  int idx = blockIdx.x*256 + threadIdx.x;      // t*M + m, exact grid
  int t = idx / M_;
  int m = idx - t*M_;
  int b = m / N_;
  int n = m - b*N_;
  const float* xp = x + (((size_t)b*T_ + t)*N_ + n)*I_;
  float xv[3] = {xp[0], xp[1], xp[2]};
  float e[3][10];
  #pragma unroll
  for (int i=0;i<3;++i){
    float h1[16];
    #pragma unroll
    for (int u=0;u<16;++u) h1[u] = sigm(xv[i]*xw1[u] + xb1[u]);
    float h2[2];
    #pragma unroll
    for (int v=0;v<2;++v){
      float a = xb2[v];
      #pragma unroll
      for (int u=0;u<16;++u) a += h1[u]*xw2[v*16+u];
      h2[v] = sigm(a);
    }
    #pragma unroll
    for (int d=0;d<10;++d) e[i][d] = xb3[d] + h2[0]*xw3[d*2] + h2[1]*xw3[d*2+1];
  }
  float in1[3];
  #pragma unroll
  for (int j=0;j<3;++j){
    float acc = 0.f;
    #pragma unroll
    for (int i=0;i<3;++i){
      float s = 0.f;
      #pragma unroll
      for (int d=0;d<10;++d) s += e[j][d]*e[i][d];
      s = fmaxf(s, 0.f);
      acc += s*xv[i];
    }
    in1[j] = xv[j] + acc;
  }
  float h1[16];
  #pragma unroll
  for (int u=0;u<16;++u)
    h1[u] = sigm(fb1[u] + in1[0]*fw1[u*3] + in1[1]*fw1[u*3+1] + in1[2]*fw1[u*3+2]);
  float h2[2];
  #pragma unroll
  for (int v=0;v<2;++v){
    float a = fb2[v];
    #pragma unroll
    for (int u=0;u<16;++u) a += h1[u]*fw2[v*16+u];
    h2[v] = sigm(a);
  }
  float* gp = g1 + (size_t)idx*10;
  #pragma unroll
  for (int d=0;d<10;++d) gp[d] = fb3[d] + h2[0]*fw3[d*2] + h2[1]*fw3[d*2+1];
}

// ---------------- per-node mixing matrices: Wn [N][c*64+r], bn [N][64]
__global__ __launch_bounds__(256) void k_wn(
    const float* __restrict__ emb2, const float* __restrict__ wpool,
    const float* __restrict__ bpool, float* __restrict__ Wn, float* __restrict__ bn)
{
  int n = blockIdx.x; int tid = threadIdx.x;
  __shared__ float e_s[10];
  if (tid < 10) e_s[tid] = emb2[n*10 + tid];
  __syncthreads();
  #pragma unroll
  for (int e=0;e<16;++e){
    int i = e*256 + tid;            // 0..4095
    float a = 0.f;
    #pragma unroll
    for (int d=0;d<10;++d) a += e_s[d]*wpool[(size_t)d*4096 + i];
    Wn[(size_t)n*4096 + i] = a;
  }
  if (tid < 64){
    float a = 0.f;
    #pragma unroll
    for (int d=0;d<10;++d) a += e_s[d]*bpool[d*64 + tid];
    bn[n*64 + tid] = a;
  }
}

// ---------------- fused node weights: Wf[n][u][c] = sum_r Wn[n][c][r]*dwB[u][r],
// bf[n][u] = db[u] + sum_r bn[n][r]*dwB[u][r]   (dwB[u][r] = dw[u*128+64+r])
__global__ __launch_bounds__(256) void k_wf(
    const float* __restrict__ Wn, const float* __restrict__ bn,
    const float* __restrict__ dw, const float* __restrict__ db,
    float* __restrict__ Wf, float* __restrict__ bf)
{
  int n = blockIdx.x; int tid = threadIdx.x;
  __shared__ float WnS[64*68];    // [c][r]
  __shared__ float dwBT[64*68];   // [r][u]
  __shared__ float bn_s[64];
  for (int idx = tid; idx < 4096; idx += 256) {
    int c = idx >> 6, r = idx & 63;
    WnS[c*68 + r] = Wn[(size_t)n*4096 + idx];
  }
  for (int idx = tid; idx < 4096; idx += 256) {
    int u = idx >> 6, r = idx & 63;
    dwBT[r*68 + u] = dw[u*128 + 64 + r];
  }
  if (tid < 64) bn_s[tid] = bn[n*64 + tid];
  __syncthreads();
  int u = tid & 63, cg = tid >> 6;
  #pragma unroll
  for (int j = 0; j < 16; ++j) {
    int c = cg*16 + j;
    float acc = 0.f;
    #pragma unroll 8
    for (int r = 0; r < 64; ++r) acc += WnS[c*68 + r] * dwBT[r*68 + u];
    Wf[(size_t)n*4096 + u*64 + c] = acc;
  }
  if (tid < 64) {
    float acc = db[tid];
    #pragma unroll 8
    for (int r = 0; r < 64; ++r) acc += bn_s[r] * dwBT[r*68 + tid];
    bf[n*64 + tid] = acc;
  }
}

// ---------------- pack GRU weights to bf16 pairs: Wpk[pair][192], pair p = (k=2p, 2p+1)
__global__ __launch_bounds__(256) void k_wpack(
    const float* __restrict__ wih2, const float* __restrict__ whh2,
    const float* __restrict__ wih1, const float* __restrict__ whh1,
    unsigned* __restrict__ Wpk2, unsigned* __restrict__ Wpk1)
{
  int i = blockIdx.x*256 + threadIdx.x;
  if (i < 64*192) {
    int p = i / 192, wr = i - (i/192)*192;
    int k0 = 2*p, k1 = 2*p + 1;
    float f0 = (k0 < 64) ? whh2[wr*64 + k0] : wih2[wr*64 + (k0-64)];
    float f1 = (k1 < 64) ? whh2[wr*64 + k1] : wih2[wr*64 + (k1-64)];
    Wpk2[i] = cvtpk(f0, f1);
  }
  int j = i - 64*192;
  if (j >= 0 && j < 38*192) {
    int p = j / 192, wr = j - (j/192)*192;
    int k0 = 2*p, k1 = 2*p + 1;
    float f0 = (k0 < 64) ? whh1[wr*64 + k0] : ((k0-64) < 10 ? wih1[wr*10 + (k0-64)] : 0.f);
    float f1 = (k1 < 64) ? whh1[wr*64 + k1] : ((k1-64) < 10 ? wih1[wr*10 + (k1-64)] : 0.f);
    Wpk1[j] = cvtpk(f0, f1);
  }
}

// ---------------- persistent GRU scan with packed-bf16 dot2 math.
template<int XP2, bool WSEQ, bool WFIN>
__global__ __launch_bounds__(256) void k_gruD(
    const float* __restrict__ xseq,   // [T][M][DIN] fp32
    const unsigned* __restrict__ Wpk, // [(32+XP2)*192]
    const float* __restrict__ bih, const float* __restrict__ bhh,
    float* __restrict__ oseq,         // [T][M][64]   (if WSEQ)
    float* __restrict__ ofin)         // [B][T][N][64] (if WFIN)
{
  constexpr int P2 = 32 + XP2;
  __shared__ __align__(16) unsigned W_s[P2*192];
  __shared__ __align__(16) unsigned hp_s[32*20];
  __shared__ __align__(16) unsigned xp_s[XP2*20];
  const int tid = threadIdx.x;
  const int row0 = blockIdx.x * 16;
  const int tr = tid & 3, u = tid >> 2;
  const int r4 = tr*4;

  for (int i = tid; i < P2*192; i += 256) W_s[i] = Wpk[i];
  for (int i = tid; i < 32*20; i += 256) hp_s[i] = 0u;

  const float brc = bih[u]     + bhh[u];
  const float bzc = bih[64+u]  + bhh[64+u];
  const float bxn = bih[128+u];
  const float bhn = bhh[128+u];

  size_t obase[4];
  #pragma unroll
  for (int rr=0;rr<4;++rr){
    int g = row0 + r4 + rr;
    if (WFIN){
      int bb = g / N_, nn = g - bb*N_;
      obase[rr] = (((size_t)bb*T_)*N_ + nn)*64;
    } else {
      obase[rr] = (size_t)g*64;
    }
  }
  float hreg[4] = {0.f, 0.f, 0.f, 0.f};

  if (XP2 == 32) {
    for (int idx = tid; idx < 512; idx += 256) {
      int row = idx >> 5, p = idx & 31;
      const float2 v = *(const float2*)&xseq[((size_t)(row0+row))*64 + 2*p];
      xp_s[p*20 + row] = cvtpk(v.x, v.y);
    }
  } else {
    if (tid < 16*XP2) {
      int row = tid / XP2, p = tid - (tid/XP2)*XP2;
      int k0 = 2*p, k1 = 2*p + 1;
      const float* xr = &xseq[((size_t)(row0+row))*10];
      float f0 = (k0 < 10) ? xr[k0] : 0.f;
      float f1 = (k1 < 10) ? xr[k1] : 0.f;
      xp_s[p*20 + row] = cvtpk(f0, f1);
    }
  }
  __syncthreads();

  for (int t = 0; t < T_; ++t) {
    float ar[4]={0,0,0,0}, az[4]={0,0,0,0}, anh[4]={0,0,0,0}, anx[4]={0,0,0,0};

    #pragma unroll 4
    for (int p = 0; p < 32; ++p) {
      uint4 a = *(const uint4*)&hp_s[p*20 + r4];
      unsigned wr_ = W_s[p*192 + u];
      unsigned wz_ = W_s[p*192 + 64 + u];
      unsigned wn_ = W_s[p*192 + 128 + u];
      dot2(ar[0], a.x, wr_); dot2(ar[1], a.y, wr_); dot2(ar[2], a.z, wr_); dot2(ar[3], a.w, wr_);
      dot2(az[0], a.x, wz_); dot2(az[1], a.y, wz_); dot2(az[2], a.z, wz_); dot2(az[3], a.w, wz_);
      dot2(anh[0], a.x, wn_); dot2(anh[1], a.y, wn_); dot2(anh[2], a.z, wn_); dot2(anh[3], a.w, wn_);
    }
    #pragma unroll 4
    for (int p = 0; p < XP2; ++p) {
      uint4 a = *(const uint4*)&xp_s[p*20 + r4];
      unsigned wr_ = W_s[(32+p)*192 + u];
      unsigned wz_ = W_s[(32+p)*192 + 64 + u];
      unsigned wn_ = W_s[(32+p)*192 + 128 + u];
      dot2(ar[0], a.x, wr_); dot2(ar[1], a.y, wr_); dot2(ar[2], a.z, wr_); dot2(ar[3], a.w, wr_);
      dot2(az[0], a.x, wz_); dot2(az[1], a.y, wz_); dot2(az[2], a.z, wz_); dot2(az[3], a.w, wz_);
      dot2(anx[0], a.x, wn_); dot2(anx[1], a.y, wn_); dot2(anx[2], a.z, wn_); dot2(anx[3], a.w, wn_);
    }

    float o_new[4];
    #pragma unroll
    for (int rr=0;rr<4;++rr){
      float rg = sigm(ar[rr] + brc);
      float zg = sigm(az[rr] + bzc);
      float ng = tanhf(anx[rr] + bxn + rg*(anh[rr] + bhn));
      o_new[rr] = (1.f - zg)*ng + zg*hreg[rr];
      hreg[rr] = o_new[rr];
    }
    #pragma unroll
    for (int rr=0;rr<4;++rr){
      if (WSEQ) oseq[(size_t)t*M_*64 + obase[rr] + u] = o_new[rr];
      if (WFIN) ofin[obase[rr] + (size_t)t*N_*64 + u] = o_new[rr];
    }
    unsigned pk[4];
    #pragma unroll
    for (int rr=0;rr<4;++rr){
      float pr = __shfl_xor(o_new[rr], 4);
      pk[rr] = cvtpk(o_new[rr], pr);
    }
    __syncthreads();
    if ((u & 1) == 0) {
      #pragma unroll
      for (int rr=0;rr<4;++rr) hp_s[(u>>1)*20 + r4 + rr] = pk[rr];
    }
    if (t+1 < T_) {
      if (XP2 == 32) {
        for (int idx = tid; idx < 512; idx += 256) {
          int row = idx >> 5, p = idx & 31;
          const float2 v = *(const float2*)&xseq[((size_t)(t+1)*M_ + row0+row)*64 + 2*p];
          xp_s[p*20 + row] = cvtpk(v.x, v.y);
        }
      } else {
        if (tid < 16*XP2) {
          int row = tid / XP2, p = tid - (tid/XP2)*XP2;
          int k0 = 2*p, k1 = 2*p + 1;
          const float* xr = &xseq[((size_t)(t+1)*M_ + row0+row)*10];
          float f0 = (k0 < 10) ? xr[k0] : 0.f;
          float f1 = (k1 < 10) ? xr[k1] : 0.f;
          xp_s[p*20 + row] = cvtpk(f0, f1);
        }
      }
    }
    __syncthreads();
  }
}

// ---------------- stage C: fc2 MLP over out1 rows + nodevec = tanh(emb1*filt)
__global__ __launch_bounds__(256) void k_stageC(
    const float* __restrict__ out1, const float* __restrict__ emb1,
    const float* __restrict__ w1, const float* __restrict__ b1,
    const float* __restrict__ w2, const float* __restrict__ b2,
    const float* __restrict__ w3, const float* __restrict__ b3,
    float* __restrict__ ndv)
{
  int idx = blockIdx.x*256 + threadIdx.x;
  int m = idx % M_;
  int n = m % N_;
  float rv[64];
  const float4* r4 = (const float4*)(out1 + (size_t)idx*64);
  #pragma unroll
  for (int q=0;q<16;++q){ float4 v=r4[q]; rv[q*4]=v.x; rv[q*4+1]=v.y; rv[q*4+2]=v.z; rv[q*4+3]=v.w; }
  float h1[16];
  for (int u=0;u<16;++u){
    float a = b1[u];
    const float* wr = w1 + u*64;
    #pragma unroll
    for (int c=0;c<64;++c) a += rv[c]*wr[c];
    h1[u] = sigm(a);
  }
  float h2[2];
  #pragma unroll
  for (int v=0;v<2;++v){
    float a = b2[v];
    #pragma unroll
    for (int u=0;u<16;++u) a += h1[u]*w2[v*16+u];
    h2[v] = sigm(a);
  }
  #pragma unroll
  for (int d=0;d<10;++d){
    float f = b3[d] + h2[0]*w3[d*2] + h2[1]*w3[d*2+1];
    ndv[(size_t)idx*10 + d] = tanhf(emb1[n*10+d]*f);
  }
}

// ---------------- stage D: x_g = out1 + relu(V V^T) @ out1 per (t,b)
__global__ __launch_bounds__(256) void k_stageD(
    const float* __restrict__ ndv, const float* __restrict__ out1, float* __restrict__ xg)
{
  int tb = blockIdx.y;
  int tile = blockIdx.x;               // 0..4
  int tid = threadIdx.x;
  __shared__ __align__(16) float V_s[320*12];
  __shared__ __align__(16) float o_s[64*68];
  __shared__ __align__(16) float s_s[64*68];   // s_s[m][row-within-tile]

  for (int i = tid; i < 320*12; i += 256) {
    int n = i / 12, d = i - n*12;
    V_s[i] = (n < N_ && d < 10) ? ndv[((size_t)tb*N_ + n)*10 + d] : 0.f;
  }
  __syncthreads();

  const int sr  = tid & 63;            // s-phase: row within tile
  const int smg = tid >> 6;            // s-phase: m-group (16 m's)
  float vr[10];
  {
    const float* vp = &V_s[(tile*64 + sr)*12];
    #pragma unroll
    for (int d = 0; d < 10; ++d) vr[d] = vp[d];
  }
  const int rq = tid & 15, cq = tid >> 4;
  const int r4 = rq*4, c4 = cq*4;
  float acc[4][4];
  #pragma unroll
  for (int a=0;a<4;++a)
    #pragma unroll
    for (int b=0;b<4;++b) acc[a][b]=0.f;

  for (int mc = 0; mc < 320; mc += 64) {
    __syncthreads();
    for (int i = tid; i < 1024; i += 256) {
      int row = i >> 4, f4 = i & 15;
      int gm = mc + row;
      float4 v = make_float4(0.f,0.f,0.f,0.f);
      if (gm < N_) v = *(const float4*)&out1[((size_t)tb*N_ + gm)*64 + f4*4];
      *(float4*)&o_s[row*68 + f4*4] = v;
    }
    #pragma unroll
    for (int j = 0; j < 16; ++j) {
      int m = smg*16 + j;
      const float* vm = &V_s[(mc + m)*12];
      float s = vr[0]*vm[0] + vr[1]*vm[1] + vr[2]*vm[2] + vr[3]*vm[3] + vr[4]*vm[4]
              + vr[5]*vm[5] + vr[6]*vm[6] + vr[7]*vm[7] + vr[8]*vm[8] + vr[9]*vm[9];
      s_s[m*68 + sr] = fmaxf(s, 0.f);
    }
    __syncthreads();
    #pragma unroll 8
    for (int m = 0; m < 64; ++m) {
      float4 sv = *(const float4*)&s_s[m*68 + r4];
      float4 ov = *(const float4*)&o_s[m*68 + c4];
      acc[0][0] += sv.x*ov.x; acc[0][1] += sv.x*ov.y; acc[0][2] += sv.x*ov.z; acc[0][3] += sv.x*ov.w;
      acc[1][0] += sv.y*ov.x; acc[1][1] += sv.y*ov.y; acc[1][2] += sv.y*ov.z; acc[1][3] += sv.y*ov.w;
      acc[2][0] += sv.z*ov.x; acc[2][1] += sv.z*ov.y; acc[2][2] += sv.z*ov.z; acc[2][3] += sv.z*ov.w;
      acc[3][0] += sv.w*ov.x; acc[3][1] += sv.w*ov.y; acc[3][2] += sv.w*ov.z; acc[3][3] += sv.w*ov.w;
    }
  }

  #pragma unroll
  for (int rr = 0; rr < 4; ++rr) {
    int nrow = tile*64 + r4 + rr;
    if (nrow < N_) {
      size_t base = ((size_t)tb*N_ + nrow)*64 + c4;
      float4 o = *(const float4*)&out1[base];
      *(float4*)&xg[base] = make_float4(o.x+acc[rr][0], o.y+acc[rr][1],
                                        o.z+acc[rr][2], o.w+acc[rr][3]);
    }
  }
}

// ---------------- stage E (fused): g2 = o@dwA^T + x@Wf[n] + bf[n]
// grid (12, N): 64 tb-rows x node. thread: r=tid>>3 -> rows r, r+32; ug=tid&7 -> 8 units.
// All main-loop LDS reads: 8 distinct stride-68 float4 x 8-way broadcast -> conflict-free.
__global__ __launch_bounds__(256) void k_stageE(
    const float* xg_in, const float* __restrict__ out1,
    const float* __restrict__ Wf, const float* __restrict__ dw,
    const float* __restrict__ bf,
    float* xg_out)
{
  int n = blockIdx.y;
  int tile = blockIdx.x;     // 12 tiles of 64 tb-rows
  int tid = threadIdx.x;
  int r = tid >> 3, ug = tid & 7;
  __shared__ __align__(16) float x_s[64*68];
  __shared__ __align__(16) float o_s[64*68];
  __shared__ __align__(16) float Wf_s[64*68];   // [u][c]
  __shared__ __align__(16) float dA_s[64*68];   // [u][c]
  __shared__ float bf_s[64];
  for (int idx = tid; idx < 64*64; idx += 256) {
    int row = idx >> 6, c = idx & 63;
    size_t g = ((size_t)(tile*64+row)*N_ + n)*64 + c;
    x_s[row*68+c] = xg_in[g];
    o_s[row*68+c] = out1[g];
  }
  for (int idx = tid; idx < 4096; idx += 256) {
    int u = idx >> 6, c = idx & 63;
    Wf_s[u*68+c] = Wf[(size_t)n*4096 + idx];
    dA_s[u*68+c] = dw[u*128 + c];
  }
  if (tid < 64) bf_s[tid] = bf[n*64 + tid];
  __syncthreads();

  float g2a[8], g2b[8];
  #pragma unroll
  for (int uu=0;uu<8;++uu){ g2a[uu] = bf_s[ug+8*uu]; g2b[uu] = g2a[uu]; }

  for (int c = 0; c < 64; c += 4) {
    float4 xa = *(const float4*)&x_s[r*68 + c];
    float4 xb = *(const float4*)&x_s[(r+32)*68 + c];
    float4 oa = *(const float4*)&o_s[r*68 + c];
    float4 ob = *(const float4*)&o_s[(r+32)*68 + c];
    #pragma unroll
    for (int uu=0;uu<8;++uu){
      int u = ug + 8*uu;
      float4 wf = *(const float4*)&Wf_s[u*68 + c];
      float4 da = *(const float4*)&dA_s[u*68 + c];
      g2a[uu] += oa.x*da.x + oa.y*da.y + oa.z*da.z + oa.w*da.w
               + xa.x*wf.x + xa.y*wf.y + xa.z*wf.z + xa.w*wf.w;
      g2b[uu] += ob.x*da.x + ob.y*da.y + ob.z*da.z + ob.w*da.w
               + xb.x*wf.x + xb.y*wf.y + xb.z*wf.z + xb.w*wf.w;
    }
  }
  size_t ba = ((size_t)(tile*64+r)*N_ + n)*64;
  size_t bb = ((size_t)(tile*64+r+32)*N_ + n)*64;
  #pragma unroll
  for (int uu=0;uu<8;++uu){
    xg_out[ba + ug + 8*uu] = g2a[uu];
    xg_out[bb + ug + 8*uu] = g2b[uu];
  }
}

extern "C" void kernel_launch(void* const* d_in, const int* in_sizes, int n_in,
                              void* d_out, int out_size, void* d_ws, size_t ws_size,
                              hipStream_t stream)
{
  (void)in_sizes; (void)n_in; (void)out_size;
  const float* x    = (const float*)d_in[0];
  const float* emb1 = (const float*)d_in[1];
  const float* emb2 = (const float*)d_in[2];
  const float* xw1  = (const float*)d_in[3];
  const float* xb1  = (const float*)d_in[4];
  const float* xw2  = (const float*)d_in[5];
  const float* xb2  = (const float*)d_in[6];
  const float* xw3  = (const float*)d_in[7];
  const float* xb3  = (const float*)d_in[8];
  const float* fw1  = (const float*)d_in[9];
  const float* fb1  = (const float*)d_in[10];
  const float* fw2  = (const float*)d_in[11];
  const float* fb2  = (const float*)d_in[12];
  const float* fw3  = (const float*)d_in[13];
  const float* fb3  = (const float*)d_in[14];
  const float* c2w1 = (const float*)d_in[15];
  const float* c2b1 = (const float*)d_in[16];
  const float* c2w2 = (const float*)d_in[17];
  const float* c2b2 = (const float*)d_in[18];
  const float* c2w3 = (const float*)d_in[19];
  const float* c2b3 = (const float*)d_in[20];
  const float* g1wih= (const float*)d_in[21];
  const float* g1whh= (const float*)d_in[22];
  const float* g1bih= (const float*)d_in[23];
  const float* g1bhh= (const float*)d_in[24];
  const float* g2wih= (const float*)d_in[25];
  const float* g2whh= (const float*)d_in[26];
  const float* g2bih= (const float*)d_in[27];
  const float* g2bhh= (const float*)d_in[28];
  const float* wpool= (const float*)d_in[29];
  const float* bpool= (const float*)d_in[30];
  const float* dww  = (const float*)d_in[31];
  const float* dwb  = (const float*)d_in[32];
  float* out = (float*)d_out;

  float* ws = (float*)d_ws;
  float* g1_in = ws;                          // TM*10
  float* out1  = g1_in + (size_t)TM_*10;      // TM*64
  float* ndv   = out1 + (size_t)TM_*64;       // TM*10
  float* xg    = ndv + (size_t)TM_*10;        // TM*64
  float* Wn    = xg + (size_t)TM_*64;         // N*4096
  float* bn    = Wn + (size_t)N_*4096;        // N*64
  float* Wf    = bn + (size_t)N_*64;          // N*4096
  float* bf    = Wf + (size_t)N_*4096;        // N*64
  unsigned* Wpk2 = (unsigned*)(bf + (size_t)N_*64);   // 64*192
  unsigned* Wpk1 = Wpk2 + 64*192;                     // 38*192
  size_t need = ((size_t)((float*)(Wpk1 + 38*192) - ws)) * 4;
  if (ws_size < need) return;

  k_stageA<<<TM_/256, 256, 0, stream>>>(x, xw1,xb1,xw2,xb2,xw3,xb3, fw1,fb1,fw2,fb2,fw3,fb3, g1_in);
  k_wn<<<N_, 256, 0, stream>>>(emb2, wpool, bpool, Wn, bn);
  k_wf<<<N_, 256, 0, stream>>>(Wn, bn, dww, dwb, Wf, bf);
  k_wpack<<<(64*192 + 38*192 + 255)/256, 256, 0, stream>>>(g2wih, g2whh, g1wih, g1whh, Wpk2, Wpk1);

  // GRU1: DIN=10 -> XP2=6
  k_gruD<6,true,false><<<M_/16, 256, 0, stream>>>(
      g1_in, Wpk1, g1bih, g1bhh, out1, nullptr);

  k_stageC<<<TM_/256, 256, 0, stream>>>(out1, emb1, c2w1,c2b1,c2w2,c2b2,c2w3,c2b3, ndv);
  k_stageD<<<dim3(5, T_*B_), 256, 0, stream>>>(ndv, out1, xg);
  k_stageE<<<dim3(12, N_), 256, 0, stream>>>(xg, out1, Wf, dww, bf, xg);

  // GRU2: DIN=64 -> XP2=32
  k_gruD<32,false,true><<<M_/16, 256, 0, stream>>>(
      xg, Wpk2, g2bih, g2bhh, nullptr, out);
}

// Round 8
// 544.052 us; speedup vs baseline: 28.0418x; 1.0770x over previous
//
#include <hip/hip_runtime.h>
#include <math.h>

#define B_ 64
#define T_ 12
#define N_ 307
#define I_ 3
#define R_ 64
#define D_ 10
#define M_ (B_*N_)      // 19648
#define TM_ (T_*M_)     // 235776

__device__ __forceinline__ float sigm(float x){ return 1.f/(1.f+__expf(-x)); }

// pack two f32 -> one dword of 2 bf16 (lo = a, hi = b)
__device__ __forceinline__ unsigned cvtpk(float a, float b){
  unsigned r;
  asm("v_cvt_pk_bf16_f32 %0, %1, %2" : "=v"(r) : "v"(a), "v"(b));
  return r;
}
// acc += a.lo*b.lo + a.hi*b.hi  (bf16 inputs, f32 accumulate)
__device__ __forceinline__ void dot2(float& acc, unsigned a, unsigned b){
  asm("v_dot2_f32_bf16 %0, %1, %2, %0" : "+v"(acc) : "v"(a), "v"(b));
}
// pack two f32 -> one dword of 2 f16 (RTZ)
__device__ __forceinline__ unsigned pkh(float a, float b){
  unsigned r;
  asm("v_cvt_pkrtz_f16_f32 %0, %1, %2" : "=v"(r) : "v"(a), "v"(b));
  return r;
}
// acc += a.lo*b.lo + a.hi*b.hi  (f16 inputs, f32 accumulate)
__device__ __forceinline__ void doth(float& acc, unsigned a, unsigned b){
  asm("v_dot2_f32_f16 %0, %1, %2, %0" : "+v"(acc) : "v"(a), "v"(b));
}

// ---------------- stage A: x-embedding MLP + feature gram + fc1 MLP -> g1_in [T][M][10]
__global__ __launch_bounds__(256) void k_stageA(
    const float* __restrict__ x,
    const float* __restrict__ xw1, const float* __restrict__ xb1,
    const float* __restrict__ xw2, const float* __restrict__ xb2,
    const float* __restrict__ xw3, const float* __restrict__ xb3,
    const float* __restrict__ fw1, const float* __restrict__ fb1,
    const float* __restrict__ fw2, const float* __restrict__ fb2,
    const float* __restrict__ fw3, const float* __restrict__ fb3,
    float* __restrict__ g1)
{
  int idx = blockIdx.x*256 + threadIdx.x;      // t*M + m, exact grid
  int t = idx / M_;
  int m = idx - t*M_;
  int b = m / N_;
  int n = m - b*N_;
  const float* xp = x + (((size_t)b*T_ + t)*N_ + n)*I_;
  float xv[3] = {xp[0], xp[1], xp[2]};
  float e[3][10];
  #pragma unroll
  for (int i=0;i<3;++i){
    float h1[16];
    #pragma unroll
    for (int u=0;u<16;++u) h1[u] = sigm(xv[i]*xw1[u] + xb1[u]);
    float h2[2];
    #pragma unroll
    for (int v=0;v<2;++v){
      float a = xb2[v];
      #pragma unroll
      for (int u=0;u<16;++u) a += h1[u]*xw2[v*16+u];
      h2[v] = sigm(a);
    }
    #pragma unroll
    for (int d=0;d<10;++d) e[i][d] = xb3[d] + h2[0]*xw3[d*2] + h2[1]*xw3[d*2+1];
  }
  float in1[3];
  #pragma unroll
  for (int j=0;j<3;++j){
    float acc = 0.f;
    #pragma unroll
    for (int i=0;i<3;++i){
      float s = 0.f;
      #pragma unroll
      for (int d=0;d<10;++d) s += e[j][d]*e[i][d];
      s = fmaxf(s, 0.f);
      acc += s*xv[i];
    }
    in1[j] = xv[j] + acc;
  }
  float h1[16];
  #pragma unroll
  for (int u=0;u<16;++u)
    h1[u] = sigm(fb1[u] + in1[0]*fw1[u*3] + in1[1]*fw1[u*3+1] + in1[2]*fw1[u*3+2]);
  float h2[2];
  #pragma unroll
  for (int v=0;v<2;++v){
    float a = fb2[v];
    #pragma unroll
    for (int u=0;u<16;++u) a += h1[u]*fw2[v*16+u];
    h2[v] = sigm(a);
  }
  float* gp = g1 + (size_t)idx*10;
  #pragma unroll
  for (int d=0;d<10;++d) gp[d] = fb3[d] + h2[0]*fw3[d*2] + h2[1]*fw3[d*2+1];
}

// ---------------- per-node mixing matrices: Wn [N][c*64+r], bn [N][64]
__global__ __launch_bounds__(256) void k_wn(
    const float* __restrict__ emb2, const float* __restrict__ wpool,
    const float* __restrict__ bpool, float* __restrict__ Wn, float* __restrict__ bn)
{
  int n = blockIdx.x; int tid = threadIdx.x;
  __shared__ float e_s[10];
  if (tid < 10) e_s[tid] = emb2[n*10 + tid];
  __syncthreads();
  #pragma unroll
  for (int e=0;e<16;++e){
    int i = e*256 + tid;            // 0..4095
    float a = 0.f;
    #pragma unroll
    for (int d=0;d<10;++d) a += e_s[d]*wpool[(size_t)d*4096 + i];
    Wn[(size_t)n*4096 + i] = a;
  }
  if (tid < 64){
    float a = 0.f;
    #pragma unroll
    for (int d=0;d<10;++d) a += e_s[d]*bpool[d*64 + tid];
    bn[n*64 + tid] = a;
  }
}

// ---------------- fused node weights: Wf[n][u][c] = sum_r Wn[n][c][r]*dwB[u][r],
// bf[n][u] = db[u] + sum_r bn[n][r]*dwB[u][r]   (dwB[u][r] = dw[u*128+64+r])
__global__ __launch_bounds__(256) void k_wf(
    const float* __restrict__ Wn, const float* __restrict__ bn,
    const float* __restrict__ dw, const float* __restrict__ db,
    float* __restrict__ Wf, float* __restrict__ bf)
{
  int n = blockIdx.x; int tid = threadIdx.x;
  __shared__ float WnS[64*68];    // [c][r]
  __shared__ float dwBT[64*68];   // [r][u]
  __shared__ float bn_s[64];
  for (int idx = tid; idx < 4096; idx += 256) {
    int c = idx >> 6, r = idx & 63;
    WnS[c*68 + r] = Wn[(size_t)n*4096 + idx];
  }
  for (int idx = tid; idx < 4096; idx += 256) {
    int u = idx >> 6, r = idx & 63;
    dwBT[r*68 + u] = dw[u*128 + 64 + r];
  }
  if (tid < 64) bn_s[tid] = bn[n*64 + tid];
  __syncthreads();
  int u = tid & 63, cg = tid >> 6;
  #pragma unroll
  for (int j = 0; j < 16; ++j) {
    int c = cg*16 + j;
    float acc = 0.f;
    #pragma unroll 8
    for (int r = 0; r < 64; ++r) acc += WnS[c*68 + r] * dwBT[r*68 + u];
    Wf[(size_t)n*4096 + u*64 + c] = acc;
  }
  if (tid < 64) {
    float acc = db[tid];
    #pragma unroll 8
    for (int r = 0; r < 64; ++r) acc += bn_s[r] * dwBT[r*68 + tid];
    bf[n*64 + tid] = acc;
  }
}

// ---------------- pack GRU weights to bf16 pairs: Wpk[pair][192], pair p = (k=2p, 2p+1)
__global__ __launch_bounds__(256) void k_wpack(
    const float* __restrict__ wih2, const float* __restrict__ whh2,
    const float* __restrict__ wih1, const float* __restrict__ whh1,
    unsigned* __restrict__ Wpk2, unsigned* __restrict__ Wpk1)
{
  int i = blockIdx.x*256 + threadIdx.x;
  if (i < 64*192) {
    int p = i / 192, wr = i - (i/192)*192;
    int k0 = 2*p, k1 = 2*p + 1;
    float f0 = (k0 < 64) ? whh2[wr*64 + k0] : wih2[wr*64 + (k0-64)];
    float f1 = (k1 < 64) ? whh2[wr*64 + k1] : wih2[wr*64 + (k1-64)];
    Wpk2[i] = cvtpk(f0, f1);
  }
  int j = i - 64*192;
  if (j >= 0 && j < 38*192) {
    int p = j / 192, wr = j - (j/192)*192;
    int k0 = 2*p, k1 = 2*p + 1;
    float f0 = (k0 < 64) ? whh1[wr*64 + k0] : ((k0-64) < 10 ? wih1[wr*10 + (k0-64)] : 0.f);
    float f1 = (k1 < 64) ? whh1[wr*64 + k1] : ((k1-64) < 10 ? wih1[wr*10 + (k1-64)] : 0.f);
    Wpk1[j] = cvtpk(f0, f1);
  }
}

// ---------------- persistent GRU scan with packed-bf16 dot2 math.
template<int XP2, bool WSEQ, bool WFIN>
__global__ __launch_bounds__(256) void k_gruD(
    const float* __restrict__ xseq,   // [T][M][DIN] fp32
    const unsigned* __restrict__ Wpk, // [(32+XP2)*192]
    const float* __restrict__ bih, const float* __restrict__ bhh,
    float* __restrict__ oseq,         // [T][M][64]   (if WSEQ)
    float* __restrict__ ofin)         // [B][T][N][64] (if WFIN)
{
  constexpr int P2 = 32 + XP2;
  __shared__ __align__(16) unsigned W_s[P2*192];
  __shared__ __align__(16) unsigned hp_s[32*20];
  __shared__ __align__(16) unsigned xp_s[XP2*20];
  const int tid = threadIdx.x;
  const int row0 = blockIdx.x * 16;
  const int tr = tid & 3, u = tid >> 2;
  const int r4 = tr*4;

  for (int i = tid; i < P2*192; i += 256) W_s[i] = Wpk[i];
  for (int i = tid; i < 32*20; i += 256) hp_s[i] = 0u;

  const float brc = bih[u]     + bhh[u];
  const float bzc = bih[64+u]  + bhh[64+u];
  const float bxn = bih[128+u];
  const float bhn = bhh[128+u];

  size_t obase[4];
  #pragma unroll
  for (int rr=0;rr<4;++rr){
    int g = row0 + r4 + rr;
    if (WFIN){
      int bb = g / N_, nn = g - bb*N_;
      obase[rr] = (((size_t)bb*T_)*N_ + nn)*64;
    } else {
      obase[rr] = (size_t)g*64;
    }
  }
  float hreg[4] = {0.f, 0.f, 0.f, 0.f};

  if (XP2 == 32) {
    for (int idx = tid; idx < 512; idx += 256) {
      int row = idx >> 5, p = idx & 31;
      const float2 v = *(const float2*)&xseq[((size_t)(row0+row))*64 + 2*p];
      xp_s[p*20 + row] = cvtpk(v.x, v.y);
    }
  } else {
    if (tid < 16*XP2) {
      int row = tid / XP2, p = tid - (tid/XP2)*XP2;
      int k0 = 2*p, k1 = 2*p + 1;
      const float* xr = &xseq[((size_t)(row0+row))*10];
      float f0 = (k0 < 10) ? xr[k0] : 0.f;
      float f1 = (k1 < 10) ? xr[k1] : 0.f;
      xp_s[p*20 + row] = cvtpk(f0, f1);
    }
  }
  __syncthreads();

  for (int t = 0; t < T_; ++t) {
    float ar[4]={0,0,0,0}, az[4]={0,0,0,0}, anh[4]={0,0,0,0}, anx[4]={0,0,0,0};

    #pragma unroll 4
    for (int p = 0; p < 32; ++p) {
      uint4 a = *(const uint4*)&hp_s[p*20 + r4];
      unsigned wr_ = W_s[p*192 + u];
      unsigned wz_ = W_s[p*192 + 64 + u];
      unsigned wn_ = W_s[p*192 + 128 + u];
      dot2(ar[0], a.x, wr_); dot2(ar[1], a.y, wr_); dot2(ar[2], a.z, wr_); dot2(ar[3], a.w, wr_);
      dot2(az[0], a.x, wz_); dot2(az[1], a.y, wz_); dot2(az[2], a.z, wz_); dot2(az[3], a.w, wz_);
      dot2(anh[0], a.x, wn_); dot2(anh[1], a.y, wn_); dot2(anh[2], a.z, wn_); dot2(anh[3], a.w, wn_);
    }
    #pragma unroll 4
    for (int p = 0; p < XP2; ++p) {
      uint4 a = *(const uint4*)&xp_s[p*20 + r4];
      unsigned wr_ = W_s[(32+p)*192 + u];
      unsigned wz_ = W_s[(32+p)*192 + 64 + u];
      unsigned wn_ = W_s[(32+p)*192 + 128 + u];
      dot2(ar[0], a.x, wr_); dot2(ar[1], a.y, wr_); dot2(ar[2], a.z, wr_); dot2(ar[3], a.w, wr_);
      dot2(az[0], a.x, wz_); dot2(az[1], a.y, wz_); dot2(az[2], a.z, wz_); dot2(az[3], a.w, wz_);
      dot2(anx[0], a.x, wn_); dot2(anx[1], a.y, wn_); dot2(anx[2], a.z, wn_); dot2(anx[3], a.w, wn_);
    }

    float o_new[4];
    #pragma unroll
    for (int rr=0;rr<4;++rr){
      float rg = sigm(ar[rr] + brc);
      float zg = sigm(az[rr] + bzc);
      float ng = tanhf(anx[rr] + bxn + rg*(anh[rr] + bhn));
      o_new[rr] = (1.f - zg)*ng + zg*hreg[rr];
      hreg[rr] = o_new[rr];
    }
    #pragma unroll
    for (int rr=0;rr<4;++rr){
      if (WSEQ) oseq[(size_t)t*M_*64 + obase[rr] + u] = o_new[rr];
      if (WFIN) ofin[obase[rr] + (size_t)t*N_*64 + u] = o_new[rr];
    }
    unsigned pk[4];
    #pragma unroll
    for (int rr=0;rr<4;++rr){
      float pr = __shfl_xor(o_new[rr], 4);
      pk[rr] = cvtpk(o_new[rr], pr);
    }
    __syncthreads();
    if ((u & 1) == 0) {
      #pragma unroll
      for (int rr=0;rr<4;++rr) hp_s[(u>>1)*20 + r4 + rr] = pk[rr];
    }
    if (t+1 < T_) {
      if (XP2 == 32) {
        for (int idx = tid; idx < 512; idx += 256) {
          int row = idx >> 5, p = idx & 31;
          const float2 v = *(const float2*)&xseq[((size_t)(t+1)*M_ + row0+row)*64 + 2*p];
          xp_s[p*20 + row] = cvtpk(v.x, v.y);
        }
      } else {
        if (tid < 16*XP2) {
          int row = tid / XP2, p = tid - (tid/XP2)*XP2;
          int k0 = 2*p, k1 = 2*p + 1;
          const float* xr = &xseq[((size_t)(t+1)*M_ + row0+row)*10];
          float f0 = (k0 < 10) ? xr[k0] : 0.f;
          float f1 = (k1 < 10) ? xr[k1] : 0.f;
          xp_s[p*20 + row] = cvtpk(f0, f1);
        }
      }
    }
    __syncthreads();
  }
}

// ---------------- stage C: fc2 MLP over out1 rows + nodevec = tanh(emb1*filt)
__global__ __launch_bounds__(256) void k_stageC(
    const float* __restrict__ out1, const float* __restrict__ emb1,
    const float* __restrict__ w1, const float* __restrict__ b1,
    const float* __restrict__ w2, const float* __restrict__ b2,
    const float* __restrict__ w3, const float* __restrict__ b3,
    float* __restrict__ ndv)
{
  int idx = blockIdx.x*256 + threadIdx.x;
  int m = idx % M_;
  int n = m % N_;
  float rv[64];
  const float4* r4 = (const float4*)(out1 + (size_t)idx*64);
  #pragma unroll
  for (int q=0;q<16;++q){ float4 v=r4[q]; rv[q*4]=v.x; rv[q*4+1]=v.y; rv[q*4+2]=v.z; rv[q*4+3]=v.w; }
  float h1[16];
  for (int u=0;u<16;++u){
    float a = b1[u];
    const float* wr = w1 + u*64;
    #pragma unroll
    for (int c=0;c<64;++c) a += rv[c]*wr[c];
    h1[u] = sigm(a);
  }
  float h2[2];
  #pragma unroll
  for (int v=0;v<2;++v){
    float a = b2[v];
    #pragma unroll
    for (int u=0;u<16;++u) a += h1[u]*w2[v*16+u];
    h2[v] = sigm(a);
  }
  #pragma unroll
  for (int d=0;d<10;++d){
    float f = b3[d] + h2[0]*w3[d*2] + h2[1]*w3[d*2+1];
    ndv[(size_t)idx*10 + d] = tanhf(emb1[n*10+d]*f);
  }
}

// ---------------- stage D: x_g = out1 + relu(V V^T) @ out1 per (t,b)
// f16-dot2 version: s and out1 packed in pairs along m; 2 MAC/instr.
__global__ __launch_bounds__(256) void k_stageD(
    const float* __restrict__ ndv, const float* __restrict__ out1, float* __restrict__ xg)
{
  int tb = blockIdx.y;
  int tile = blockIdx.x;               // 0..4
  int tid = threadIdx.x;
  __shared__ __align__(16) float V_s[320*12];
  __shared__ __align__(16) unsigned sp_s[32*68];   // packed s pairs [pair][row]
  __shared__ __align__(16) unsigned op_s[32*68];   // packed o pairs [pair][col]

  for (int i = tid; i < 320*12; i += 256) {
    int n = i / 12, d = i - n*12;
    V_s[i] = (n < N_ && d < 10) ? ndv[((size_t)tb*N_ + n)*10 + d] : 0.f;
  }
  __syncthreads();

  const int sr  = tid & 63;            // s-phase: row within tile
  const int smg = tid >> 6;            // s-phase: pair-group (8 pairs)
  float vr[10];
  {
    const float* vp = &V_s[(tile*64 + sr)*12];
    #pragma unroll
    for (int d = 0; d < 10; ++d) vr[d] = vp[d];
  }
  const int rq = tid & 15, cq = tid >> 4;
  const int r4 = rq*4, c4 = cq*4;
  float acc[4][4];
  #pragma unroll
  for (int a=0;a<4;++a)
    #pragma unroll
    for (int b=0;b<4;++b) acc[a][b]=0.f;

  const float* ob = out1 + (size_t)tb*N_*64;
  for (int mc = 0; mc < 320; mc += 64) {
    __syncthreads();
    // stage o pairs: 32 pairs x 16 col-groups (two rows packed vertically)
    for (int i = tid; i < 512; i += 256) {
      int p = i >> 4, cgi = i & 15;
      int gm0 = mc + 2*p, gm1 = gm0 + 1;
      float4 a = make_float4(0.f,0.f,0.f,0.f), b = a;
      if (gm0 < N_) a = *(const float4*)&ob[(size_t)gm0*64 + cgi*4];
      if (gm1 < N_) b = *(const float4*)&ob[(size_t)gm1*64 + cgi*4];
      uint4 pk4 = make_uint4(pkh(a.x,b.x), pkh(a.y,b.y), pkh(a.z,b.z), pkh(a.w,b.w));
      *(uint4*)&op_s[p*68 + cgi*4] = pk4;
    }
    // s pairs: each thread computes 16 m's for its row, packs 8 pairs
    #pragma unroll
    for (int j = 0; j < 8; ++j) {
      int m0 = mc + smg*16 + 2*j;
      const float* vm0 = &V_s[m0*12];
      const float* vm1 = &V_s[(m0+1)*12];
      float s0 = vr[0]*vm0[0] + vr[1]*vm0[1] + vr[2]*vm0[2] + vr[3]*vm0[3] + vr[4]*vm0[4]
               + vr[5]*vm0[5] + vr[6]*vm0[6] + vr[7]*vm0[7] + vr[8]*vm0[8] + vr[9]*vm0[9];
      float s1 = vr[0]*vm1[0] + vr[1]*vm1[1] + vr[2]*vm1[2] + vr[3]*vm1[3] + vr[4]*vm1[4]
               + vr[5]*vm1[5] + vr[6]*vm1[6] + vr[7]*vm1[7] + vr[8]*vm1[8] + vr[9]*vm1[9];
      sp_s[(smg*8 + j)*68 + sr] = pkh(fmaxf(s0,0.f), fmaxf(s1,0.f));
    }
    __syncthreads();
    // accumulate 4x4 tile over 32 pairs
    #pragma unroll 8
    for (int p = 0; p < 32; ++p) {
      uint4 sv = *(const uint4*)&sp_s[p*68 + r4];
      uint4 ov = *(const uint4*)&op_s[p*68 + c4];
      doth(acc[0][0], sv.x, ov.x); doth(acc[0][1], sv.x, ov.y); doth(acc[0][2], sv.x, ov.z); doth(acc[0][3], sv.x, ov.w);
      doth(acc[1][0], sv.y, ov.x); doth(acc[1][1], sv.y, ov.y); doth(acc[1][2], sv.y, ov.z); doth(acc[1][3], sv.y, ov.w);
      doth(acc[2][0], sv.z, ov.x); doth(acc[2][1], sv.z, ov.y); doth(acc[2][2], sv.z, ov.z); doth(acc[2][3], sv.z, ov.w);
      doth(acc[3][0], sv.w, ov.x); doth(acc[3][1], sv.w, ov.y); doth(acc[3][2], sv.w, ov.z); doth(acc[3][3], sv.w, ov.w);
    }
  }

  #pragma unroll
  for (int rr = 0; rr < 4; ++rr) {
    int nrow = tile*64 + r4 + rr;
    if (nrow < N_) {
      size_t base = ((size_t)tb*N_ + nrow)*64 + c4;
      float4 o = *(const float4*)&out1[base];
      *(float4*)&xg[base] = make_float4(o.x+acc[rr][0], o.y+acc[rr][1],
                                        o.z+acc[rr][2], o.w+acc[rr][3]);
    }
  }
}

// ---------------- stage E (fused): g2 = o@dwA^T + x@Wf[n] + bf[n]
__global__ __launch_bounds__(256) void k_stageE(
    const float* xg_in, const float* __restrict__ out1,
    const float* __restrict__ Wf, const float* __restrict__ dw,
    const float* __restrict__ bf,
    float* xg_out)
{
  int n = blockIdx.y;
  int tile = blockIdx.x;     // 12 tiles of 64 tb-rows
  int tid = threadIdx.x;
  int r = tid >> 3, ug = tid & 7;
  __shared__ __align__(16) float x_s[64*68];
  __shared__ __align__(16) float o_s[64*68];
  __shared__ __align__(16) float Wf_s[64*68];   // [u][c]
  __shared__ __align__(16) float dA_s[64*68];   // [u][c]
  __shared__ float bf_s[64];
  for (int idx = tid; idx < 64*64; idx += 256) {
    int row = idx >> 6, c = idx & 63;
    size_t g = ((size_t)(tile*64+row)*N_ + n)*64 + c;
    x_s[row*68+c] = xg_in[g];
    o_s[row*68+c] = out1[g];
  }
  for (int idx = tid; idx < 4096; idx += 256) {
    int u = idx >> 6, c = idx & 63;
    Wf_s[u*68+c] = Wf[(size_t)n*4096 + idx];
    dA_s[u*68+c] = dw[u*128 + c];
  }
  if (tid < 64) bf_s[tid] = bf[n*64 + tid];
  __syncthreads();

  float g2a[8], g2b[8];
  #pragma unroll
  for (int uu=0;uu<8;++uu){ g2a[uu] = bf_s[ug+8*uu]; g2b[uu] = g2a[uu]; }

  for (int c = 0; c < 64; c += 4) {
    float4 xa = *(const float4*)&x_s[r*68 + c];
    float4 xb = *(const float4*)&x_s[(r+32)*68 + c];
    float4 oa = *(const float4*)&o_s[r*68 + c];
    float4 ob = *(const float4*)&o_s[(r+32)*68 + c];
    #pragma unroll
    for (int uu=0;uu<8;++uu){
      int u = ug + 8*uu;
      float4 wf = *(const float4*)&Wf_s[u*68 + c];
      float4 da = *(const float4*)&dA_s[u*68 + c];
      g2a[uu] += oa.x*da.x + oa.y*da.y + oa.z*da.z + oa.w*da.w
               + xa.x*wf.x + xa.y*wf.y + xa.z*wf.z + xa.w*wf.w;
      g2b[uu] += ob.x*da.x + ob.y*da.y + ob.z*da.z + ob.w*da.w
               + xb.x*wf.x + xb.y*wf.y + xb.z*wf.z + xb.w*wf.w;
    }
  }
  size_t ba = ((size_t)(tile*64+r)*N_ + n)*64;
  size_t bb = ((size_t)(tile*64+r+32)*N_ + n)*64;
  #pragma unroll
  for (int uu=0;uu<8;++uu){
    xg_out[ba + ug + 8*uu] = g2a[uu];
    xg_out[bb + ug + 8*uu] = g2b[uu];
  }
}

extern "C" void kernel_launch(void* const* d_in, const int* in_sizes, int n_in,
                              void* d_out, int out_size, void* d_ws, size_t ws_size,
                              hipStream_t stream)
{
  (void)in_sizes; (void)n_in; (void)out_size;
  const float* x    = (const float*)d_in[0];
  const float* emb1 = (const float*)d_in[1];
  const float* emb2 = (const float*)d_in[2];
  const float* xw1  = (const float*)d_in[3];
  const float* xb1  = (const float*)d_in[4];
  const float* xw2  = (const float*)d_in[5];
  const float* xb2  = (const float*)d_in[6];
  const float* xw3  = (const float*)d_in[7];
  const float* xb3  = (const float*)d_in[8];
  const float* fw1  = (const float*)d_in[9];
  const float* fb1  = (const float*)d_in[10];
  const float* fw2  = (const float*)d_in[11];
  const float* fb2  = (const float*)d_in[12];
  const float* fw3  = (const float*)d_in[13];
  const float* fb3  = (const float*)d_in[14];
  const float* c2w1 = (const float*)d_in[15];
  const float* c2b1 = (const float*)d_in[16];
  const float* c2w2 = (const float*)d_in[17];
  const float* c2b2 = (const float*)d_in[18];
  const float* c2w3 = (const float*)d_in[19];
  const float* c2b3 = (const float*)d_in[20];
  const float* g1wih= (const float*)d_in[21];
  const float* g1whh= (const float*)d_in[22];
  const float* g1bih= (const float*)d_in[23];
  const float* g1bhh= (const float*)d_in[24];
  const float* g2wih= (const float*)d_in[25];
  const float* g2whh= (const float*)d_in[26];
  const float* g2bih= (const float*)d_in[27];
  const float* g2bhh= (const float*)d_in[28];
  const float* wpool= (const float*)d_in[29];
  const float* bpool= (const float*)d_in[30];
  const float* dww  = (const float*)d_in[31];
  const float* dwb  = (const float*)d_in[32];
  float* out = (float*)d_out;

  float* ws = (float*)d_ws;
  float* g1_in = ws;                          // TM*10
  float* out1  = g1_in + (size_t)TM_*10;      // TM*64
  float* ndv   = out1 + (size_t)TM_*64;       // TM*10
  float* xg    = ndv + (size_t)TM_*10;        // TM*64
  float* Wn    = xg + (size_t)TM_*64;         // N*4096
  float* bn    = Wn + (size_t)N_*4096;        // N*64
  float* Wf    = bn + (size_t)N_*64;          // N*4096
  float* bf    = Wf + (size_t)N_*4096;        // N*64
  unsigned* Wpk2 = (unsigned*)(bf + (size_t)N_*64);   // 64*192
  unsigned* Wpk1 = Wpk2 + 64*192;                     // 38*192
  size_t need = ((size_t)((float*)(Wpk1 + 38*192) - ws)) * 4;
  if (ws_size < need) return;

  k_stageA<<<TM_/256, 256, 0, stream>>>(x, xw1,xb1,xw2,xb2,xw3,xb3, fw1,fb1,fw2,fb2,fw3,fb3, g1_in);
  k_wn<<<N_, 256, 0, stream>>>(emb2, wpool, bpool, Wn, bn);
  k_wf<<<N_, 256, 0, stream>>>(Wn, bn, dww, dwb, Wf, bf);
  k_wpack<<<(64*192 + 38*192 + 255)/256, 256, 0, stream>>>(g2wih, g2whh, g1wih, g1whh, Wpk2, Wpk1);

  // GRU1: DIN=10 -> XP2=6
  k_gruD<6,true,false><<<M_/16, 256, 0, stream>>>(
      g1_in, Wpk1, g1bih, g1bhh, out1, nullptr);

  k_stageC<<<TM_/256, 256, 0, stream>>>(out1, emb1, c2w1,c2b1,c2w2,c2b2,c2w3,c2b3, ndv);
  k_stageD<<<dim3(5, T_*B_), 256, 0, stream>>>(ndv, out1, xg);
  k_stageE<<<dim3(12, N_), 256, 0, stream>>>(xg, out1, Wf, dww, bf, xg);

  // GRU2: DIN=64 -> XP2=32
  k_gruD<32,false,true><<<M_/16, 256, 0, stream>>>(
      xg, Wpk2, g2bih, g2bhh, nullptr, out);
}

// Round 9
// 533.127 us; speedup vs baseline: 28.6164x; 1.0205x over previous
//
#include <hip/hip_runtime.h>
#include <hip/hip_fp16.h>
#include <math.h>

#define B_ 64
#define T_ 12
#define N_ 307
#define I_ 3
#define R_ 64
#define D_ 10
#define M_ (B_*N_)      // 19648
#define TM_ (T_*M_)     // 235776

__device__ __forceinline__ float sigm(float x){ return 1.f/(1.f+__expf(-x)); }

__device__ __forceinline__ unsigned cvtpk(float a, float b){
  unsigned r;
  asm("v_cvt_pk_bf16_f32 %0, %1, %2" : "=v"(r) : "v"(a), "v"(b));
  return r;
}
__device__ __forceinline__ void dot2(float& acc, unsigned a, unsigned b){
  asm("v_dot2_f32_bf16 %0, %1, %2, %0" : "+v"(acc) : "v"(a), "v"(b));
}
__device__ __forceinline__ unsigned pkh(float a, float b){
  unsigned r;
  asm("v_cvt_pkrtz_f16_f32 %0, %1, %2" : "=v"(r) : "v"(a), "v"(b));
  return r;
}
__device__ __forceinline__ void doth(float& acc, unsigned a, unsigned b){
  asm("v_dot2_f32_f16 %0, %1, %2, %0" : "+v"(acc) : "v"(a), "v"(b));
}

// ---------------- stage A ----------------
__global__ __launch_bounds__(256) void k_stageA(
    const float* __restrict__ x,
    const float* __restrict__ xw1, const float* __restrict__ xb1,
    const float* __restrict__ xw2, const float* __restrict__ xb2,
    const float* __restrict__ xw3, const float* __restrict__ xb3,
    const float* __restrict__ fw1, const float* __restrict__ fb1,
    const float* __restrict__ fw2, const float* __restrict__ fb2,
    const float* __restrict__ fw3, const float* __restrict__ fb3,
    float* __restrict__ g1)
{
  int idx = blockIdx.x*256 + threadIdx.x;
  int t = idx / M_;
  int m = idx - t*M_;
  int b = m / N_;
  int n = m - b*N_;
  const float* xp = x + (((size_t)b*T_ + t)*N_ + n)*I_;
  float xv[3] = {xp[0], xp[1], xp[2]};
  float e[3][10];
  #pragma unroll
  for (int i=0;i<3;++i){
    float h1[16];
    #pragma unroll
    for (int u=0;u<16;++u) h1[u] = sigm(xv[i]*xw1[u] + xb1[u]);
    float h2[2];
    #pragma unroll
    for (int v=0;v<2;++v){
      float a = xb2[v];
      #pragma unroll
      for (int u=0;u<16;++u) a += h1[u]*xw2[v*16+u];
      h2[v] = sigm(a);
    }
    #pragma unroll
    for (int d=0;d<10;++d) e[i][d] = xb3[d] + h2[0]*xw3[d*2] + h2[1]*xw3[d*2+1];
  }
  float in1[3];
  #pragma unroll
  for (int j=0;j<3;++j){
    float acc = 0.f;
    #pragma unroll
    for (int i=0;i<3;++i){
      float s = 0.f;
      #pragma unroll
      for (int d=0;d<10;++d) s += e[j][d]*e[i][d];
      s = fmaxf(s, 0.f);
      acc += s*xv[i];
    }
    in1[j] = xv[j] + acc;
  }
  float h1[16];
  #pragma unroll
  for (int u=0;u<16;++u)
    h1[u] = sigm(fb1[u] + in1[0]*fw1[u*3] + in1[1]*fw1[u*3+1] + in1[2]*fw1[u*3+2]);
  float h2[2];
  #pragma unroll
  for (int v=0;v<2;++v){
    float a = fb2[v];
    #pragma unroll
    for (int u=0;u<16;++u) a += h1[u]*fw2[v*16+u];
    h2[v] = sigm(a);
  }
  float* gp = g1 + (size_t)idx*10;
  #pragma unroll
  for (int d=0;d<10;++d) gp[d] = fb3[d] + h2[0]*fw3[d*2] + h2[1]*fw3[d*2+1];
}

// ---------------- k_wn ----------------
__global__ __launch_bounds__(256) void k_wn(
    const float* __restrict__ emb2, const float* __restrict__ wpool,
    const float* __restrict__ bpool, float* __restrict__ Wn, float* __restrict__ bn)
{
  int n = blockIdx.x; int tid = threadIdx.x;
  __shared__ float e_s[10];
  if (tid < 10) e_s[tid] = emb2[n*10 + tid];
  __syncthreads();
  #pragma unroll
  for (int e=0;e<16;++e){
    int i = e*256 + tid;
    float a = 0.f;
    #pragma unroll
    for (int d=0;d<10;++d) a += e_s[d]*wpool[(size_t)d*4096 + i];
    Wn[(size_t)n*4096 + i] = a;
  }
  if (tid < 64){
    float a = 0.f;
    #pragma unroll
    for (int d=0;d<10;++d) a += e_s[d]*bpool[d*64 + tid];
    bn[n*64 + tid] = a;
  }
}

// ---------------- k_wf ----------------
__global__ __launch_bounds__(256) void k_wf(
    const float* __restrict__ Wn, const float* __restrict__ bn,
    const float* __restrict__ dw, const float* __restrict__ db,
    float* __restrict__ Wf, float* __restrict__ bf)
{
  int n = blockIdx.x; int tid = threadIdx.x;
  __shared__ float WnS[64*68];
  __shared__ float dwBT[64*68];
  __shared__ float bn_s[64];
  for (int idx = tid; idx < 4096; idx += 256) {
    int c = idx >> 6, r = idx & 63;
    WnS[c*68 + r] = Wn[(size_t)n*4096 + idx];
  }
  for (int idx = tid; idx < 4096; idx += 256) {
    int u = idx >> 6, r = idx & 63;
    dwBT[r*68 + u] = dw[u*128 + 64 + r];
  }
  if (tid < 64) bn_s[tid] = bn[n*64 + tid];
  __syncthreads();
  int u = tid & 63, cg = tid >> 6;
  #pragma unroll
  for (int j = 0; j < 16; ++j) {
    int c = cg*16 + j;
    float acc = 0.f;
    #pragma unroll 8
    for (int r = 0; r < 64; ++r) acc += WnS[c*68 + r] * dwBT[r*68 + u];
    Wf[(size_t)n*4096 + u*64 + c] = acc;
  }
  if (tid < 64) {
    float acc = db[tid];
    #pragma unroll 8
    for (int r = 0; r < 64; ++r) acc += bn_s[r] * dwBT[r*68 + tid];
    bf[n*64 + tid] = acc;
  }
}

// ---------------- old pair-major packing (fallback path) ----------------
__global__ __launch_bounds__(256) void k_wpack(
    const float* __restrict__ wih2, const float* __restrict__ whh2,
    const float* __restrict__ wih1, const float* __restrict__ whh1,
    unsigned* __restrict__ Wpk2, unsigned* __restrict__ Wpk1)
{
  int i = blockIdx.x*256 + threadIdx.x;
  if (i < 64*192) {
    int p = i / 192, wr = i - (i/192)*192;
    int k0 = 2*p, k1 = 2*p + 1;
    float f0 = (k0 < 64) ? whh2[wr*64 + k0] : wih2[wr*64 + (k0-64)];
    float f1 = (k1 < 64) ? whh2[wr*64 + k1] : wih2[wr*64 + (k1-64)];
    Wpk2[i] = cvtpk(f0, f1);
  }
  int j = i - 64*192;
  if (j >= 0 && j < 38*192) {
    int p = j / 192, wr = j - (j/192)*192;
    int k0 = 2*p, k1 = 2*p + 1;
    float f0 = (k0 < 64) ? whh1[wr*64 + k0] : ((k0-64) < 10 ? wih1[wr*10 + (k0-64)] : 0.f);
    float f1 = (k1 < 64) ? whh1[wr*64 + k1] : ((k1-64) < 10 ? wih1[wr*10 + (k1-64)] : 0.f);
    Wpk1[j] = cvtpk(f0, f1);
  }
}

// ---------------- new u-major packing:
// Wq2 [192][36]: whh2 pairs (p<32); Wxq2 [192][36]: wih2 pairs (p<32);
// Wq1 [192][44]: p<32 = whh1 pairs, p in [36,41) = wih1 pairs (5), rest 0.
__global__ __launch_bounds__(256) void k_wpack2(
    const float* __restrict__ wih2, const float* __restrict__ whh2,
    const float* __restrict__ wih1, const float* __restrict__ whh1,
    unsigned* __restrict__ Wq2, unsigned* __restrict__ Wxq2, unsigned* __restrict__ Wq1)
{
  int i = blockIdx.x*256 + threadIdx.x;
  if (i < 192*36) {
    int wr = i / 36, c = i - wr*36;
    unsigned v = 0u;
    if (c < 32) v = cvtpk(whh2[wr*64 + 2*c], whh2[wr*64 + 2*c + 1]);
    Wq2[i] = v;
    unsigned vx = 0u;
    if (c < 32) vx = cvtpk(wih2[wr*64 + 2*c], wih2[wr*64 + 2*c + 1]);
    Wxq2[i] = vx;
  }
  int j = i - 192*36;
  if (j >= 0 && j < 192*44) {
    int wr = j / 44, c = j - wr*44;
    unsigned v = 0u;
    if (c < 32) {
      v = cvtpk(whh1[wr*64 + 2*c], whh1[wr*64 + 2*c + 1]);
    } else if (c >= 36 && c < 41) {
      int p = c - 36, k0 = 2*p, k1 = 2*p + 1;
      float f0 = (k0 < 10) ? wih1[wr*10 + k0] : 0.f;
      float f1 = (k1 < 10) ? wih1[wr*10 + k1] : 0.f;
      v = cvtpk(f0, f1);
    }
    Wq1[j] = v;
  }
}

// ---------------- old combined scan (fallback path) ----------------
template<int XP2, bool WSEQ, bool WFIN>
__global__ __launch_bounds__(256) void k_gruD(
    const float* __restrict__ xseq,
    const unsigned* __restrict__ Wpk,
    const float* __restrict__ bih, const float* __restrict__ bhh,
    float* __restrict__ oseq, float* __restrict__ ofin)
{
  constexpr int P2 = 32 + XP2;
  __shared__ __align__(16) unsigned W_s[P2*192];
  __shared__ __align__(16) unsigned hp_s[32*20];
  __shared__ __align__(16) unsigned xp_s[XP2*20];
  const int tid = threadIdx.x;
  const int row0 = blockIdx.x * 16;
  const int tr = tid & 3, u = tid >> 2;
  const int r4 = tr*4;

  for (int i = tid; i < P2*192; i += 256) W_s[i] = Wpk[i];
  for (int i = tid; i < 32*20; i += 256) hp_s[i] = 0u;

  const float brc = bih[u]     + bhh[u];
  const float bzc = bih[64+u]  + bhh[64+u];
  const float bxn = bih[128+u];
  const float bhn = bhh[128+u];

  size_t obase[4];
  #pragma unroll
  for (int rr=0;rr<4;++rr){
    int g = row0 + r4 + rr;
    if (WFIN){
      int bb = g / N_, nn = g - bb*N_;
      obase[rr] = (((size_t)bb*T_)*N_ + nn)*64;
    } else {
      obase[rr] = (size_t)g*64;
    }
  }
  float hreg[4] = {0.f, 0.f, 0.f, 0.f};

  if (XP2 == 32) {
    for (int idx = tid; idx < 512; idx += 256) {
      int row = idx >> 5, p = idx & 31;
      const float2 v = *(const float2*)&xseq[((size_t)(row0+row))*64 + 2*p];
      xp_s[p*20 + row] = cvtpk(v.x, v.y);
    }
  } else {
    if (tid < 16*XP2) {
      int row = tid / XP2, p = tid - (tid/XP2)*XP2;
      int k0 = 2*p, k1 = 2*p + 1;
      const float* xr = &xseq[((size_t)(row0+row))*10];
      float f0 = (k0 < 10) ? xr[k0] : 0.f;
      float f1 = (k1 < 10) ? xr[k1] : 0.f;
      xp_s[p*20 + row] = cvtpk(f0, f1);
    }
  }
  __syncthreads();

  for (int t = 0; t < T_; ++t) {
    float ar[4]={0,0,0,0}, az[4]={0,0,0,0}, anh[4]={0,0,0,0}, anx[4]={0,0,0,0};
    #pragma unroll 4
    for (int p = 0; p < 32; ++p) {
      uint4 a = *(const uint4*)&hp_s[p*20 + r4];
      unsigned wr_ = W_s[p*192 + u];
      unsigned wz_ = W_s[p*192 + 64 + u];
      unsigned wn_ = W_s[p*192 + 128 + u];
      dot2(ar[0], a.x, wr_); dot2(ar[1], a.y, wr_); dot2(ar[2], a.z, wr_); dot2(ar[3], a.w, wr_);
      dot2(az[0], a.x, wz_); dot2(az[1], a.y, wz_); dot2(az[2], a.z, wz_); dot2(az[3], a.w, wz_);
      dot2(anh[0], a.x, wn_); dot2(anh[1], a.y, wn_); dot2(anh[2], a.z, wn_); dot2(anh[3], a.w, wn_);
    }
    #pragma unroll 4
    for (int p = 0; p < XP2; ++p) {
      uint4 a = *(const uint4*)&xp_s[p*20 + r4];
      unsigned wr_ = W_s[(32+p)*192 + u];
      unsigned wz_ = W_s[(32+p)*192 + 64 + u];
      unsigned wn_ = W_s[(32+p)*192 + 128 + u];
      dot2(ar[0], a.x, wr_); dot2(ar[1], a.y, wr_); dot2(ar[2], a.z, wr_); dot2(ar[3], a.w, wr_);
      dot2(az[0], a.x, wz_); dot2(az[1], a.y, wz_); dot2(az[2], a.z, wz_); dot2(az[3], a.w, wz_);
      dot2(anx[0], a.x, wn_); dot2(anx[1], a.y, wn_); dot2(anx[2], a.z, wn_); dot2(anx[3], a.w, wn_);
    }
    float o_new[4];
    #pragma unroll
    for (int rr=0;rr<4;++rr){
      float rg = sigm(ar[rr] + brc);
      float zg = sigm(az[rr] + bzc);
      float ng = tanhf(anx[rr] + bxn + rg*(anh[rr] + bhn));
      o_new[rr] = (1.f - zg)*ng + zg*hreg[rr];
      hreg[rr] = o_new[rr];
    }
    #pragma unroll
    for (int rr=0;rr<4;++rr){
      if (WSEQ) oseq[(size_t)t*M_*64 + obase[rr] + u] = o_new[rr];
      if (WFIN) ofin[obase[rr] + (size_t)t*N_*64 + u] = o_new[rr];
    }
    unsigned pk[4];
    #pragma unroll
    for (int rr=0;rr<4;++rr){
      float pr = __shfl_xor(o_new[rr], 4);
      pk[rr] = cvtpk(o_new[rr], pr);
    }
    __syncthreads();
    if ((u & 1) == 0) {
      #pragma unroll
      for (int rr=0;rr<4;++rr) hp_s[(u>>1)*20 + r4 + rr] = pk[rr];
    }
    if (t+1 < T_) {
      if (XP2 == 32) {
        for (int idx = tid; idx < 512; idx += 256) {
          int row = idx >> 5, p = idx & 31;
          const float2 v = *(const float2*)&xseq[((size_t)(t+1)*M_ + row0+row)*64 + 2*p];
          xp_s[p*20 + row] = cvtpk(v.x, v.y);
        }
      } else {
        if (tid < 16*XP2) {
          int row = tid / XP2, p = tid - (tid/XP2)*XP2;
          int k0 = 2*p, k1 = 2*p + 1;
          const float* xr = &xseq[((size_t)(t+1)*M_ + row0+row)*10];
          float f0 = (k0 < 10) ? xr[k0] : 0.f;
          float f1 = (k1 < 10) ? xr[k1] : 0.f;
          xp_s[p*20 + row] = cvtpk(f0, f1);
        }
      }
    }
    __syncthreads();
  }
}

// ---------------- k_xw: xw2 = g2 @ wih2^T + bih2 -> f16 [TM][192]
// grid TM/16, 256 thr: tr=tid&3 (4 rows), u=tid>>2 (unit).
__global__ __launch_bounds__(256) void k_xw(
    const float* __restrict__ g2, const unsigned* __restrict__ Wxq,
    const float* __restrict__ bih, unsigned short* __restrict__ xwh)
{
  __shared__ __align__(16) unsigned W_s[192*36];
  __shared__ __align__(16) unsigned xp_s[32*20];
  const int tid = threadIdx.x;
  const int row0 = blockIdx.x * 16;
  const int tr = tid & 3, u = tid >> 2;
  const int r4 = tr*4;

  for (int i = tid; i < 192*36; i += 256) W_s[i] = Wxq[i];
  for (int idx = tid; idx < 512; idx += 256) {
    int row = idx >> 5, p = idx & 31;
    const float2 v = *(const float2*)&g2[((size_t)(row0+row))*64 + 2*p];
    xp_s[p*20 + row] = cvtpk(v.x, v.y);
  }
  const float bi_r = bih[u], bi_z = bih[64+u], bi_n = bih[128+u];
  __syncthreads();

  float ar[4]={0,0,0,0}, az[4]={0,0,0,0}, an[4]={0,0,0,0};
  #pragma unroll
  for (int pc = 0; pc < 32; pc += 4) {
    uint4 h0 = *(const uint4*)&xp_s[(pc+0)*20 + r4];
    uint4 h1 = *(const uint4*)&xp_s[(pc+1)*20 + r4];
    uint4 h2 = *(const uint4*)&xp_s[(pc+2)*20 + r4];
    uint4 h3 = *(const uint4*)&xp_s[(pc+3)*20 + r4];
    uint4 wr4 = *(const uint4*)&W_s[u*36 + pc];
    uint4 wz4 = *(const uint4*)&W_s[(64+u)*36 + pc];
    uint4 wn4 = *(const uint4*)&W_s[(128+u)*36 + pc];
    dot2(ar[0],h0.x,wr4.x); dot2(ar[1],h0.y,wr4.x); dot2(ar[2],h0.z,wr4.x); dot2(ar[3],h0.w,wr4.x);
    dot2(ar[0],h1.x,wr4.y); dot2(ar[1],h1.y,wr4.y); dot2(ar[2],h1.z,wr4.y); dot2(ar[3],h1.w,wr4.y);
    dot2(ar[0],h2.x,wr4.z); dot2(ar[1],h2.y,wr4.z); dot2(ar[2],h2.z,wr4.z); dot2(ar[3],h2.w,wr4.z);
    dot2(ar[0],h3.x,wr4.w); dot2(ar[1],h3.y,wr4.w); dot2(ar[2],h3.z,wr4.w); dot2(ar[3],h3.w,wr4.w);
    dot2(az[0],h0.x,wz4.x); dot2(az[1],h0.y,wz4.x); dot2(az[2],h0.z,wz4.x); dot2(az[3],h0.w,wz4.x);
    dot2(az[0],h1.x,wz4.y); dot2(az[1],h1.y,wz4.y); dot2(az[2],h1.z,wz4.y); dot2(az[3],h1.w,wz4.y);
    dot2(az[0],h2.x,wz4.z); dot2(az[1],h2.y,wz4.z); dot2(az[2],h2.z,wz4.z); dot2(az[3],h2.w,wz4.z);
    dot2(az[0],h3.x,wz4.w); dot2(az[1],h3.y,wz4.w); dot2(az[2],h3.z,wz4.w); dot2(az[3],h3.w,wz4.w);
    dot2(an[0],h0.x,wn4.x); dot2(an[1],h0.y,wn4.x); dot2(an[2],h0.z,wn4.x); dot2(an[3],h0.w,wn4.x);
    dot2(an[0],h1.x,wn4.y); dot2(an[1],h1.y,wn4.y); dot2(an[2],h1.z,wn4.y); dot2(an[3],h1.w,wn4.y);
    dot2(an[0],h2.x,wn4.z); dot2(an[1],h2.y,wn4.z); dot2(an[2],h2.z,wn4.z); dot2(an[3],h2.w,wn4.z);
    dot2(an[0],h3.x,wn4.w); dot2(an[1],h3.y,wn4.w); dot2(an[2],h3.z,wn4.w); dot2(an[3],h3.w,wn4.w);
  }
  #pragma unroll
  for (int rr = 0; rr < 4; ++rr) {
    size_t rbase = (size_t)(row0 + r4 + rr)*192;
    float vr_ = ar[rr] + bi_r;
    float vz_ = az[rr] + bi_z;
    float vn_ = an[rr] + bi_n;
    float pr = __shfl_xor(vr_, 4);
    float pz = __shfl_xor(vz_, 4);
    float pn = __shfl_xor(vn_, 4);
    if ((u & 1) == 0) {
      *(unsigned*)&xwh[rbase + u]        = pkh(vr_, pr);
      *(unsigned*)&xwh[rbase + 64 + u]   = pkh(vz_, pz);
      *(unsigned*)&xwh[rbase + 128 + u]  = pkh(vn_, pn);
    }
  }
}

// ---------------- k_gruH: GRU2 scan, h-only; xw streamed from global f16 ----------------
__global__ __launch_bounds__(256) void k_gruH(
    const unsigned short* __restrict__ xwh,  // [TM][192] f16, includes bih
    const unsigned* __restrict__ Wq,         // [192][36]
    const float* __restrict__ bhh,
    float* __restrict__ ofin)                // [B][T][N][64]
{
  __shared__ __align__(16) unsigned W_s[192*36];
  __shared__ __align__(16) unsigned hp_s[32*20];
  const int tid = threadIdx.x;
  const int row0 = blockIdx.x * 16;
  const int tr = tid & 3, u = tid >> 2;
  const int r4 = tr*4;

  for (int i = tid; i < 192*36; i += 256) W_s[i] = Wq[i];
  for (int i = tid; i < 32*20; i += 256) hp_s[i] = 0u;

  const float bh_r = bhh[u], bh_z = bhh[64+u], bh_n = bhh[128+u];
  size_t obase[4];
  #pragma unroll
  for (int rr=0;rr<4;++rr){
    int g = row0 + r4 + rr;
    int bb = g / N_, nn = g - bb*N_;
    obase[rr] = (((size_t)bb*T_)*N_ + nn)*64;
  }
  float hreg[4] = {0.f,0.f,0.f,0.f};
  const __half* xh = (const __half*)xwh;
  __syncthreads();

  for (int t = 0; t < T_; ++t) {
    // issue xw loads early (consumed after the h loop)
    float xr_[4], xz_[4], xn_[4];
    #pragma unroll
    for (int rr=0;rr<4;++rr){
      size_t base = ((size_t)t*M_ + row0 + r4 + rr)*192 + u;
      xr_[rr] = __half2float(xh[base]);
      xz_[rr] = __half2float(xh[base+64]);
      xn_[rr] = __half2float(xh[base+128]);
    }
    float ar[4]={0,0,0,0}, az[4]={0,0,0,0}, anh[4]={0,0,0,0};
    #pragma unroll
    for (int pc = 0; pc < 32; pc += 4) {
      uint4 h0 = *(const uint4*)&hp_s[(pc+0)*20 + r4];
      uint4 h1 = *(const uint4*)&hp_s[(pc+1)*20 + r4];
      uint4 h2 = *(const uint4*)&hp_s[(pc+2)*20 + r4];
      uint4 h3 = *(const uint4*)&hp_s[(pc+3)*20 + r4];
      uint4 wr4 = *(const uint4*)&W_s[u*36 + pc];
      uint4 wz4 = *(const uint4*)&W_s[(64+u)*36 + pc];
      uint4 wn4 = *(const uint4*)&W_s[(128+u)*36 + pc];
      dot2(ar[0],h0.x,wr4.x); dot2(ar[1],h0.y,wr4.x); dot2(ar[2],h0.z,wr4.x); dot2(ar[3],h0.w,wr4.x);
      dot2(ar[0],h1.x,wr4.y); dot2(ar[1],h1.y,wr4.y); dot2(ar[2],h1.z,wr4.y); dot2(ar[3],h1.w,wr4.y);
      dot2(ar[0],h2.x,wr4.z); dot2(ar[1],h2.y,wr4.z); dot2(ar[2],h2.z,wr4.z); dot2(ar[3],h2.w,wr4.z);
      dot2(ar[0],h3.x,wr4.w); dot2(ar[1],h3.y,wr4.w); dot2(ar[2],h3.z,wr4.w); dot2(ar[3],h3.w,wr4.w);
      dot2(az[0],h0.x,wz4.x); dot2(az[1],h0.y,wz4.x); dot2(az[2],h0.z,wz4.x); dot2(az[3],h0.w,wz4.x);
      dot2(az[0],h1.x,wz4.y); dot2(az[1],h1.y,wz4.y); dot2(az[2],h1.z,wz4.y); dot2(az[3],h1.w,wz4.y);
      dot2(az[0],h2.x,wz4.z); dot2(az[1],h2.y,wz4.z); dot2(az[2],h2.z,wz4.z); dot2(az[3],h2.w,wz4.z);
      dot2(az[0],h3.x,wz4.w); dot2(az[1],h3.y,wz4.w); dot2(az[2],h3.z,wz4.w); dot2(az[3],h3.w,wz4.w);
      dot2(anh[0],h0.x,wn4.x); dot2(anh[1],h0.y,wn4.x); dot2(anh[2],h0.z,wn4.x); dot2(anh[3],h0.w,wn4.x);
      dot2(anh[0],h1.x,wn4.y); dot2(anh[1],h1.y,wn4.y); dot2(anh[2],h1.z,wn4.y); dot2(anh[3],h1.w,wn4.y);
      dot2(anh[0],h2.x,wn4.z); dot2(anh[1],h2.y,wn4.z); dot2(anh[2],h2.z,wn4.z); dot2(anh[3],h2.w,wn4.z);
      dot2(anh[0],h3.x,wn4.w); dot2(anh[1],h3.y,wn4.w); dot2(anh[2],h3.z,wn4.w); dot2(anh[3],h3.w,wn4.w);
    }
    float o_new[4];
    #pragma unroll
    for (int rr=0;rr<4;++rr){
      float rg = sigm(ar[rr] + xr_[rr] + bh_r);
      float zg = sigm(az[rr] + xz_[rr] + bh_z);
      float ng = tanhf(xn_[rr] + rg*(anh[rr] + bh_n));
      o_new[rr] = (1.f - zg)*ng + zg*hreg[rr];
      hreg[rr] = o_new[rr];
    }
    #pragma unroll
    for (int rr=0;rr<4;++rr)
      ofin[obase[rr] + (size_t)t*N_*64 + u] = o_new[rr];
    unsigned pk[4];
    #pragma unroll
    for (int rr=0;rr<4;++rr){
      float pr = __shfl_xor(o_new[rr], 4);
      pk[rr] = cvtpk(o_new[rr], pr);
    }
    __syncthreads();
    if ((u & 1) == 0) {
      #pragma unroll
      for (int rr=0;rr<4;++rr) hp_s[(u>>1)*20 + r4 + rr] = pk[rr];
    }
    __syncthreads();
  }
}

// ---------------- k_gruX: GRU1 scan, vectorized-W; small x-part in LDS ----------------
__global__ __launch_bounds__(256) void k_gruX(
    const float* __restrict__ xseq,          // [T][M][10]
    const unsigned* __restrict__ Wq,         // [192][44]
    const float* __restrict__ bih, const float* __restrict__ bhh,
    float* __restrict__ oseq)                // [T][M][64]
{
  __shared__ __align__(16) unsigned W_s[192*44];
  __shared__ __align__(16) unsigned hp_s[32*20];
  __shared__ __align__(16) unsigned xp_s[8*20];
  const int tid = threadIdx.x;
  const int row0 = blockIdx.x * 16;
  const int tr = tid & 3, u = tid >> 2;
  const int r4 = tr*4;

  for (int i = tid; i < 192*44; i += 256) W_s[i] = Wq[i];
  for (int i = tid; i < 32*20; i += 256) hp_s[i] = 0u;
  for (int i = tid; i < 8*20; i += 256) xp_s[i] = 0u;

  const float brc = bih[u]    + bhh[u];
  const float bzc = bih[64+u] + bhh[64+u];
  const float bxn = bih[128+u];
  const float bhn = bhh[128+u];
  size_t obase[4];
  #pragma unroll
  for (int rr=0;rr<4;++rr) obase[rr] = (size_t)(row0 + r4 + rr)*64;
  float hreg[4] = {0.f,0.f,0.f,0.f};
  __syncthreads();

  for (int t = 0; t < T_; ++t) {
    // stage x_t pairs (5 real pairs, rest stay zero)
    if (tid < 80) {
      int row = tid / 5, p = tid % 5;
      const float* xr = &xseq[((size_t)t*M_ + row0+row)*10];
      int k0 = 2*p, k1 = 2*p+1;
      float f1 = (k1 < 10) ? xr[k1] : 0.f;
      xp_s[p*20 + row] = cvtpk(xr[k0], f1);
    }
    __syncthreads();

    float ar[4]={0,0,0,0}, az[4]={0,0,0,0}, anh[4]={0,0,0,0}, anx[4]={0,0,0,0};
    #pragma unroll
    for (int pc = 0; pc < 32; pc += 4) {
      uint4 h0 = *(const uint4*)&hp_s[(pc+0)*20 + r4];
      uint4 h1 = *(const uint4*)&hp_s[(pc+1)*20 + r4];
      uint4 h2 = *(const uint4*)&hp_s[(pc+2)*20 + r4];
      uint4 h3 = *(const uint4*)&hp_s[(pc+3)*20 + r4];
      uint4 wr4 = *(const uint4*)&W_s[u*44 + pc];
      uint4 wz4 = *(const uint4*)&W_s[(64+u)*44 + pc];
      uint4 wn4 = *(const uint4*)&W_s[(128+u)*44 + pc];
      dot2(ar[0],h0.x,wr4.x); dot2(ar[1],h0.y,wr4.x); dot2(ar[2],h0.z,wr4.x); dot2(ar[3],h0.w,wr4.x);
      dot2(ar[0],h1.x,wr4.y); dot2(ar[1],h1.y,wr4.y); dot2(ar[2],h1.z,wr4.y); dot2(ar[3],h1.w,wr4.y);
      dot2(ar[0],h2.x,wr4.z); dot2(ar[1],h2.y,wr4.z); dot2(ar[2],h2.z,wr4.z); dot2(ar[3],h2.w,wr4.z);
      dot2(ar[0],h3.x,wr4.w); dot2(ar[1],h3.y,wr4.w); dot2(ar[2],h3.z,wr4.w); dot2(ar[3],h3.w,wr4.w);
      dot2(az[0],h0.x,wz4.x); dot2(az[1],h0.y,wz4.x); dot2(az[2],h0.z,wz4.x); dot2(az[3],h0.w,wz4.x);
      dot2(az[0],h1.x,wz4.y); dot2(az[1],h1.y,wz4.y); dot2(az[2],h1.z,wz4.y); dot2(az[3],h1.w,wz4.y);
      dot2(az[0],h2.x,wz4.z); dot2(az[1],h2.y,wz4.z); dot2(az[2],h2.z,wz4.z); dot2(az[3],h2.w,wz4.z);
      dot2(az[0],h3.x,wz4.w); dot2(az[1],h3.y,wz4.w); dot2(az[2],h3.z,wz4.w); dot2(az[3],h3.w,wz4.w);
      dot2(anh[0],h0.x,wn4.x); dot2(anh[1],h0.y,wn4.x); dot2(anh[2],h0.z,wn4.x); dot2(anh[3],h0.w,wn4.x);
      dot2(anh[0],h1.x,wn4.y); dot2(anh[1],h1.y,wn4.y); dot2(anh[2],h1.z,wn4.y); dot2(anh[3],h1.w,wn4.y);
      dot2(anh[0],h2.x,wn4.z); dot2(anh[1],h2.y,wn4.z); dot2(anh[2],h2.z,wn4.z); dot2(anh[3],h2.w,wn4.z);
      dot2(anh[0],h3.x,wn4.w); dot2(anh[1],h3.y,wn4.w); dot2(anh[2],h3.z,wn4.w); dot2(anh[3],h3.w,wn4.w);
    }
    #pragma unroll
    for (int pc = 0; pc < 8; pc += 4) {
      uint4 x0 = *(const uint4*)&xp_s[(pc+0)*20 + r4];
      uint4 x1 = *(const uint4*)&xp_s[(pc+1)*20 + r4];
      uint4 x2 = *(const uint4*)&xp_s[(pc+2)*20 + r4];
      uint4 x3 = *(const uint4*)&xp_s[(pc+3)*20 + r4];
      uint4 wr4 = *(const uint4*)&W_s[u*44 + 36 + pc];
      uint4 wz4 = *(const uint4*)&W_s[(64+u)*44 + 36 + pc];
      uint4 wn4 = *(const uint4*)&W_s[(128+u)*44 + 36 + pc];
      dot2(ar[0],x0.x,wr4.x); dot2(ar[1],x0.y,wr4.x); dot2(ar[2],x0.z,wr4.x); dot2(ar[3],x0.w,wr4.x);
      dot2(ar[0],x1.x,wr4.y); dot2(ar[1],x1.y,wr4.y); dot2(ar[2],x1.z,wr4.y); dot2(ar[3],x1.w,wr4.y);
      dot2(ar[0],x2.x,wr4.z); dot2(ar[1],x2.y,wr4.z); dot2(ar[2],x2.z,wr4.z); dot2(ar[3],x2.w,wr4.z);
      dot2(ar[0],x3.x,wr4.w); dot2(ar[1],x3.y,wr4.w); dot2(ar[2],x3.z,wr4.w); dot2(ar[3],x3.w,wr4.w);
      dot2(az[0],x0.x,wz4.x); dot2(az[1],x0.y,wz4.x); dot2(az[2],x0.z,wz4.x); dot2(az[3],x0.w,wz4.x);
      dot2(az[0],x1.x,wz4.y); dot2(az[1],x1.y,wz4.y); dot2(az[2],x1.z,wz4.y); dot2(az[3],x1.w,wz4.y);
      dot2(az[0],x2.x,wz4.z); dot2(az[1],x2.y,wz4.z); dot2(az[2],x2.z,wz4.z); dot2(az[3],x2.w,wz4.z);
      dot2(az[0],x3.x,wz4.w); dot2(az[1],x3.y,wz4.w); dot2(az[2],x3.z,wz4.w); dot2(az[3],x3.w,wz4.w);
      dot2(anx[0],x0.x,wn4.x); dot2(anx[1],x0.y,wn4.x); dot2(anx[2],x0.z,wn4.x); dot2(anx[3],x0.w,wn4.x);
      dot2(anx[0],x1.x,wn4.y); dot2(anx[1],x1.y,wn4.y); dot2(anx[2],x1.z,wn4.y); dot2(anx[3],x1.w,wn4.y);
      dot2(anx[0],x2.x,wn4.z); dot2(anx[1],x2.y,wn4.z); dot2(anx[2],x2.z,wn4.z); dot2(anx[3],x2.w,wn4.z);
      dot2(anx[0],x3.x,wn4.w); dot2(anx[1],x3.y,wn4.w); dot2(anx[2],x3.z,wn4.w); dot2(anx[3],x3.w,wn4.w);
    }
    float o_new[4];
    #pragma unroll
    for (int rr=0;rr<4;++rr){
      float rg = sigm(ar[rr] + brc);
      float zg = sigm(az[rr] + bzc);
      float ng = tanhf(anx[rr] + bxn + rg*(anh[rr] + bhn));
      o_new[rr] = (1.f - zg)*ng + zg*hreg[rr];
      hreg[rr] = o_new[rr];
    }
    #pragma unroll
    for (int rr=0;rr<4;++rr)
      oseq[(size_t)t*M_*64 + obase[rr] + u] = o_new[rr];
    unsigned pk[4];
    #pragma unroll
    for (int rr=0;rr<4;++rr){
      float pr = __shfl_xor(o_new[rr], 4);
      pk[rr] = cvtpk(o_new[rr], pr);
    }
    __syncthreads();
    if ((u & 1) == 0) {
      #pragma unroll
      for (int rr=0;rr<4;++rr) hp_s[(u>>1)*20 + r4 + rr] = pk[rr];
    }
    __syncthreads();
  }
}

// ---------------- stage C ----------------
__global__ __launch_bounds__(256) void k_stageC(
    const float* __restrict__ out1, const float* __restrict__ emb1,
    const float* __restrict__ w1, const float* __restrict__ b1,
    const float* __restrict__ w2, const float* __restrict__ b2,
    const float* __restrict__ w3, const float* __restrict__ b3,
    float* __restrict__ ndv)
{
  int idx = blockIdx.x*256 + threadIdx.x;
  int m = idx % M_;
  int n = m % N_;
  float rv[64];
  const float4* r4 = (const float4*)(out1 + (size_t)idx*64);
  #pragma unroll
  for (int q=0;q<16;++q){ float4 v=r4[q]; rv[q*4]=v.x; rv[q*4+1]=v.y; rv[q*4+2]=v.z; rv[q*4+3]=v.w; }
  float h1[16];
  for (int u=0;u<16;++u){
    float a = b1[u];
    const float* wr = w1 + u*64;
    #pragma unroll
    for (int c=0;c<64;++c) a += rv[c]*wr[c];
    h1[u] = sigm(a);
  }
  float h2[2];
  #pragma unroll
  for (int v=0;v<2;++v){
    float a = b2[v];
    #pragma unroll
    for (int u=0;u<16;++u) a += h1[u]*w2[v*16+u];
    h2[v] = sigm(a);
  }
  #pragma unroll
  for (int d=0;d<10;++d){
    float f = b3[d] + h2[0]*w3[d*2] + h2[1]*w3[d*2+1];
    ndv[(size_t)idx*10 + d] = tanhf(emb1[n*10+d]*f);
  }
}

// ---------------- stage D ----------------
__global__ __launch_bounds__(256) void k_stageD(
    const float* __restrict__ ndv, const float* __restrict__ out1, float* __restrict__ xg)
{
  int tb = blockIdx.y;
  int tile = blockIdx.x;
  int tid = threadIdx.x;
  __shared__ __align__(16) float V_s[320*12];
  __shared__ __align__(16) unsigned sp_s[32*68];
  __shared__ __align__(16) unsigned op_s[32*68];

  for (int i = tid; i < 320*12; i += 256) {
    int n = i / 12, d = i - n*12;
    V_s[i] = (n < N_ && d < 10) ? ndv[((size_t)tb*N_ + n)*10 + d] : 0.f;
  }
  __syncthreads();

  const int sr  = tid & 63;
  const int smg = tid >> 6;
  float vr[10];
  {
    const float* vp = &V_s[(tile*64 + sr)*12];
    #pragma unroll
    for (int d = 0; d < 10; ++d) vr[d] = vp[d];
  }
  const int rq = tid & 15, cq = tid >> 4;
  const int r4 = rq*4, c4 = cq*4;
  float acc[4][4];
  #pragma unroll
  for (int a=0;a<4;++a)
    #pragma unroll
    for (int b=0;b<4;++b) acc[a][b]=0.f;

  const float* ob = out1 + (size_t)tb*N_*64;
  for (int mc = 0; mc < 320; mc += 64) {
    __syncthreads();
    for (int i = tid; i < 512; i += 256) {
      int p = i >> 4, cgi = i & 15;
      int gm0 = mc + 2*p, gm1 = gm0 + 1;
      float4 a = make_float4(0.f,0.f,0.f,0.f), b = a;
      if (gm0 < N_) a = *(const float4*)&ob[(size_t)gm0*64 + cgi*4];
      if (gm1 < N_) b = *(const float4*)&ob[(size_t)gm1*64 + cgi*4];
      uint4 pk4 = make_uint4(pkh(a.x,b.x), pkh(a.y,b.y), pkh(a.z,b.z), pkh(a.w,b.w));
      *(uint4*)&op_s[p*68 + cgi*4] = pk4;
    }
    #pragma unroll
    for (int j = 0; j < 8; ++j) {
      int m0 = mc + smg*16 + 2*j;
      const float* vm0 = &V_s[m0*12];
      const float* vm1 = &V_s[(m0+1)*12];
      float s0 = vr[0]*vm0[0] + vr[1]*vm0[1] + vr[2]*vm0[2] + vr[3]*vm0[3] + vr[4]*vm0[4]
               + vr[5]*vm0[5] + vr[6]*vm0[6] + vr[7]*vm0[7] + vr[8]*vm0[8] + vr[9]*vm0[9];
      float s1 = vr[0]*vm1[0] + vr[1]*vm1[1] + vr[2]*vm1[2] + vr[3]*vm1[3] + vr[4]*vm1[4]
               + vr[5]*vm1[5] + vr[6]*vm1[6] + vr[7]*vm1[7] + vr[8]*vm1[8] + vr[9]*vm1[9];
      sp_s[(smg*8 + j)*68 + sr] = pkh(fmaxf(s0,0.f), fmaxf(s1,0.f));
    }
    __syncthreads();
    #pragma unroll 8
    for (int p = 0; p < 32; ++p) {
      uint4 sv = *(const uint4*)&sp_s[p*68 + r4];
      uint4 ov = *(const uint4*)&op_s[p*68 + c4];
      doth(acc[0][0], sv.x, ov.x); doth(acc[0][1], sv.x, ov.y); doth(acc[0][2], sv.x, ov.z); doth(acc[0][3], sv.x, ov.w);
      doth(acc[1][0], sv.y, ov.x); doth(acc[1][1], sv.y, ov.y); doth(acc[1][2], sv.y, ov.z); doth(acc[1][3], sv.y, ov.w);
      doth(acc[2][0], sv.z, ov.x); doth(acc[2][1], sv.z, ov.y); doth(acc[2][2], sv.z, ov.z); doth(acc[2][3], sv.z, ov.w);
      doth(acc[3][0], sv.w, ov.x); doth(acc[3][1], sv.w, ov.y); doth(acc[3][2], sv.w, ov.z); doth(acc[3][3], sv.w, ov.w);
    }
  }

  #pragma unroll
  for (int rr = 0; rr < 4; ++rr) {
    int nrow = tile*64 + r4 + rr;
    if (nrow < N_) {
      size_t base = ((size_t)tb*N_ + nrow)*64 + c4;
      float4 o = *(const float4*)&out1[base];
      *(float4*)&xg[base] = make_float4(o.x+acc[rr][0], o.y+acc[rr][1],
                                        o.z+acc[rr][2], o.w+acc[rr][3]);
    }
  }
}

// ---------------- stage E ----------------
__global__ __launch_bounds__(256) void k_stageE(
    const float* xg_in, const float* __restrict__ out1,
    const float* __restrict__ Wf, const float* __restrict__ dw,
    const float* __restrict__ bf,
    float* xg_out)
{
  int n = blockIdx.y;
  int tile = blockIdx.x;
  int tid = threadIdx.x;
  int r = tid >> 3, ug = tid & 7;
  __shared__ __align__(16) float x_s[64*68];
  __shared__ __align__(16) float o_s[64*68];
  __shared__ __align__(16) float Wf_s[64*68];
  __shared__ __align__(16) float dA_s[64*68];
  __shared__ float bf_s[64];
  for (int idx = tid; idx < 64*64; idx += 256) {
    int row = idx >> 6, c = idx & 63;
    size_t g = ((size_t)(tile*64+row)*N_ + n)*64 + c;
    x_s[row*68+c] = xg_in[g];
    o_s[row*68+c] = out1[g];
  }
  for (int idx = tid; idx < 4096; idx += 256) {
    int u = idx >> 6, c = idx & 63;
    Wf_s[u*68+c] = Wf[(size_t)n*4096 + idx];
    dA_s[u*68+c] = dw[u*128 + c];
  }
  if (tid < 64) bf_s[tid] = bf[n*64 + tid];
  __syncthreads();

  float g2a[8], g2b[8];
  #pragma unroll
  for (int uu=0;uu<8;++uu){ g2a[uu] = bf_s[ug+8*uu]; g2b[uu] = g2a[uu]; }

  for (int c = 0; c < 64; c += 4) {
    float4 xa = *(const float4*)&x_s[r*68 + c];
    float4 xb = *(const float4*)&x_s[(r+32)*68 + c];
    float4 oa = *(const float4*)&o_s[r*68 + c];
    float4 ob = *(const float4*)&o_s[(r+32)*68 + c];
    #pragma unroll
    for (int uu=0;uu<8;++uu){
      int u = ug + 8*uu;
      float4 wf = *(const float4*)&Wf_s[u*68 + c];
      float4 da = *(const float4*)&dA_s[u*68 + c];
      g2a[uu] += oa.x*da.x + oa.y*da.y + oa.z*da.z + oa.w*da.w
               + xa.x*wf.x + xa.y*wf.y + xa.z*wf.z + xa.w*wf.w;
      g2b[uu] += ob.x*da.x + ob.y*da.y + ob.z*da.z + ob.w*da.w
               + xb.x*wf.x + xb.y*wf.y + xb.z*wf.z + xb.w*wf.w;
    }
  }
  size_t ba = ((size_t)(tile*64+r)*N_ + n)*64;
  size_t bb = ((size_t)(tile*64+r+32)*N_ + n)*64;
  #pragma unroll
  for (int uu=0;uu<8;++uu){
    xg_out[ba + ug + 8*uu] = g2a[uu];
    xg_out[bb + ug + 8*uu] = g2b[uu];
  }
}

extern "C" void kernel_launch(void* const* d_in, const int* in_sizes, int n_in,
                              void* d_out, int out_size, void* d_ws, size_t ws_size,
                              hipStream_t stream)
{
  (void)in_sizes; (void)n_in; (void)out_size;
  const float* x    = (const float*)d_in[0];
  const float* emb1 = (const float*)d_in[1];
  const float* emb2 = (const float*)d_in[2];
  const float* xw1  = (const float*)d_in[3];
  const float* xb1  = (const float*)d_in[4];
  const float* xw2  = (const float*)d_in[5];
  const float* xb2  = (const float*)d_in[6];
  const float* xw3  = (const float*)d_in[7];
  const float* xb3  = (const float*)d_in[8];
  const float* fw1  = (const float*)d_in[9];
  const float* fb1  = (const float*)d_in[10];
  const float* fw2  = (const float*)d_in[11];
  const float* fb2  = (const float*)d_in[12];
  const float* fw3  = (const float*)d_in[13];
  const float* fb3  = (const float*)d_in[14];
  const float* c2w1 = (const float*)d_in[15];
  const float* c2b1 = (const float*)d_in[16];
  const float* c2w2 = (const float*)d_in[17];
  const float* c2b2 = (const float*)d_in[18];
  const float* c2w3 = (const float*)d_in[19];
  const float* c2b3 = (const float*)d_in[20];
  const float* g1wih= (const float*)d_in[21];
  const float* g1whh= (const float*)d_in[22];
  const float* g1bih= (const float*)d_in[23];
  const float* g1bhh= (const float*)d_in[24];
  const float* g2wih= (const float*)d_in[25];
  const float* g2whh= (const float*)d_in[26];
  const float* g2bih= (const float*)d_in[27];
  const float* g2bhh= (const float*)d_in[28];
  const float* wpool= (const float*)d_in[29];
  const float* bpool= (const float*)d_in[30];
  const float* dww  = (const float*)d_in[31];
  const float* dwb  = (const float*)d_in[32];
  float* out = (float*)d_out;

  float* ws = (float*)d_ws;
  float* g1_in = ws;                          // TM*10
  float* out1  = g1_in + (size_t)TM_*10;      // TM*64
  float* ndv   = out1 + (size_t)TM_*64;       // TM*10
  float* xg    = ndv + (size_t)TM_*10;        // TM*64
  float* Wn    = xg + (size_t)TM_*64;         // N*4096
  float* bn    = Wn + (size_t)N_*4096;        // N*64
  float* Wf    = bn + (size_t)N_*64;          // N*4096
  float* bf    = Wf + (size_t)N_*4096;        // N*64
  unsigned* Wpk2 = (unsigned*)(bf + (size_t)N_*64);   // 64*192
  unsigned* Wpk1 = Wpk2 + 64*192;                     // 38*192
  unsigned* Wq2  = Wpk1 + 38*192;                     // 192*36
  unsigned* Wq1  = Wq2 + 192*36;                      // 192*44
  unsigned* Wxq2 = Wq1 + 192*44;                      // 192*36
  unsigned short* xwh = (unsigned short*)(Wxq2 + 192*36);  // TM*192 f16
  size_t need_old = ((size_t)((float*)Wq2 - ws)) * 4;
  size_t need_new = ((size_t)((char*)(xwh + (size_t)TM_*192) - (char*)ws));
  if (ws_size < need_old) return;
  bool use_new = (ws_size >= need_new);

  k_stageA<<<TM_/256, 256, 0, stream>>>(x, xw1,xb1,xw2,xb2,xw3,xb3, fw1,fb1,fw2,fb2,fw3,fb3, g1_in);
  k_wn<<<N_, 256, 0, stream>>>(emb2, wpool, bpool, Wn, bn);
  k_wf<<<N_, 256, 0, stream>>>(Wn, bn, dww, dwb, Wf, bf);

  if (use_new) {
    k_wpack2<<<(192*36 + 192*44 + 255)/256, 256, 0, stream>>>(
        g2wih, g2whh, g1wih, g1whh, Wq2, Wxq2, Wq1);
    k_gruX<<<M_/16, 256, 0, stream>>>(g1_in, Wq1, g1bih, g1bhh, out1);
    k_stageC<<<TM_/256, 256, 0, stream>>>(out1, emb1, c2w1,c2b1,c2w2,c2b2,c2w3,c2b3, ndv);
    k_stageD<<<dim3(5, T_*B_), 256, 0, stream>>>(ndv, out1, xg);
    k_stageE<<<dim3(12, N_), 256, 0, stream>>>(xg, out1, Wf, dww, bf, xg);
    k_xw<<<TM_/16, 256, 0, stream>>>(xg, Wxq2, g2bih, xwh);
    k_gruH<<<M_/16, 256, 0, stream>>>(xwh, Wq2, g2bhh, out);
  } else {
    k_wpack<<<(64*192 + 38*192 + 255)/256, 256, 0, stream>>>(g2wih, g2whh, g1wih, g1whh, Wpk2, Wpk1);
    k_gruD<6,true,false><<<M_/16, 256, 0, stream>>>(g1_in, Wpk1, g1bih, g1bhh, out1, nullptr);
    k_stageC<<<TM_/256, 256, 0, stream>>>(out1, emb1, c2w1,c2b1,c2w2,c2b2,c2w3,c2b3, ndv);
    k_stageD<<<dim3(5, T_*B_), 256, 0, stream>>>(ndv, out1, xg);
    k_stageE<<<dim3(12, N_), 256, 0, stream>>>(xg, out1, Wf, dww, bf, xg);
    k_gruD<32,false,true><<<M_/16, 256, 0, stream>>>(xg, Wpk2, g2bih, g2bhh, nullptr, out);
  }
}

// Round 10
// 487.681 us; speedup vs baseline: 31.2831x; 1.0932x over previous
//
#include <hip/hip_runtime.h>
#include <hip/hip_fp16.h>
#include <math.h>

#define B_ 64
#define T_ 12
#define N_ 307
#define I_ 3
#define R_ 64
#define D_ 10
#define M_ (B_*N_)      // 19648
#define TM_ (T_*M_)     // 235776

typedef _Float16 f16x8 __attribute__((ext_vector_type(8)));
typedef float f32x4 __attribute__((ext_vector_type(4)));

__device__ __forceinline__ float sigm(float x){ return 1.f/(1.f+__expf(-x)); }

__device__ __forceinline__ unsigned cvtpk(float a, float b){
  unsigned r;
  asm("v_cvt_pk_bf16_f32 %0, %1, %2" : "=v"(r) : "v"(a), "v"(b));
  return r;
}
__device__ __forceinline__ void dot2(float& acc, unsigned a, unsigned b){
  asm("v_dot2_f32_bf16 %0, %1, %2, %0" : "+v"(acc) : "v"(a), "v"(b));
}
__device__ __forceinline__ unsigned pkh(float a, float b){
  unsigned r;
  asm("v_cvt_pkrtz_f16_f32 %0, %1, %2" : "=v"(r) : "v"(a), "v"(b));
  return r;
}
__device__ __forceinline__ void doth(float& acc, unsigned a, unsigned b){
  asm("v_dot2_f32_f16 %0, %1, %2, %0" : "+v"(acc) : "v"(a), "v"(b));
}

// ---------------- stage A ----------------
__global__ __launch_bounds__(256) void k_stageA(
    const float* __restrict__ x,
    const float* __restrict__ xw1, const float* __restrict__ xb1,
    const float* __restrict__ xw2, const float* __restrict__ xb2,
    const float* __restrict__ xw3, const float* __restrict__ xb3,
    const float* __restrict__ fw1, const float* __restrict__ fb1,
    const float* __restrict__ fw2, const float* __restrict__ fb2,
    const float* __restrict__ fw3, const float* __restrict__ fb3,
    float* __restrict__ g1)
{
  int idx = blockIdx.x*256 + threadIdx.x;
  int t = idx / M_;
  int m = idx - t*M_;
  int b = m / N_;
  int n = m - b*N_;
  const float* xp = x + (((size_t)b*T_ + t)*N_ + n)*I_;
  float xv[3] = {xp[0], xp[1], xp[2]};
  float e[3][10];
  #pragma unroll
  for (int i=0;i<3;++i){
    float h1[16];
    #pragma unroll
    for (int u=0;u<16;++u) h1[u] = sigm(xv[i]*xw1[u] + xb1[u]);
    float h2[2];
    #pragma unroll
    for (int v=0;v<2;++v){
      float a = xb2[v];
      #pragma unroll
      for (int u=0;u<16;++u) a += h1[u]*xw2[v*16+u];
      h2[v] = sigm(a);
    }
    #pragma unroll
    for (int d=0;d<10;++d) e[i][d] = xb3[d] + h2[0]*xw3[d*2] + h2[1]*xw3[d*2+1];
  }
  float in1[3];
  #pragma unroll
  for (int j=0;j<3;++j){
    float acc = 0.f;
    #pragma unroll
    for (int i=0;i<3;++i){
      float s = 0.f;
      #pragma unroll
      for (int d=0;d<10;++d) s += e[j][d]*e[i][d];
      s = fmaxf(s, 0.f);
      acc += s*xv[i];
    }
    in1[j] = xv[j] + acc;
  }
  float h1[16];
  #pragma unroll
  for (int u=0;u<16;++u)
    h1[u] = sigm(fb1[u] + in1[0]*fw1[u*3] + in1[1]*fw1[u*3+1] + in1[2]*fw1[u*3+2]);
  float h2[2];
  #pragma unroll
  for (int v=0;v<2;++v){
    float a = fb2[v];
    #pragma unroll
    for (int u=0;u<16;++u) a += h1[u]*fw2[v*16+u];
    h2[v] = sigm(a);
  }
  float* gp = g1 + (size_t)idx*10;
  #pragma unroll
  for (int d=0;d<10;++d) gp[d] = fb3[d] + h2[0]*fw3[d*2] + h2[1]*fw3[d*2+1];
}

// ---------------- k_wn ----------------
__global__ __launch_bounds__(256) void k_wn(
    const float* __restrict__ emb2, const float* __restrict__ wpool,
    const float* __restrict__ bpool, float* __restrict__ Wn, float* __restrict__ bn)
{
  int n = blockIdx.x; int tid = threadIdx.x;
  __shared__ float e_s[10];
  if (tid < 10) e_s[tid] = emb2[n*10 + tid];
  __syncthreads();
  #pragma unroll
  for (int e=0;e<16;++e){
    int i = e*256 + tid;
    float a = 0.f;
    #pragma unroll
    for (int d=0;d<10;++d) a += e_s[d]*wpool[(size_t)d*4096 + i];
    Wn[(size_t)n*4096 + i] = a;
  }
  if (tid < 64){
    float a = 0.f;
    #pragma unroll
    for (int d=0;d<10;++d) a += e_s[d]*bpool[d*64 + tid];
    bn[n*64 + tid] = a;
  }
}

// ---------------- k_wf ----------------
__global__ __launch_bounds__(256) void k_wf(
    const float* __restrict__ Wn, const float* __restrict__ bn,
    const float* __restrict__ dw, const float* __restrict__ db,
    float* __restrict__ Wf, float* __restrict__ bf)
{
  int n = blockIdx.x; int tid = threadIdx.x;
  __shared__ float WnS[64*68];
  __shared__ float dwBT[64*68];
  __shared__ float bn_s[64];
  for (int idx = tid; idx < 4096; idx += 256) {
    int c = idx >> 6, r = idx & 63;
    WnS[c*68 + r] = Wn[(size_t)n*4096 + idx];
  }
  for (int idx = tid; idx < 4096; idx += 256) {
    int u = idx >> 6, r = idx & 63;
    dwBT[r*68 + u] = dw[u*128 + 64 + r];
  }
  if (tid < 64) bn_s[tid] = bn[n*64 + tid];
  __syncthreads();
  int u = tid & 63, cg = tid >> 6;
  #pragma unroll
  for (int j = 0; j < 16; ++j) {
    int c = cg*16 + j;
    float acc = 0.f;
    #pragma unroll 8
    for (int r = 0; r < 64; ++r) acc += WnS[c*68 + r] * dwBT[r*68 + u];
    Wf[(size_t)n*4096 + u*64 + c] = acc;
  }
  if (tid < 64) {
    float acc = db[tid];
    #pragma unroll 8
    for (int r = 0; r < 64; ++r) acc += bn_s[r] * dwBT[r*68 + tid];
    bf[n*64 + tid] = acc;
  }
}

// ---------------- old pair-major packing (fallback path) ----------------
__global__ __launch_bounds__(256) void k_wpack(
    const float* __restrict__ wih2, const float* __restrict__ whh2,
    const float* __restrict__ wih1, const float* __restrict__ whh1,
    unsigned* __restrict__ Wpk2, unsigned* __restrict__ Wpk1)
{
  int i = blockIdx.x*256 + threadIdx.x;
  if (i < 64*192) {
    int p = i / 192, wr = i - (i/192)*192;
    int k0 = 2*p, k1 = 2*p + 1;
    float f0 = (k0 < 64) ? whh2[wr*64 + k0] : wih2[wr*64 + (k0-64)];
    float f1 = (k1 < 64) ? whh2[wr*64 + k1] : wih2[wr*64 + (k1-64)];
    Wpk2[i] = cvtpk(f0, f1);
  }
  int j = i - 64*192;
  if (j >= 0 && j < 38*192) {
    int p = j / 192, wr = j - (j/192)*192;
    int k0 = 2*p, k1 = 2*p + 1;
    float f0 = (k0 < 64) ? whh1[wr*64 + k0] : ((k0-64) < 10 ? wih1[wr*10 + (k0-64)] : 0.f);
    float f1 = (k1 < 64) ? whh1[wr*64 + k1] : ((k1-64) < 10 ? wih1[wr*10 + (k1-64)] : 0.f);
    Wpk1[j] = cvtpk(f0, f1);
  }
}

// ---------------- u-major packing ----------------
__global__ __launch_bounds__(256) void k_wpack2(
    const float* __restrict__ wih2, const float* __restrict__ whh2,
    const float* __restrict__ wih1, const float* __restrict__ whh1,
    unsigned* __restrict__ Wq2, unsigned* __restrict__ Wxq2, unsigned* __restrict__ Wq1)
{
  int i = blockIdx.x*256 + threadIdx.x;
  if (i < 192*36) {
    int wr = i / 36, c = i - wr*36;
    unsigned v = 0u;
    if (c < 32) v = cvtpk(whh2[wr*64 + 2*c], whh2[wr*64 + 2*c + 1]);
    Wq2[i] = v;
    unsigned vx = 0u;
    if (c < 32) vx = cvtpk(wih2[wr*64 + 2*c], wih2[wr*64 + 2*c + 1]);
    Wxq2[i] = vx;
  }
  int j = i - 192*36;
  if (j >= 0 && j < 192*44) {
    int wr = j / 44, c = j - wr*44;
    unsigned v = 0u;
    if (c < 32) {
      v = cvtpk(whh1[wr*64 + 2*c], whh1[wr*64 + 2*c + 1]);
    } else if (c >= 36 && c < 41) {
      int p = c - 36, k0 = 2*p, k1 = 2*p + 1;
      float f0 = (k0 < 10) ? wih1[wr*10 + k0] : 0.f;
      float f1 = (k1 < 10) ? wih1[wr*10 + k1] : 0.f;
      v = cvtpk(f0, f1);
    }
    Wq1[j] = v;
  }
}

// ---------------- old combined scan (fallback path) ----------------
template<int XP2, bool WSEQ, bool WFIN>
__global__ __launch_bounds__(256) void k_gruD(
    const float* __restrict__ xseq,
    const unsigned* __restrict__ Wpk,
    const float* __restrict__ bih, const float* __restrict__ bhh,
    float* __restrict__ oseq, float* __restrict__ ofin)
{
  constexpr int P2 = 32 + XP2;
  __shared__ __align__(16) unsigned W_s[P2*192];
  __shared__ __align__(16) unsigned hp_s[32*20];
  __shared__ __align__(16) unsigned xp_s[XP2*20];
  const int tid = threadIdx.x;
  const int row0 = blockIdx.x * 16;
  const int tr = tid & 3, u = tid >> 2;
  const int r4 = tr*4;

  for (int i = tid; i < P2*192; i += 256) W_s[i] = Wpk[i];
  for (int i = tid; i < 32*20; i += 256) hp_s[i] = 0u;

  const float brc = bih[u]     + bhh[u];
  const float bzc = bih[64+u]  + bhh[64+u];
  const float bxn = bih[128+u];
  const float bhn = bhh[128+u];

  size_t obase[4];
  #pragma unroll
  for (int rr=0;rr<4;++rr){
    int g = row0 + r4 + rr;
    if (WFIN){
      int bb = g / N_, nn = g - bb*N_;
      obase[rr] = (((size_t)bb*T_)*N_ + nn)*64;
    } else {
      obase[rr] = (size_t)g*64;
    }
  }
  float hreg[4] = {0.f, 0.f, 0.f, 0.f};

  if (XP2 == 32) {
    for (int idx = tid; idx < 512; idx += 256) {
      int row = idx >> 5, p = idx & 31;
      const float2 v = *(const float2*)&xseq[((size_t)(row0+row))*64 + 2*p];
      xp_s[p*20 + row] = cvtpk(v.x, v.y);
    }
  } else {
    if (tid < 16*XP2) {
      int row = tid / XP2, p = tid - (tid/XP2)*XP2;
      int k0 = 2*p, k1 = 2*p + 1;
      const float* xr = &xseq[((size_t)(row0+row))*10];
      float f0 = (k0 < 10) ? xr[k0] : 0.f;
      float f1 = (k1 < 10) ? xr[k1] : 0.f;
      xp_s[p*20 + row] = cvtpk(f0, f1);
    }
  }
  __syncthreads();

  for (int t = 0; t < T_; ++t) {
    float ar[4]={0,0,0,0}, az[4]={0,0,0,0}, anh[4]={0,0,0,0}, anx[4]={0,0,0,0};
    #pragma unroll 4
    for (int p = 0; p < 32; ++p) {
      uint4 a = *(const uint4*)&hp_s[p*20 + r4];
      unsigned wr_ = W_s[p*192 + u];
      unsigned wz_ = W_s[p*192 + 64 + u];
      unsigned wn_ = W_s[p*192 + 128 + u];
      dot2(ar[0], a.x, wr_); dot2(ar[1], a.y, wr_); dot2(ar[2], a.z, wr_); dot2(ar[3], a.w, wr_);
      dot2(az[0], a.x, wz_); dot2(az[1], a.y, wz_); dot2(az[2], a.z, wz_); dot2(az[3], a.w, wz_);
      dot2(anh[0], a.x, wn_); dot2(anh[1], a.y, wn_); dot2(anh[2], a.z, wn_); dot2(anh[3], a.w, wn_);
    }
    #pragma unroll 4
    for (int p = 0; p < XP2; ++p) {
      uint4 a = *(const uint4*)&xp_s[p*20 + r4];
      unsigned wr_ = W_s[(32+p)*192 + u];
      unsigned wz_ = W_s[(32+p)*192 + 64 + u];
      unsigned wn_ = W_s[(32+p)*192 + 128 + u];
      dot2(ar[0], a.x, wr_); dot2(ar[1], a.y, wr_); dot2(ar[2], a.z, wr_); dot2(ar[3], a.w, wr_);
      dot2(az[0], a.x, wz_); dot2(az[1], a.y, wz_); dot2(az[2], a.z, wz_); dot2(az[3], a.w, wz_);
      dot2(anx[0], a.x, wn_); dot2(anx[1], a.y, wn_); dot2(anx[2], a.z, wn_); dot2(anx[3], a.w, wn_);
    }
    float o_new[4];
    #pragma unroll
    for (int rr=0;rr<4;++rr){
      float rg = sigm(ar[rr] + brc);
      float zg = sigm(az[rr] + bzc);
      float ng = tanhf(anx[rr] + bxn + rg*(anh[rr] + bhn));
      o_new[rr] = (1.f - zg)*ng + zg*hreg[rr];
      hreg[rr] = o_new[rr];
    }
    #pragma unroll
    for (int rr=0;rr<4;++rr){
      if (WSEQ) oseq[(size_t)t*M_*64 + obase[rr] + u] = o_new[rr];
      if (WFIN) ofin[obase[rr] + (size_t)t*N_*64 + u] = o_new[rr];
    }
    unsigned pk[4];
    #pragma unroll
    for (int rr=0;rr<4;++rr){
      float pr = __shfl_xor(o_new[rr], 4);
      pk[rr] = cvtpk(o_new[rr], pr);
    }
    __syncthreads();
    if ((u & 1) == 0) {
      #pragma unroll
      for (int rr=0;rr<4;++rr) hp_s[(u>>1)*20 + r4 + rr] = pk[rr];
    }
    if (t+1 < T_) {
      if (XP2 == 32) {
        for (int idx = tid; idx < 512; idx += 256) {
          int row = idx >> 5, p = idx & 31;
          const float2 v = *(const float2*)&xseq[((size_t)(t+1)*M_ + row0+row)*64 + 2*p];
          xp_s[p*20 + row] = cvtpk(v.x, v.y);
        }
      } else {
        if (tid < 16*XP2) {
          int row = tid / XP2, p = tid - (tid/XP2)*XP2;
          int k0 = 2*p, k1 = 2*p + 1;
          const float* xr = &xseq[((size_t)(t+1)*M_ + row0+row)*10];
          float f0 = (k0 < 10) ? xr[k0] : 0.f;
          float f1 = (k1 < 10) ? xr[k1] : 0.f;
          xp_s[p*20 + row] = cvtpk(f0, f1);
        }
      }
    }
    __syncthreads();
  }
}

// ---------------- k_xw: xw2 = g2 @ wih2^T + bih2 -> f16 [TM][192] ----------------
__global__ __launch_bounds__(256) void k_xw(
    const float* __restrict__ g2, const unsigned* __restrict__ Wxq,
    const float* __restrict__ bih, unsigned short* __restrict__ xwh)
{
  __shared__ __align__(16) unsigned W_s[192*36];
  __shared__ __align__(16) unsigned xp_s[32*20];
  const int tid = threadIdx.x;
  const int row0 = blockIdx.x * 16;
  const int tr = tid & 3, u = tid >> 2;
  const int r4 = tr*4;

  for (int i = tid; i < 192*36; i += 256) W_s[i] = Wxq[i];
  for (int idx = tid; idx < 512; idx += 256) {
    int row = idx >> 5, p = idx & 31;
    const float2 v = *(const float2*)&g2[((size_t)(row0+row))*64 + 2*p];
    xp_s[p*20 + row] = cvtpk(v.x, v.y);
  }
  const float bi_r = bih[u], bi_z = bih[64+u], bi_n = bih[128+u];
  __syncthreads();

  float ar[4]={0,0,0,0}, az[4]={0,0,0,0}, an[4]={0,0,0,0};
  #pragma unroll
  for (int pc = 0; pc < 32; pc += 4) {
    uint4 h0 = *(const uint4*)&xp_s[(pc+0)*20 + r4];
    uint4 h1 = *(const uint4*)&xp_s[(pc+1)*20 + r4];
    uint4 h2 = *(const uint4*)&xp_s[(pc+2)*20 + r4];
    uint4 h3 = *(const uint4*)&xp_s[(pc+3)*20 + r4];
    uint4 wr4 = *(const uint4*)&W_s[u*36 + pc];
    uint4 wz4 = *(const uint4*)&W_s[(64+u)*36 + pc];
    uint4 wn4 = *(const uint4*)&W_s[(128+u)*36 + pc];
    dot2(ar[0],h0.x,wr4.x); dot2(ar[1],h0.y,wr4.x); dot2(ar[2],h0.z,wr4.x); dot2(ar[3],h0.w,wr4.x);
    dot2(ar[0],h1.x,wr4.y); dot2(ar[1],h1.y,wr4.y); dot2(ar[2],h1.z,wr4.y); dot2(ar[3],h1.w,wr4.y);
    dot2(ar[0],h2.x,wr4.z); dot2(ar[1],h2.y,wr4.z); dot2(ar[2],h2.z,wr4.z); dot2(ar[3],h2.w,wr4.z);
    dot2(ar[0],h3.x,wr4.w); dot2(ar[1],h3.y,wr4.w); dot2(ar[2],h3.z,wr4.w); dot2(ar[3],h3.w,wr4.w);
    dot2(az[0],h0.x,wz4.x); dot2(az[1],h0.y,wz4.x); dot2(az[2],h0.z,wz4.x); dot2(az[3],h0.w,wz4.x);
    dot2(az[0],h1.x,wz4.y); dot2(az[1],h1.y,wz4.y); dot2(az[2],h1.z,wz4.y); dot2(az[3],h1.w,wz4.y);
    dot2(az[0],h2.x,wz4.z); dot2(az[1],h2.y,wz4.z); dot2(az[2],h2.z,wz4.z); dot2(az[3],h2.w,wz4.z);
    dot2(az[0],h3.x,wz4.w); dot2(az[1],h3.y,wz4.w); dot2(az[2],h3.z,wz4.w); dot2(az[3],h3.w,wz4.w);
    dot2(an[0],h0.x,wn4.x); dot2(an[1],h0.y,wn4.x); dot2(an[2],h0.z,wn4.x); dot2(an[3],h0.w,wn4.x);
    dot2(an[0],h1.x,wn4.y); dot2(an[1],h1.y,wn4.y); dot2(an[2],h1.z,wn4.y); dot2(an[3],h1.w,wn4.y);
    dot2(an[0],h2.x,wn4.z); dot2(an[1],h2.y,wn4.z); dot2(an[2],h2.z,wn4.z); dot2(an[3],h2.w,wn4.z);
    dot2(an[0],h3.x,wn4.w); dot2(an[1],h3.y,wn4.w); dot2(an[2],h3.z,wn4.w); dot2(an[3],h3.w,wn4.w);
  }
  #pragma unroll
  for (int rr = 0; rr < 4; ++rr) {
    size_t rbase = (size_t)(row0 + r4 + rr)*192;
    float vr_ = ar[rr] + bi_r;
    float vz_ = az[rr] + bi_z;
    float vn_ = an[rr] + bi_n;
    float pr = __shfl_xor(vr_, 4);
    float pz = __shfl_xor(vz_, 4);
    float pn = __shfl_xor(vn_, 4);
    if ((u & 1) == 0) {
      *(unsigned*)&xwh[rbase + u]        = pkh(vr_, pr);
      *(unsigned*)&xwh[rbase + 64 + u]   = pkh(vz_, pz);
      *(unsigned*)&xwh[rbase + 128 + u]  = pkh(vn_, pn);
    }
  }
}

// ---------------- k_gruH: GRU2 scan, h-only; xw streamed from global f16 ----------------
__global__ __launch_bounds__(256) void k_gruH(
    const unsigned short* __restrict__ xwh,
    const unsigned* __restrict__ Wq,
    const float* __restrict__ bhh,
    float* __restrict__ ofin)
{
  __shared__ __align__(16) unsigned W_s[192*36];
  __shared__ __align__(16) unsigned hp_s[32*20];
  const int tid = threadIdx.x;
  const int row0 = blockIdx.x * 16;
  const int tr = tid & 3, u = tid >> 2;
  const int r4 = tr*4;

  for (int i = tid; i < 192*36; i += 256) W_s[i] = Wq[i];
  for (int i = tid; i < 32*20; i += 256) hp_s[i] = 0u;

  const float bh_r = bhh[u], bh_z = bhh[64+u], bh_n = bhh[128+u];
  size_t obase[4];
  #pragma unroll
  for (int rr=0;rr<4;++rr){
    int g = row0 + r4 + rr;
    int bb = g / N_, nn = g - bb*N_;
    obase[rr] = (((size_t)bb*T_)*N_ + nn)*64;
  }
  float hreg[4] = {0.f,0.f,0.f,0.f};
  const __half* xh = (const __half*)xwh;
  __syncthreads();

  for (int t = 0; t < T_; ++t) {
    float xr_[4], xz_[4], xn_[4];
    #pragma unroll
    for (int rr=0;rr<4;++rr){
      size_t base = ((size_t)t*M_ + row0 + r4 + rr)*192 + u;
      xr_[rr] = __half2float(xh[base]);
      xz_[rr] = __half2float(xh[base+64]);
      xn_[rr] = __half2float(xh[base+128]);
    }
    float ar[4]={0,0,0,0}, az[4]={0,0,0,0}, anh[4]={0,0,0,0};
    #pragma unroll
    for (int pc = 0; pc < 32; pc += 4) {
      uint4 h0 = *(const uint4*)&hp_s[(pc+0)*20 + r4];
      uint4 h1 = *(const uint4*)&hp_s[(pc+1)*20 + r4];
      uint4 h2 = *(const uint4*)&hp_s[(pc+2)*20 + r4];
      uint4 h3 = *(const uint4*)&hp_s[(pc+3)*20 + r4];
      uint4 wr4 = *(const uint4*)&W_s[u*36 + pc];
      uint4 wz4 = *(const uint4*)&W_s[(64+u)*36 + pc];
      uint4 wn4 = *(const uint4*)&W_s[(128+u)*36 + pc];
      dot2(ar[0],h0.x,wr4.x); dot2(ar[1],h0.y,wr4.x); dot2(ar[2],h0.z,wr4.x); dot2(ar[3],h0.w,wr4.x);
      dot2(ar[0],h1.x,wr4.y); dot2(ar[1],h1.y,wr4.y); dot2(ar[2],h1.z,wr4.y); dot2(ar[3],h1.w,wr4.y);
      dot2(ar[0],h2.x,wr4.z); dot2(ar[1],h2.y,wr4.z); dot2(ar[2],h2.z,wr4.z); dot2(ar[3],h2.w,wr4.z);
      dot2(ar[0],h3.x,wr4.w); dot2(ar[1],h3.y,wr4.w); dot2(ar[2],h3.z,wr4.w); dot2(ar[3],h3.w,wr4.w);
      dot2(az[0],h0.x,wz4.x); dot2(az[1],h0.y,wz4.x); dot2(az[2],h0.z,wz4.x); dot2(az[3],h0.w,wz4.x);
      dot2(az[0],h1.x,wz4.y); dot2(az[1],h1.y,wz4.y); dot2(az[2],h1.z,wz4.y); dot2(az[3],h1.w,wz4.y);
      dot2(az[0],h2.x,wz4.z); dot2(az[1],h2.y,wz4.z); dot2(az[2],h2.z,wz4.z); dot2(az[3],h2.w,wz4.z);
      dot2(az[0],h3.x,wz4.w); dot2(az[1],h3.y,wz4.w); dot2(az[2],h3.z,wz4.w); dot2(az[3],h3.w,wz4.w);
      dot2(anh[0],h0.x,wn4.x); dot2(anh[1],h0.y,wn4.x); dot2(anh[2],h0.z,wn4.x); dot2(anh[3],h0.w,wn4.x);
      dot2(anh[0],h1.x,wn4.y); dot2(anh[1],h1.y,wn4.y); dot2(anh[2],h1.z,wn4.y); dot2(anh[3],h1.w,wn4.y);
      dot2(anh[0],h2.x,wn4.z); dot2(anh[1],h2.y,wn4.z); dot2(anh[2],h2.z,wn4.z); dot2(anh[3],h2.w,wn4.z);
      dot2(anh[0],h3.x,wn4.w); dot2(anh[1],h3.y,wn4.w); dot2(anh[2],h3.z,wn4.w); dot2(anh[3],h3.w,wn4.w);
    }
    float o_new[4];
    #pragma unroll
    for (int rr=0;rr<4;++rr){
      float rg = sigm(ar[rr] + xr_[rr] + bh_r);
      float zg = sigm(az[rr] + xz_[rr] + bh_z);
      float ng = tanhf(xn_[rr] + rg*(anh[rr] + bh_n));
      o_new[rr] = (1.f - zg)*ng + zg*hreg[rr];
      hreg[rr] = o_new[rr];
    }
    #pragma unroll
    for (int rr=0;rr<4;++rr)
      ofin[obase[rr] + (size_t)t*N_*64 + u] = o_new[rr];
    unsigned pk[4];
    #pragma unroll
    for (int rr=0;rr<4;++rr){
      float pr = __shfl_xor(o_new[rr], 4);
      pk[rr] = cvtpk(o_new[rr], pr);
    }
    __syncthreads();
    if ((u & 1) == 0) {
      #pragma unroll
      for (int rr=0;rr<4;++rr) hp_s[(u>>1)*20 + r4 + rr] = pk[rr];
    }
    __syncthreads();
  }
}

// ---------------- k_gruX: GRU1 scan ----------------
__global__ __launch_bounds__(256) void k_gruX(
    const float* __restrict__ xseq,
    const unsigned* __restrict__ Wq,
    const float* __restrict__ bih, const float* __restrict__ bhh,
    float* __restrict__ oseq)
{
  __shared__ __align__(16) unsigned W_s[192*44];
  __shared__ __align__(16) unsigned hp_s[32*20];
  __shared__ __align__(16) unsigned xp_s[8*20];
  const int tid = threadIdx.x;
  const int row0 = blockIdx.x * 16;
  const int tr = tid & 3, u = tid >> 2;
  const int r4 = tr*4;

  for (int i = tid; i < 192*44; i += 256) W_s[i] = Wq[i];
  for (int i = tid; i < 32*20; i += 256) hp_s[i] = 0u;
  for (int i = tid; i < 8*20; i += 256) xp_s[i] = 0u;

  const float brc = bih[u]    + bhh[u];
  const float bzc = bih[64+u] + bhh[64+u];
  const float bxn = bih[128+u];
  const float bhn = bhh[128+u];
  size_t obase[4];
  #pragma unroll
  for (int rr=0;rr<4;++rr) obase[rr] = (size_t)(row0 + r4 + rr)*64;
  float hreg[4] = {0.f,0.f,0.f,0.f};
  __syncthreads();

  for (int t = 0; t < T_; ++t) {
    if (tid < 80) {
      int row = tid / 5, p = tid % 5;
      const float* xr = &xseq[((size_t)t*M_ + row0+row)*10];
      int k0 = 2*p, k1 = 2*p+1;
      float f1 = (k1 < 10) ? xr[k1] : 0.f;
      xp_s[p*20 + row] = cvtpk(xr[k0], f1);
    }
    __syncthreads();

    float ar[4]={0,0,0,0}, az[4]={0,0,0,0}, anh[4]={0,0,0,0}, anx[4]={0,0,0,0};
    #pragma unroll
    for (int pc = 0; pc < 32; pc += 4) {
      uint4 h0 = *(const uint4*)&hp_s[(pc+0)*20 + r4];
      uint4 h1 = *(const uint4*)&hp_s[(pc+1)*20 + r4];
      uint4 h2 = *(const uint4*)&hp_s[(pc+2)*20 + r4];
      uint4 h3 = *(const uint4*)&hp_s[(pc+3)*20 + r4];
      uint4 wr4 = *(const uint4*)&W_s[u*44 + pc];
      uint4 wz4 = *(const uint4*)&W_s[(64+u)*44 + pc];
      uint4 wn4 = *(const uint4*)&W_s[(128+u)*44 + pc];
      dot2(ar[0],h0.x,wr4.x); dot2(ar[1],h0.y,wr4.x); dot2(ar[2],h0.z,wr4.x); dot2(ar[3],h0.w,wr4.x);
      dot2(ar[0],h1.x,wr4.y); dot2(ar[1],h1.y,wr4.y); dot2(ar[2],h1.z,wr4.y); dot2(ar[3],h1.w,wr4.y);
      dot2(ar[0],h2.x,wr4.z); dot2(ar[1],h2.y,wr4.z); dot2(ar[2],h2.z,wr4.z); dot2(ar[3],h2.w,wr4.z);
      dot2(ar[0],h3.x,wr4.w); dot2(ar[1],h3.y,wr4.w); dot2(ar[2],h3.z,wr4.w); dot2(ar[3],h3.w,wr4.w);
      dot2(az[0],h0.x,wz4.x); dot2(az[1],h0.y,wz4.x); dot2(az[2],h0.z,wz4.x); dot2(az[3],h0.w,wz4.x);
      dot2(az[0],h1.x,wz4.y); dot2(az[1],h1.y,wz4.y); dot2(az[2],h1.z,wz4.y); dot2(az[3],h1.w,wz4.y);
      dot2(az[0],h2.x,wz4.z); dot2(az[1],h2.y,wz4.z); dot2(az[2],h2.z,wz4.z); dot2(az[3],h2.w,wz4.z);
      dot2(az[0],h3.x,wz4.w); dot2(az[1],h3.y,wz4.w); dot2(az[2],h3.z,wz4.w); dot2(az[3],h3.w,wz4.w);
      dot2(anh[0],h0.x,wn4.x); dot2(anh[1],h0.y,wn4.x); dot2(anh[2],h0.z,wn4.x); dot2(anh[3],h0.w,wn4.x);
      dot2(anh[0],h1.x,wn4.y); dot2(anh[1],h1.y,wn4.y); dot2(anh[2],h1.z,wn4.y); dot2(anh[3],h1.w,wn4.y);
      dot2(anh[0],h2.x,wn4.z); dot2(anh[1],h2.y,wn4.z); dot2(anh[2],h2.z,wn4.z); dot2(anh[3],h2.w,wn4.z);
      dot2(anh[0],h3.x,wn4.w); dot2(anh[1],h3.y,wn4.w); dot2(anh[2],h3.z,wn4.w); dot2(anh[3],h3.w,wn4.w);
    }
    #pragma unroll
    for (int pc = 0; pc < 8; pc += 4) {
      uint4 x0 = *(const uint4*)&xp_s[(pc+0)*20 + r4];
      uint4 x1 = *(const uint4*)&xp_s[(pc+1)*20 + r4];
      uint4 x2 = *(const uint4*)&xp_s[(pc+2)*20 + r4];
      uint4 x3 = *(const uint4*)&xp_s[(pc+3)*20 + r4];
      uint4 wr4 = *(const uint4*)&W_s[u*44 + 36 + pc];
      uint4 wz4 = *(const uint4*)&W_s[(64+u)*44 + 36 + pc];
      uint4 wn4 = *(const uint4*)&W_s[(128+u)*44 + 36 + pc];
      dot2(ar[0],x0.x,wr4.x); dot2(ar[1],x0.y,wr4.x); dot2(ar[2],x0.z,wr4.x); dot2(ar[3],x0.w,wr4.x);
      dot2(ar[0],x1.x,wr4.y); dot2(ar[1],x1.y,wr4.y); dot2(ar[2],x1.z,wr4.y); dot2(ar[3],x1.w,wr4.y);
      dot2(ar[0],x2.x,wr4.z); dot2(ar[1],x2.y,wr4.z); dot2(ar[2],x2.z,wr4.z); dot2(ar[3],x2.w,wr4.z);
      dot2(ar[0],x3.x,wr4.w); dot2(ar[1],x3.y,wr4.w); dot2(ar[2],x3.z,wr4.w); dot2(ar[3],x3.w,wr4.w);
      dot2(az[0],x0.x,wz4.x); dot2(az[1],x0.y,wz4.x); dot2(az[2],x0.z,wz4.x); dot2(az[3],x0.w,wz4.x);
      dot2(az[0],x1.x,wz4.y); dot2(az[1],x1.y,wz4.y); dot2(az[2],x1.z,wz4.y); dot2(az[3],x1.w,wz4.y);
      dot2(az[0],x2.x,wz4.z); dot2(az[1],x2.y,wz4.z); dot2(az[2],x2.z,wz4.z); dot2(az[3],x2.w,wz4.z);
      dot2(az[0],x3.x,wz4.w); dot2(az[1],x3.y,wz4.w); dot2(az[2],x3.z,wz4.w); dot2(az[3],x3.w,wz4.w);
      dot2(anx[0],x0.x,wn4.x); dot2(anx[1],x0.y,wn4.x); dot2(anx[2],x0.z,wn4.x); dot2(anx[3],x0.w,wn4.x);
      dot2(anx[0],x1.x,wn4.y); dot2(anx[1],x1.y,wn4.y); dot2(anx[2],x1.z,wn4.y); dot2(anx[3],x1.w,wn4.y);
      dot2(anx[0],x2.x,wn4.z); dot2(anx[1],x2.y,wn4.z); dot2(anx[2],x2.z,wn4.z); dot2(anx[3],x2.w,wn4.z);
      dot2(anx[0],x3.x,wn4.w); dot2(anx[1],x3.y,wn4.w); dot2(anx[2],x3.z,wn4.w); dot2(anx[3],x3.w,wn4.w);
    }
    float o_new[4];
    #pragma unroll
    for (int rr=0;rr<4;++rr){
      float rg = sigm(ar[rr] + brc);
      float zg = sigm(az[rr] + bzc);
      float ng = tanhf(anx[rr] + bxn + rg*(anh[rr] + bhn));
      o_new[rr] = (1.f - zg)*ng + zg*hreg[rr];
      hreg[rr] = o_new[rr];
    }
    #pragma unroll
    for (int rr=0;rr<4;++rr)
      oseq[(size_t)t*M_*64 + obase[rr] + u] = o_new[rr];
    unsigned pk[4];
    #pragma unroll
    for (int rr=0;rr<4;++rr){
      float pr = __shfl_xor(o_new[rr], 4);
      pk[rr] = cvtpk(o_new[rr], pr);
    }
    __syncthreads();
    if ((u & 1) == 0) {
      #pragma unroll
      for (int rr=0;rr<4;++rr) hp_s[(u>>1)*20 + r4 + rr] = pk[rr];
    }
    __syncthreads();
  }
}

// ---------------- stage C ----------------
__global__ __launch_bounds__(256) void k_stageC(
    const float* __restrict__ out1, const float* __restrict__ emb1,
    const float* __restrict__ w1, const float* __restrict__ b1,
    const float* __restrict__ w2, const float* __restrict__ b2,
    const float* __restrict__ w3, const float* __restrict__ b3,
    float* __restrict__ ndv)
{
  int idx = blockIdx.x*256 + threadIdx.x;
  int m = idx % M_;
  int n = m % N_;
  float rv[64];
  const float4* r4 = (const float4*)(out1 + (size_t)idx*64);
  #pragma unroll
  for (int q=0;q<16;++q){ float4 v=r4[q]; rv[q*4]=v.x; rv[q*4+1]=v.y; rv[q*4+2]=v.z; rv[q*4+3]=v.w; }
  float h1[16];
  for (int u=0;u<16;++u){
    float a = b1[u];
    const float* wr = w1 + u*64;
    #pragma unroll
    for (int c=0;c<64;++c) a += rv[c]*wr[c];
    h1[u] = sigm(a);
  }
  float h2[2];
  #pragma unroll
  for (int v=0;v<2;++v){
    float a = b2[v];
    #pragma unroll
    for (int u=0;u<16;++u) a += h1[u]*w2[v*16+u];
    h2[v] = sigm(a);
  }
  #pragma unroll
  for (int d=0;d<10;++d){
    float f = b3[d] + h2[0]*w3[d*2] + h2[1]*w3[d*2+1];
    ndv[(size_t)idx*10 + d] = tanhf(emb1[n*10+d]*f);
  }
}

// ---------------- stage D (MFMA): x_g = out1 + relu(V V^T) @ out1 per (t,b) ----------------
// One block per tb. P (f16, rows along m) and O^T (f16, cols along m) staged per 64-m chunk;
// v_mfma_f32_16x16x32_f16 accumulates 20 row-tiles x 4 col-tiles across 4 waves.
__global__ __launch_bounds__(256, 2) void k_stageDM(
    const float* __restrict__ ndv, const float* __restrict__ out1, float* __restrict__ xg)
{
  int tb = blockIdx.x;
  const int tid = threadIdx.x;
  const int lane = tid & 63, wid = tid >> 6;
  const int fr = lane & 15, fq = lane >> 4;

  __shared__ __align__(16) float V_s[320*12];
  __shared__ __align__(16) unsigned P_s[320*36];
  __shared__ __align__(16) unsigned O_s[64*36];

  // stage V (zero-padded rows/cols)
  for (int i = tid; i < 320*12; i += 256) {
    int n = i / 12, d = i - n*12;
    V_s[i] = (n < N_ && d < 10) ? ndv[((size_t)tb*N_ + n)*10 + d] : 0.f;
  }
  __syncthreads();

  // cache this thread's 5 row-vectors in registers
  const int srow = lane;             // + 64j  (note: rows indexed by lane; all waves same rows, diff m)
  const int smg = wid;               // m-group (16 m per wave)
  float vr[5][10];
  #pragma unroll
  for (int j = 0; j < 5; ++j) {
    const float* vp = &V_s[(64*j + srow)*12];
    #pragma unroll
    for (int d = 0; d < 10; ++d) vr[j][d] = vp[d];
  }

  f32x4 acc[5][4];
  #pragma unroll
  for (int a = 0; a < 5; ++a)
    #pragma unroll
    for (int c = 0; c < 4; ++c)
      acc[a][c] = (f32x4){0.f, 0.f, 0.f, 0.f};

  const float* ob = out1 + (size_t)tb*N_*64;

  for (int mc = 0; mc < 320; mc += 64) {
    // ---- stage O chunk transposed as f16 pairs: O_s[col][m-pair]
    for (int it = tid; it < 512; it += 256) {
      int p = it >> 4, cg = it & 15;
      int m0 = mc + 2*p;
      float4 a = make_float4(0.f,0.f,0.f,0.f), b = a;
      if (m0     < N_) a = *(const float4*)&ob[(size_t)m0*64 + cg*4];
      if (m0 + 1 < N_) b = *(const float4*)&ob[(size_t)(m0+1)*64 + cg*4];
      int c0 = cg*4;
      O_s[(c0+0)*36 + p] = pkh(a.x, b.x);
      O_s[(c0+1)*36 + p] = pkh(a.y, b.y);
      O_s[(c0+2)*36 + p] = pkh(a.z, b.z);
      O_s[(c0+3)*36 + p] = pkh(a.w, b.w);
    }
    // ---- s compute: P_s[n][m-pair] f16; vm broadcast per wave, p-outer j-inner
    unsigned pk8[5][8];
    #pragma unroll
    for (int p = 0; p < 8; ++p) {
      int m0 = mc + smg*16 + 2*p;
      const float* va = &V_s[m0*12];
      const float* vb = va + 12;
      float4 va0 = *(const float4*)va,     va1 = *(const float4*)(va+4);
      float2 va2 = *(const float2*)(va+8);
      float4 vb0 = *(const float4*)vb,     vb1 = *(const float4*)(vb+4);
      float2 vb2 = *(const float2*)(vb+8);
      #pragma unroll
      for (int j = 0; j < 5; ++j) {
        float s0 = vr[j][0]*va0.x + vr[j][1]*va0.y + vr[j][2]*va0.z + vr[j][3]*va0.w
                 + vr[j][4]*va1.x + vr[j][5]*va1.y + vr[j][6]*va1.z + vr[j][7]*va1.w
                 + vr[j][8]*va2.x + vr[j][9]*va2.y;
        float s1 = vr[j][0]*vb0.x + vr[j][1]*vb0.y + vr[j][2]*vb0.z + vr[j][3]*vb0.w
                 + vr[j][4]*vb1.x + vr[j][5]*vb1.y + vr[j][6]*vb1.z + vr[j][7]*vb1.w
                 + vr[j][8]*vb2.x + vr[j][9]*vb2.y;
        pk8[j][p] = pkh(fmaxf(s0, 0.f), fmaxf(s1, 0.f));
      }
    }
    #pragma unroll
    for (int j = 0; j < 5; ++j) {
      int n = 64*j + srow;
      *(uint4*)&P_s[n*36 + smg*8]     = make_uint4(pk8[j][0], pk8[j][1], pk8[j][2], pk8[j][3]);
      *(uint4*)&P_s[n*36 + smg*8 + 4] = make_uint4(pk8[j][4], pk8[j][5], pk8[j][6], pk8[j][7]);
    }
    __syncthreads();

    // ---- MFMA: 2 k-slices of 32
    #pragma unroll
    for (int ks = 0; ks < 2; ++ks) {
      int kd = ks*16 + fq*4;
      f16x8 bf[4];
      #pragma unroll
      for (int ct = 0; ct < 4; ++ct)
        bf[ct] = *(const f16x8*)&O_s[(ct*16 + fr)*36 + kd];
      #pragma unroll
      for (int a = 0; a < 5; ++a) {
        f16x8 af = *(const f16x8*)&P_s[((wid + 4*a)*16 + fr)*36 + kd];
        #pragma unroll
        for (int ct = 0; ct < 4; ++ct)
          acc[a][ct] = __builtin_amdgcn_mfma_f32_16x16x32_f16(af, bf[ct], acc[a][ct], 0, 0, 0);
      }
    }
    __syncthreads();
  }

  // ---- epilogue: xg = out1 + acc  (C/D: col = lane&15, row = (lane>>4)*4 + reg)
  #pragma unroll
  for (int a = 0; a < 5; ++a) {
    #pragma unroll
    for (int ct = 0; ct < 4; ++ct) {
      int col = ct*16 + fr;
      #pragma unroll
      for (int reg = 0; reg < 4; ++reg) {
        int n = (wid + 4*a)*16 + fq*4 + reg;
        if (n < N_) {
          size_t base = (size_t)tb*N_*64 + (size_t)n*64 + col;
          xg[base] = out1[base] + acc[a][ct][reg];
        }
      }
    }
  }
}

// ---------------- stage E ----------------
__global__ __launch_bounds__(256) void k_stageE(
    const float* xg_in, const float* __restrict__ out1,
    const float* __restrict__ Wf, const float* __restrict__ dw,
    const float* __restrict__ bf,
    float* xg_out)
{
  int n = blockIdx.y;
  int tile = blockIdx.x;
  int tid = threadIdx.x;
  int r = tid >> 3, ug = tid & 7;
  __shared__ __align__(16) float x_s[64*68];
  __shared__ __align__(16) float o_s[64*68];
  __shared__ __align__(16) float Wf_s[64*68];
  __shared__ __align__(16) float dA_s[64*68];
  __shared__ float bf_s[64];
  for (int idx = tid; idx < 64*64; idx += 256) {
    int row = idx >> 6, c = idx & 63;
    size_t g = ((size_t)(tile*64+row)*N_ + n)*64 + c;
    x_s[row*68+c] = xg_in[g];
    o_s[row*68+c] = out1[g];
  }
  for (int idx = tid; idx < 4096; idx += 256) {
    int u = idx >> 6, c = idx & 63;
    Wf_s[u*68+c] = Wf[(size_t)n*4096 + idx];
    dA_s[u*68+c] = dw[u*128 + c];
  }
  if (tid < 64) bf_s[tid] = bf[n*64 + tid];
  __syncthreads();

  float g2a[8], g2b[8];
  #pragma unroll
  for (int uu=0;uu<8;++uu){ g2a[uu] = bf_s[ug+8*uu]; g2b[uu] = g2a[uu]; }

  for (int c = 0; c < 64; c += 4) {
    float4 xa = *(const float4*)&x_s[r*68 + c];
    float4 xb = *(const float4*)&x_s[(r+32)*68 + c];
    float4 oa = *(const float4*)&o_s[r*68 + c];
    float4 ob = *(const float4*)&o_s[(r+32)*68 + c];
    #pragma unroll
    for (int uu=0;uu<8;++uu){
      int u = ug + 8*uu;
      float4 wf = *(const float4*)&Wf_s[u*68 + c];
      float4 da = *(const float4*)&dA_s[u*68 + c];
      g2a[uu] += oa.x*da.x + oa.y*da.y + oa.z*da.z + oa.w*da.w
               + xa.x*wf.x + xa.y*wf.y + xa.z*wf.z + xa.w*wf.w;
      g2b[uu] += ob.x*da.x + ob.y*da.y + ob.z*da.z + ob.w*da.w
               + xb.x*wf.x + xb.y*wf.y + xb.z*wf.z + xb.w*wf.w;
    }
  }
  size_t ba = ((size_t)(tile*64+r)*N_ + n)*64;
  size_t bb = ((size_t)(tile*64+r+32)*N_ + n)*64;
  #pragma unroll
  for (int uu=0;uu<8;++uu){
    xg_out[ba + ug + 8*uu] = g2a[uu];
    xg_out[bb + ug + 8*uu] = g2b[uu];
  }
}

extern "C" void kernel_launch(void* const* d_in, const int* in_sizes, int n_in,
                              void* d_out, int out_size, void* d_ws, size_t ws_size,
                              hipStream_t stream)
{
  (void)in_sizes; (void)n_in; (void)out_size;
  const float* x    = (const float*)d_in[0];
  const float* emb1 = (const float*)d_in[1];
  const float* emb2 = (const float*)d_in[2];
  const float* xw1  = (const float*)d_in[3];
  const float* xb1  = (const float*)d_in[4];
  const float* xw2  = (const float*)d_in[5];
  const float* xb2  = (const float*)d_in[6];
  const float* xw3  = (const float*)d_in[7];
  const float* xb3  = (const float*)d_in[8];
  const float* fw1  = (const float*)d_in[9];
  const float* fb1  = (const float*)d_in[10];
  const float* fw2  = (const float*)d_in[11];
  const float* fb2  = (const float*)d_in[12];
  const float* fw3  = (const float*)d_in[13];
  const float* fb3  = (const float*)d_in[14];
  const float* c2w1 = (const float*)d_in[15];
  const float* c2b1 = (const float*)d_in[16];
  const float* c2w2 = (const float*)d_in[17];
  const float* c2b2 = (const float*)d_in[18];
  const float* c2w3 = (const float*)d_in[19];
  const float* c2b3 = (const float*)d_in[20];
  const float* g1wih= (const float*)d_in[21];
  const float* g1whh= (const float*)d_in[22];
  const float* g1bih= (const float*)d_in[23];
  const float* g1bhh= (const float*)d_in[24];
  const float* g2wih= (const float*)d_in[25];
  const float* g2whh= (const float*)d_in[26];
  const float* g2bih= (const float*)d_in[27];
  const float* g2bhh= (const float*)d_in[28];
  const float* wpool= (const float*)d_in[29];
  const float* bpool= (const float*)d_in[30];
  const float* dww  = (const float*)d_in[31];
  const float* dwb  = (const float*)d_in[32];
  float* out = (float*)d_out;

  float* ws = (float*)d_ws;
  float* g1_in = ws;                          // TM*10
  float* out1  = g1_in + (size_t)TM_*10;      // TM*64
  float* ndv   = out1 + (size_t)TM_*64;       // TM*10
  float* xg    = ndv + (size_t)TM_*10;        // TM*64
  float* Wn    = xg + (size_t)TM_*64;         // N*4096
  float* bn    = Wn + (size_t)N_*4096;        // N*64
  float* Wf    = bn + (size_t)N_*64;          // N*4096
  float* bf    = Wf + (size_t)N_*4096;        // N*64
  unsigned* Wpk2 = (unsigned*)(bf + (size_t)N_*64);   // 64*192
  unsigned* Wpk1 = Wpk2 + 64*192;                     // 38*192
  unsigned* Wq2  = Wpk1 + 38*192;                     // 192*36
  unsigned* Wq1  = Wq2 + 192*36;                      // 192*44
  unsigned* Wxq2 = Wq1 + 192*44;                      // 192*36
  unsigned short* xwh = (unsigned short*)(Wxq2 + 192*36);  // TM*192 f16
  size_t need_old = ((size_t)((float*)Wq2 - ws)) * 4;
  size_t need_new = ((size_t)((char*)(xwh + (size_t)TM_*192) - (char*)ws));
  if (ws_size < need_old) return;
  bool use_new = (ws_size >= need_new);

  k_stageA<<<TM_/256, 256, 0, stream>>>(x, xw1,xb1,xw2,xb2,xw3,xb3, fw1,fb1,fw2,fb2,fw3,fb3, g1_in);
  k_wn<<<N_, 256, 0, stream>>>(emb2, wpool, bpool, Wn, bn);
  k_wf<<<N_, 256, 0, stream>>>(Wn, bn, dww, dwb, Wf, bf);

  if (use_new) {
    k_wpack2<<<(192*36 + 192*44 + 255)/256, 256, 0, stream>>>(
        g2wih, g2whh, g1wih, g1whh, Wq2, Wxq2, Wq1);
    k_gruX<<<M_/16, 256, 0, stream>>>(g1_in, Wq1, g1bih, g1bhh, out1);
    k_stageC<<<TM_/256, 256, 0, stream>>>(out1, emb1, c2w1,c2b1,c2w2,c2b2,c2w3,c2b3, ndv);
    k_stageDM<<<T_*B_, 256, 0, stream>>>(ndv, out1, xg);
    k_stageE<<<dim3(12, N_), 256, 0, stream>>>(xg, out1, Wf, dww, bf, xg);
    k_xw<<<TM_/16, 256, 0, stream>>>(xg, Wxq2, g2bih, xwh);
    k_gruH<<<M_/16, 256, 0, stream>>>(xwh, Wq2, g2bhh, out);
  } else {
    k_wpack<<<(64*192 + 38*192 + 255)/256, 256, 0, stream>>>(g2wih, g2whh, g1wih, g1whh, Wpk2, Wpk1);
    k_gruD<6,true,false><<<M_/16, 256, 0, stream>>>(g1_in, Wpk1, g1bih, g1bhh, out1, nullptr);
    k_stageC<<<TM_/256, 256, 0, stream>>>(out1, emb1, c2w1,c2b1,c2w2,c2b2,c2w3,c2b3, ndv);
    k_stageDM<<<T_*B_, 256, 0, stream>>>(ndv, out1, xg);
    k_stageE<<<dim3(12, N_), 256, 0, stream>>>(xg, out1, Wf, dww, bf, xg);
    k_gruD<32,false,true><<<M_/16, 256, 0, stream>>>(xg, Wpk2, g2bih, g2bhh, nullptr, out);
  }
}

// Round 12
// 312.898 us; speedup vs baseline: 48.7577x; 1.5586x over previous
//
#include <hip/hip_runtime.h>
#include <hip/hip_fp16.h>
#include <math.h>

#define B_ 64
#define T_ 12
#define N_ 307
#define I_ 3
#define R_ 64
#define D_ 10
#define M_ (B_*N_)      // 19648
#define TM_ (T_*M_)     // 235776

typedef _Float16 f16x8 __attribute__((ext_vector_type(8)));
typedef float f32x4 __attribute__((ext_vector_type(4)));

__device__ __forceinline__ float sigm(float x){ return 1.f/(1.f+__expf(-x)); }

// pack two f32 -> one dword of 2 f16 (RTZ)
__device__ __forceinline__ unsigned pkh(float a, float b){
  unsigned r;
  asm("v_cvt_pkrtz_f16_f32 %0, %1, %2" : "=v"(r) : "v"(a), "v"(b));
  return r;
}

// ---------------- stage A ----------------
__global__ __launch_bounds__(256) void k_stageA(
    const float* __restrict__ x,
    const float* __restrict__ xw1, const float* __restrict__ xb1,
    const float* __restrict__ xw2, const float* __restrict__ xb2,
    const float* __restrict__ xw3, const float* __restrict__ xb3,
    const float* __restrict__ fw1, const float* __restrict__ fb1,
    const float* __restrict__ fw2, const float* __restrict__ fb2,
    const float* __restrict__ fw3, const float* __restrict__ fb3,
    float* __restrict__ g1)
{
  int idx = blockIdx.x*256 + threadIdx.x;
  int t = idx / M_;
  int m = idx - t*M_;
  int b = m / N_;
  int n = m - b*N_;
  const float* xp = x + (((size_t)b*T_ + t)*N_ + n)*I_;
  float xv[3] = {xp[0], xp[1], xp[2]};
  float e[3][10];
  #pragma unroll
  for (int i=0;i<3;++i){
    float h1[16];
    #pragma unroll
    for (int u=0;u<16;++u) h1[u] = sigm(xv[i]*xw1[u] + xb1[u]);
    float h2[2];
    #pragma unroll
    for (int v=0;v<2;++v){
      float a = xb2[v];
      #pragma unroll
      for (int u=0;u<16;++u) a += h1[u]*xw2[v*16+u];
      h2[v] = sigm(a);
    }
    #pragma unroll
    for (int d=0;d<10;++d) e[i][d] = xb3[d] + h2[0]*xw3[d*2] + h2[1]*xw3[d*2+1];
  }
  float in1[3];
  #pragma unroll
  for (int j=0;j<3;++j){
    float acc = 0.f;
    #pragma unroll
    for (int i=0;i<3;++i){
      float s = 0.f;
      #pragma unroll
      for (int d=0;d<10;++d) s += e[j][d]*e[i][d];
      s = fmaxf(s, 0.f);
      acc += s*xv[i];
    }
    in1[j] = xv[j] + acc;
  }
  float h1[16];
  #pragma unroll
  for (int u=0;u<16;++u)
    h1[u] = sigm(fb1[u] + in1[0]*fw1[u*3] + in1[1]*fw1[u*3+1] + in1[2]*fw1[u*3+2]);
  float h2[2];
  #pragma unroll
  for (int v=0;v<2;++v){
    float a = fb2[v];
    #pragma unroll
    for (int u=0;u<16;++u) a += h1[u]*fw2[v*16+u];
    h2[v] = sigm(a);
  }
  float* gp = g1 + (size_t)idx*10;
  #pragma unroll
  for (int d=0;d<10;++d) gp[d] = fb3[d] + h2[0]*fw3[d*2] + h2[1]*fw3[d*2+1];
}

// ---------------- k_wn ----------------
__global__ __launch_bounds__(256) void k_wn(
    const float* __restrict__ emb2, const float* __restrict__ wpool,
    const float* __restrict__ bpool, float* __restrict__ Wn, float* __restrict__ bn)
{
  int n = blockIdx.x; int tid = threadIdx.x;
  __shared__ float e_s[10];
  if (tid < 10) e_s[tid] = emb2[n*10 + tid];
  __syncthreads();
  #pragma unroll
  for (int e=0;e<16;++e){
    int i = e*256 + tid;
    float a = 0.f;
    #pragma unroll
    for (int d=0;d<10;++d) a += e_s[d]*wpool[(size_t)d*4096 + i];
    Wn[(size_t)n*4096 + i] = a;
  }
  if (tid < 64){
    float a = 0.f;
    #pragma unroll
    for (int d=0;d<10;++d) a += e_s[d]*bpool[d*64 + tid];
    bn[n*64 + tid] = a;
  }
}

// ---------------- k_wf ----------------
__global__ __launch_bounds__(256) void k_wf(
    const float* __restrict__ Wn, const float* __restrict__ bn,
    const float* __restrict__ dw, const float* __restrict__ db,
    float* __restrict__ Wf, float* __restrict__ bf)
{
  int n = blockIdx.x; int tid = threadIdx.x;
  __shared__ float WnS[64*68];
  __shared__ float dwBT[64*68];
  __shared__ float bn_s[64];
  for (int idx = tid; idx < 4096; idx += 256) {
    int c = idx >> 6, r = idx & 63;
    WnS[c*68 + r] = Wn[(size_t)n*4096 + idx];
  }
  for (int idx = tid; idx < 4096; idx += 256) {
    int u = idx >> 6, r = idx & 63;
    dwBT[r*68 + u] = dw[u*128 + 64 + r];
  }
  if (tid < 64) bn_s[tid] = bn[n*64 + tid];
  __syncthreads();
  int u = tid & 63, cg = tid >> 6;
  #pragma unroll
  for (int j = 0; j < 16; ++j) {
    int c = cg*16 + j;
    float acc = 0.f;
    #pragma unroll 8
    for (int r = 0; r < 64; ++r) acc += WnS[c*68 + r] * dwBT[r*68 + u];
    Wf[(size_t)n*4096 + u*64 + c] = acc;
  }
  if (tid < 64) {
    float acc = db[tid];
    #pragma unroll 8
    for (int r = 0; r < 64; ++r) acc += bn_s[r] * dwBT[r*68 + tid];
    bf[n*64 + tid] = acc;
  }
}

// ---------------- k_wpackM: GRU weights as f16 pair-chunks, u-major (MFMA B layout)
__global__ __launch_bounds__(256) void k_wpackM(
    const float* __restrict__ wih2, const float* __restrict__ whh2,
    const float* __restrict__ wih1, const float* __restrict__ whh1,
    unsigned* __restrict__ Wh2, unsigned* __restrict__ Wx2,
    unsigned* __restrict__ Wh1, unsigned* __restrict__ Wx1)
{
  int i = blockIdx.x*256 + threadIdx.x;
  if (i < 192*32) {
    int wr = i >> 5, p = i & 31;
    Wh2[i] = pkh(whh2[wr*64 + 2*p], whh2[wr*64 + 2*p + 1]);
    Wx2[i] = pkh(wih2[wr*64 + 2*p], wih2[wr*64 + 2*p + 1]);
    Wh1[i] = pkh(whh1[wr*64 + 2*p], whh1[wr*64 + 2*p + 1]);
  }
  int j = i - 192*32;
  if (j >= 0 && j < 192*16) {
    int wr = j >> 4, p = j & 15;
    Wx1[j] = (p < 5) ? pkh(wih1[wr*10 + 2*p], wih1[wr*10 + 2*p + 1]) : 0u;
  }
}

// ---------------- k_gruM: MFMA GRU scan.
// 16 rows/block, 4 waves. Wave w owns units u = w*16 + (lane&15) for all 3 gates.
// Weights held as B-fragments in registers across all T steps; h/x A-tiles in LDS.
template<int DIN, bool WFIN>
__global__ __launch_bounds__(256, 3) void k_gruM(
    const float* __restrict__ xseq,    // [T][M][DIN]
    const unsigned* __restrict__ Whf,  // [192][32] f16 pairs
    const unsigned* __restrict__ Wxf,  // [192][DIN==64?32:16]
    const float* __restrict__ bih, const float* __restrict__ bhh,
    float* __restrict__ o_out)         // WFIN ? [B][T][N][64] : [T][M][64]
{
  constexpr int XPR = (DIN == 64) ? 32 : 16;   // x pairs (padded)
  constexpr int XKS = XPR / 16;                // x k-slices (2 or 1)
  constexpr int XST = XPR + 4;                 // LDS stride
  __shared__ __align__(16) unsigned Ah_s[16*36];
  __shared__ __align__(16) unsigned Ax_s[16*XST];
  const int tid = threadIdx.x;
  const int lane = tid & 63, w = tid >> 6;
  const int fr = lane & 15, fq = lane >> 4;
  const int row0 = blockIdx.x * 16;
  const int u = w*16 + fr;

  // B-fragments from global, once (index pattern identical to stageDM's verified one)
  f16x8 bh_r[2], bh_z[2], bh_n[2];
  #pragma unroll
  for (int ks = 0; ks < 2; ++ks) {
    bh_r[ks] = *(const f16x8*)&Whf[(size_t)u*32        + ks*16 + fq*4];
    bh_z[ks] = *(const f16x8*)&Whf[(size_t)(64+u)*32   + ks*16 + fq*4];
    bh_n[ks] = *(const f16x8*)&Whf[(size_t)(128+u)*32  + ks*16 + fq*4];
  }
  f16x8 bx_r[XKS], bx_z[XKS], bx_n[XKS];
  #pragma unroll
  for (int ks = 0; ks < XKS; ++ks) {
    bx_r[ks] = *(const f16x8*)&Wxf[(size_t)u*XPR       + ks*16 + fq*4];
    bx_z[ks] = *(const f16x8*)&Wxf[(size_t)(64+u)*XPR  + ks*16 + fq*4];
    bx_n[ks] = *(const f16x8*)&Wxf[(size_t)(128+u)*XPR + ks*16 + fq*4];
  }

  const float brc = bih[u]     + bhh[u];
  const float bzc = bih[64+u]  + bhh[64+u];
  const float bxn = bih[128+u];
  const float bhn = bhh[128+u];

  for (int i = tid; i < 16*36;  i += 256) Ah_s[i] = 0u;
  for (int i = tid; i < 16*XST; i += 256) Ax_s[i] = 0u;
  __syncthreads();   // FIX (R11): order zero-init before t=0 x staging — this race
                     // was clobbering staged x values with zeros (absmax 0.13).

  // output bases: rows = row0 + fq*4 + reg, unit u  (C/D: col=lane&15, row=fq*4+reg)
  size_t obase[4];
  #pragma unroll
  for (int reg = 0; reg < 4; ++reg) {
    int g = row0 + fq*4 + reg;
    if (WFIN) { int bb = g / N_, nn = g - bb*N_; obase[reg] = (((size_t)bb*T_)*N_ + nn)*64 + u; }
    else      { obase[reg] = (size_t)g*64 + u; }
  }
  const size_t tstep = WFIN ? (size_t)N_*64 : (size_t)M_*64;
  float hreg[4] = {0.f, 0.f, 0.f, 0.f};

  for (int t = 0; t < T_; ++t) {
    // ---- stage x_t as f16-pair A-tile
    if (DIN == 64) {
      #pragma unroll
      for (int it = 0; it < 2; ++it) {
        int idx = tid + it*256;
        int row = idx >> 5, p = idx & 31;
        const float2 v = *(const float2*)&xseq[((size_t)t*M_ + row0 + row)*64 + 2*p];
        Ax_s[row*XST + p] = pkh(v.x, v.y);
      }
    } else {
      if (tid < 80) {
        int row = tid / 5, p = tid - (tid/5)*5;
        const float2 v = *(const float2*)&xseq[((size_t)t*M_ + row0 + row)*10 + 2*p];
        Ax_s[row*XST + p] = pkh(v.x, v.y);
      }
    }
    __syncthreads();   // x staged; prev-step h writes visible

    f32x4 ar  = {0.f,0.f,0.f,0.f}, az  = {0.f,0.f,0.f,0.f};
    f32x4 anh = {0.f,0.f,0.f,0.f}, anx = {0.f,0.f,0.f,0.f};
    #pragma unroll
    for (int ks = 0; ks < 2; ++ks) {
      f16x8 ah = *(const f16x8*)&Ah_s[fr*36 + ks*16 + fq*4];
      ar  = __builtin_amdgcn_mfma_f32_16x16x32_f16(ah, bh_r[ks], ar,  0,0,0);
      az  = __builtin_amdgcn_mfma_f32_16x16x32_f16(ah, bh_z[ks], az,  0,0,0);
      anh = __builtin_amdgcn_mfma_f32_16x16x32_f16(ah, bh_n[ks], anh, 0,0,0);
    }
    #pragma unroll
    for (int ks = 0; ks < XKS; ++ks) {
      f16x8 ax = *(const f16x8*)&Ax_s[fr*XST + ks*16 + fq*4];
      ar  = __builtin_amdgcn_mfma_f32_16x16x32_f16(ax, bx_r[ks], ar,  0,0,0);
      az  = __builtin_amdgcn_mfma_f32_16x16x32_f16(ax, bx_z[ks], az,  0,0,0);
      anx = __builtin_amdgcn_mfma_f32_16x16x32_f16(ax, bx_n[ks], anx, 0,0,0);
    }

    float o_new[4];
    #pragma unroll
    for (int reg = 0; reg < 4; ++reg) {
      float rg = sigm(ar[reg] + brc);
      float zg = sigm(az[reg] + bzc);
      float ng = tanhf(anx[reg] + bxn + rg*(anh[reg] + bhn));
      o_new[reg] = (1.f - zg)*ng + zg*hreg[reg];
      hreg[reg] = o_new[reg];
    }
    #pragma unroll
    for (int reg = 0; reg < 4; ++reg)
      o_out[obase[reg] + (size_t)t*tstep] = o_new[reg];

    // pack h pairs: even fr pairs (u, u+1) via lane^1
    unsigned pk[4];
    #pragma unroll
    for (int reg = 0; reg < 4; ++reg) {
      float pr = __shfl_xor(o_new[reg], 1);
      pk[reg] = pkh(o_new[reg], pr);
    }
    __syncthreads();   // all MFMA reads of Ah_s/Ax_s done
    if ((fr & 1) == 0) {
      #pragma unroll
      for (int reg = 0; reg < 4; ++reg)
        Ah_s[(fq*4 + reg)*36 + w*8 + (fr >> 1)] = pk[reg];
    }
    // next iter's first barrier orders these writes before the reads
  }
}

// ---------------- stage C ----------------
__global__ __launch_bounds__(256) void k_stageC(
    const float* __restrict__ out1, const float* __restrict__ emb1,
    const float* __restrict__ w1, const float* __restrict__ b1,
    const float* __restrict__ w2, const float* __restrict__ b2,
    const float* __restrict__ w3, const float* __restrict__ b3,
    float* __restrict__ ndv)
{
  int idx = blockIdx.x*256 + threadIdx.x;
  int m = idx % M_;
  int n = m % N_;
  float rv[64];
  const float4* r4 = (const float4*)(out1 + (size_t)idx*64);
  #pragma unroll
  for (int q=0;q<16;++q){ float4 v=r4[q]; rv[q*4]=v.x; rv[q*4+1]=v.y; rv[q*4+2]=v.z; rv[q*4+3]=v.w; }
  float h1[16];
  for (int u=0;u<16;++u){
    float a = b1[u];
    const float* wr = w1 + u*64;
    #pragma unroll
    for (int c=0;c<64;++c) a += rv[c]*wr[c];
    h1[u] = sigm(a);
  }
  float h2[2];
  #pragma unroll
  for (int v=0;v<2;++v){
    float a = b2[v];
    #pragma unroll
    for (int u=0;u<16;++u) a += h1[u]*w2[v*16+u];
    h2[v] = sigm(a);
  }
  #pragma unroll
  for (int d=0;d<10;++d){
    float f = b3[d] + h2[0]*w3[d*2] + h2[1]*w3[d*2+1];
    ndv[(size_t)idx*10 + d] = tanhf(emb1[n*10+d]*f);
  }
}

// ---------------- stage D (MFMA) ----------------
__global__ __launch_bounds__(256, 2) void k_stageDM(
    const float* __restrict__ ndv, const float* __restrict__ out1, float* __restrict__ xg)
{
  int tb = blockIdx.x;
  const int tid = threadIdx.x;
  const int lane = tid & 63, wid = tid >> 6;
  const int fr = lane & 15, fq = lane >> 4;

  __shared__ __align__(16) float V_s[320*12];
  __shared__ __align__(16) unsigned P_s[320*36];
  __shared__ __align__(16) unsigned O_s[64*36];

  for (int i = tid; i < 320*12; i += 256) {
    int n = i / 12, d = i - n*12;
    V_s[i] = (n < N_ && d < 10) ? ndv[((size_t)tb*N_ + n)*10 + d] : 0.f;
  }
  __syncthreads();

  const int srow = lane;
  const int smg = wid;
  float vr[5][10];
  #pragma unroll
  for (int j = 0; j < 5; ++j) {
    const float* vp = &V_s[(64*j + srow)*12];
    #pragma unroll
    for (int d = 0; d < 10; ++d) vr[j][d] = vp[d];
  }

  f32x4 acc[5][4];
  #pragma unroll
  for (int a = 0; a < 5; ++a)
    #pragma unroll
    for (int c = 0; c < 4; ++c)
      acc[a][c] = (f32x4){0.f, 0.f, 0.f, 0.f};

  const float* ob = out1 + (size_t)tb*N_*64;

  for (int mc = 0; mc < 320; mc += 64) {
    for (int it = tid; it < 512; it += 256) {
      int p = it >> 4, cg = it & 15;
      int m0 = mc + 2*p;
      float4 a = make_float4(0.f,0.f,0.f,0.f), b = a;
      if (m0     < N_) a = *(const float4*)&ob[(size_t)m0*64 + cg*4];
      if (m0 + 1 < N_) b = *(const float4*)&ob[(size_t)(m0+1)*64 + cg*4];
      int c0 = cg*4;
      O_s[(c0+0)*36 + p] = pkh(a.x, b.x);
      O_s[(c0+1)*36 + p] = pkh(a.y, b.y);
      O_s[(c0+2)*36 + p] = pkh(a.z, b.z);
      O_s[(c0+3)*36 + p] = pkh(a.w, b.w);
    }
    unsigned pk8[5][8];
    #pragma unroll
    for (int p = 0; p < 8; ++p) {
      int m0 = mc + smg*16 + 2*p;
      const float* va = &V_s[m0*12];
      const float* vb = va + 12;
      float4 va0 = *(const float4*)va,     va1 = *(const float4*)(va+4);
      float2 va2 = *(const float2*)(va+8);
      float4 vb0 = *(const float4*)vb,     vb1 = *(const float4*)(vb+4);
      float2 vb2 = *(const float2*)(vb+8);
      #pragma unroll
      for (int j = 0; j < 5; ++j) {
        float s0 = vr[j][0]*va0.x + vr[j][1]*va0.y + vr[j][2]*va0.z + vr[j][3]*va0.w
                 + vr[j][4]*va1.x + vr[j][5]*va1.y + vr[j][6]*va1.z + vr[j][7]*va1.w
                 + vr[j][8]*va2.x + vr[j][9]*va2.y;
        float s1 = vr[j][0]*vb0.x + vr[j][1]*vb0.y + vr[j][2]*vb0.z + vr[j][3]*vb0.w
                 + vr[j][4]*vb1.x + vr[j][5]*vb1.y + vr[j][6]*vb1.z + vr[j][7]*vb1.w
                 + vr[j][8]*vb2.x + vr[j][9]*vb2.y;
        pk8[j][p] = pkh(fmaxf(s0, 0.f), fmaxf(s1, 0.f));
      }
    }
    #pragma unroll
    for (int j = 0; j < 5; ++j) {
      int n = 64*j + srow;
      *(uint4*)&P_s[n*36 + smg*8]     = make_uint4(pk8[j][0], pk8[j][1], pk8[j][2], pk8[j][3]);
      *(uint4*)&P_s[n*36 + smg*8 + 4] = make_uint4(pk8[j][4], pk8[j][5], pk8[j][6], pk8[j][7]);
    }
    __syncthreads();

    #pragma unroll
    for (int ks = 0; ks < 2; ++ks) {
      int kd = ks*16 + fq*4;
      f16x8 bf[4];
      #pragma unroll
      for (int ct = 0; ct < 4; ++ct)
        bf[ct] = *(const f16x8*)&O_s[(ct*16 + fr)*36 + kd];
      #pragma unroll
      for (int a = 0; a < 5; ++a) {
        f16x8 af = *(const f16x8*)&P_s[((wid + 4*a)*16 + fr)*36 + kd];
        #pragma unroll
        for (int ct = 0; ct < 4; ++ct)
          acc[a][ct] = __builtin_amdgcn_mfma_f32_16x16x32_f16(af, bf[ct], acc[a][ct], 0, 0, 0);
      }
    }
    __syncthreads();
  }

  #pragma unroll
  for (int a = 0; a < 5; ++a) {
    #pragma unroll
    for (int ct = 0; ct < 4; ++ct) {
      int col = ct*16 + fr;
      #pragma unroll
      for (int reg = 0; reg < 4; ++reg) {
        int n = (wid + 4*a)*16 + fq*4 + reg;
        if (n < N_) {
          size_t base = (size_t)tb*N_*64 + (size_t)n*64 + col;
          xg[base] = out1[base] + acc[a][ct][reg];
        }
      }
    }
  }
}

// ---------------- stage E ----------------
__global__ __launch_bounds__(256) void k_stageE(
    const float* xg_in, const float* __restrict__ out1,
    const float* __restrict__ Wf, const float* __restrict__ dw,
    const float* __restrict__ bf,
    float* xg_out)
{
  int n = blockIdx.y;
  int tile = blockIdx.x;
  int tid = threadIdx.x;
  int r = tid >> 3, ug = tid & 7;
  __shared__ __align__(16) float x_s[64*68];
  __shared__ __align__(16) float o_s[64*68];
  __shared__ __align__(16) float Wf_s[64*68];
  __shared__ __align__(16) float dA_s[64*68];
  __shared__ float bf_s[64];
  for (int idx = tid; idx < 64*64; idx += 256) {
    int row = idx >> 6, c = idx & 63;
    size_t g = ((size_t)(tile*64+row)*N_ + n)*64 + c;
    x_s[row*68+c] = xg_in[g];
    o_s[row*68+c] = out1[g];
  }
  for (int idx = tid; idx < 4096; idx += 256) {
    int u = idx >> 6, c = idx & 63;
    Wf_s[u*68+c] = Wf[(size_t)n*4096 + idx];
    dA_s[u*68+c] = dw[u*128 + c];
  }
  if (tid < 64) bf_s[tid] = bf[n*64 + tid];
  __syncthreads();

  float g2a[8], g2b[8];
  #pragma unroll
  for (int uu=0;uu<8;++uu){ g2a[uu] = bf_s[ug+8*uu]; g2b[uu] = g2a[uu]; }

  for (int c = 0; c < 64; c += 4) {
    float4 xa = *(const float4*)&x_s[r*68 + c];
    float4 xb = *(const float4*)&x_s[(r+32)*68 + c];
    float4 oa = *(const float4*)&o_s[r*68 + c];
    float4 ob = *(const float4*)&o_s[(r+32)*68 + c];
    #pragma unroll
    for (int uu=0;uu<8;++uu){
      int u = ug + 8*uu;
      float4 wf = *(const float4*)&Wf_s[u*68 + c];
      float4 da = *(const float4*)&dA_s[u*68 + c];
      g2a[uu] += oa.x*da.x + oa.y*da.y + oa.z*da.z + oa.w*da.w
               + xa.x*wf.x + xa.y*wf.y + xa.z*wf.z + xa.w*wf.w;
      g2b[uu] += ob.x*da.x + ob.y*da.y + ob.z*da.z + ob.w*da.w
               + xb.x*wf.x + xb.y*wf.y + xb.z*wf.z + xb.w*wf.w;
    }
  }
  size_t ba = ((size_t)(tile*64+r)*N_ + n)*64;
  size_t bb = ((size_t)(tile*64+r+32)*N_ + n)*64;
  #pragma unroll
  for (int uu=0;uu<8;++uu){
    xg_out[ba + ug + 8*uu] = g2a[uu];
    xg_out[bb + ug + 8*uu] = g2b[uu];
  }
}

extern "C" void kernel_launch(void* const* d_in, const int* in_sizes, int n_in,
                              void* d_out, int out_size, void* d_ws, size_t ws_size,
                              hipStream_t stream)
{
  (void)in_sizes; (void)n_in; (void)out_size;
  const float* x    = (const float*)d_in[0];
  const float* emb1 = (const float*)d_in[1];
  const float* emb2 = (const float*)d_in[2];
  const float* xw1  = (const float*)d_in[3];
  const float* xb1  = (const float*)d_in[4];
  const float* xw2  = (const float*)d_in[5];
  const float* xb2  = (const float*)d_in[6];
  const float* xw3  = (const float*)d_in[7];
  const float* xb3  = (const float*)d_in[8];
  const float* fw1  = (const float*)d_in[9];
  const float* fb1  = (const float*)d_in[10];
  const float* fw2  = (const float*)d_in[11];
  const float* fb2  = (const float*)d_in[12];
  const float* fw3  = (const float*)d_in[13];
  const float* fb3  = (const float*)d_in[14];
  const float* c2w1 = (const float*)d_in[15];
  const float* c2b1 = (const float*)d_in[16];
  const float* c2w2 = (const float*)d_in[17];
  const float* c2b2 = (const float*)d_in[18];
  const float* c2w3 = (const float*)d_in[19];
  const float* c2b3 = (const float*)d_in[20];
  const float* g1wih= (const float*)d_in[21];
  const float* g1whh= (const float*)d_in[22];
  const float* g1bih= (const float*)d_in[23];
  const float* g1bhh= (const float*)d_in[24];
  const float* g2wih= (const float*)d_in[25];
  const float* g2whh= (const float*)d_in[26];
  const float* g2bih= (const float*)d_in[27];
  const float* g2bhh= (const float*)d_in[28];
  const float* wpool= (const float*)d_in[29];
  const float* bpool= (const float*)d_in[30];
  const float* dww  = (const float*)d_in[31];
  const float* dwb  = (const float*)d_in[32];
  float* out = (float*)d_out;

  float* ws = (float*)d_ws;
  float* g1_in = ws;                          // TM*10
  float* out1  = g1_in + (size_t)TM_*10;      // TM*64
  float* ndv   = out1 + (size_t)TM_*64;       // TM*10
  float* xg    = ndv + (size_t)TM_*10;        // TM*64
  float* Wn    = xg + (size_t)TM_*64;         // N*4096
  float* bn    = Wn + (size_t)N_*4096;        // N*64
  float* Wf    = bn + (size_t)N_*64;          // N*4096
  float* bf    = Wf + (size_t)N_*4096;        // N*64
  unsigned* Wh2f = (unsigned*)(bf + (size_t)N_*64);   // 192*32
  unsigned* Wx2f = Wh2f + 192*32;                     // 192*32
  unsigned* Wh1f = Wx2f + 192*32;                     // 192*32
  unsigned* Wx1f = Wh1f + 192*32;                     // 192*16
  size_t need = ((size_t)((char*)(Wx1f + 192*16) - (char*)ws));
  if (ws_size < need) return;

  k_stageA<<<TM_/256, 256, 0, stream>>>(x, xw1,xb1,xw2,xb2,xw3,xb3, fw1,fb1,fw2,fb2,fw3,fb3, g1_in);
  k_wn<<<N_, 256, 0, stream>>>(emb2, wpool, bpool, Wn, bn);
  k_wf<<<N_, 256, 0, stream>>>(Wn, bn, dww, dwb, Wf, bf);
  k_wpackM<<<(192*32 + 192*16 + 255)/256, 256, 0, stream>>>(
      g2wih, g2whh, g1wih, g1whh, Wh2f, Wx2f, Wh1f, Wx1f);

  // GRU1: x = g1_in (DIN=10), output out1 [T][M][64]
  k_gruM<10,false><<<M_/16, 256, 0, stream>>>(g1_in, Wh1f, Wx1f, g1bih, g1bhh, out1);

  k_stageC<<<TM_/256, 256, 0, stream>>>(out1, emb1, c2w1,c2b1,c2w2,c2b2,c2w3,c2b3, ndv);
  k_stageDM<<<T_*B_, 256, 0, stream>>>(ndv, out1, xg);
  k_stageE<<<dim3(12, N_), 256, 0, stream>>>(xg, out1, Wf, dww, bf, xg);

  // GRU2: x = xg (DIN=64), output [B][T][N][64]
  k_gruM<64,true><<<M_/16, 256, 0, stream>>>(xg, Wh2f, Wx2f, g2bih, g2bhh, out);
}

// Round 13
// 293.566 us; speedup vs baseline: 51.9685x; 1.0659x over previous
//
#include <hip/hip_runtime.h>
#include <hip/hip_fp16.h>
#include <math.h>

#define B_ 64
#define T_ 12
#define N_ 307
#define I_ 3
#define R_ 64
#define D_ 10
#define M_ (B_*N_)      // 19648
#define TM_ (T_*M_)     // 235776

typedef _Float16 f16x8 __attribute__((ext_vector_type(8)));
typedef float f32x4 __attribute__((ext_vector_type(4)));

__device__ __forceinline__ float sigm(float x){ return 1.f/(1.f+__expf(-x)); }

// pack two f32 -> one dword of 2 f16 (RTZ)
__device__ __forceinline__ unsigned pkh(float a, float b){
  unsigned r;
  asm("v_cvt_pkrtz_f16_f32 %0, %1, %2" : "=v"(r) : "v"(a), "v"(b));
  return r;
}

// ---------------- stage A ----------------
__global__ __launch_bounds__(256) void k_stageA(
    const float* __restrict__ x,
    const float* __restrict__ xw1, const float* __restrict__ xb1,
    const float* __restrict__ xw2, const float* __restrict__ xb2,
    const float* __restrict__ xw3, const float* __restrict__ xb3,
    const float* __restrict__ fw1, const float* __restrict__ fb1,
    const float* __restrict__ fw2, const float* __restrict__ fb2,
    const float* __restrict__ fw3, const float* __restrict__ fb3,
    float* __restrict__ g1)
{
  int idx = blockIdx.x*256 + threadIdx.x;
  int t = idx / M_;
  int m = idx - t*M_;
  int b = m / N_;
  int n = m - b*N_;
  const float* xp = x + (((size_t)b*T_ + t)*N_ + n)*I_;
  float xv[3] = {xp[0], xp[1], xp[2]};
  float e[3][10];
  #pragma unroll
  for (int i=0;i<3;++i){
    float h1[16];
    #pragma unroll
    for (int u=0;u<16;++u) h1[u] = sigm(xv[i]*xw1[u] + xb1[u]);
    float h2[2];
    #pragma unroll
    for (int v=0;v<2;++v){
      float a = xb2[v];
      #pragma unroll
      for (int u=0;u<16;++u) a += h1[u]*xw2[v*16+u];
      h2[v] = sigm(a);
    }
    #pragma unroll
    for (int d=0;d<10;++d) e[i][d] = xb3[d] + h2[0]*xw3[d*2] + h2[1]*xw3[d*2+1];
  }
  float in1[3];
  #pragma unroll
  for (int j=0;j<3;++j){
    float acc = 0.f;
    #pragma unroll
    for (int i=0;i<3;++i){
      float s = 0.f;
      #pragma unroll
      for (int d=0;d<10;++d) s += e[j][d]*e[i][d];
      s = fmaxf(s, 0.f);
      acc += s*xv[i];
    }
    in1[j] = xv[j] + acc;
  }
  float h1[16];
  #pragma unroll
  for (int u=0;u<16;++u)
    h1[u] = sigm(fb1[u] + in1[0]*fw1[u*3] + in1[1]*fw1[u*3+1] + in1[2]*fw1[u*3+2]);
  float h2[2];
  #pragma unroll
  for (int v=0;v<2;++v){
    float a = fb2[v];
    #pragma unroll
    for (int u=0;u<16;++u) a += h1[u]*fw2[v*16+u];
    h2[v] = sigm(a);
  }
  float* gp = g1 + (size_t)idx*10;
  #pragma unroll
  for (int d=0;d<10;++d) gp[d] = fb3[d] + h2[0]*fw3[d*2] + h2[1]*fw3[d*2+1];
}

// ---------------- k_wn ----------------
__global__ __launch_bounds__(256) void k_wn(
    const float* __restrict__ emb2, const float* __restrict__ wpool,
    const float* __restrict__ bpool, float* __restrict__ Wn, float* __restrict__ bn)
{
  int n = blockIdx.x; int tid = threadIdx.x;
  __shared__ float e_s[10];
  if (tid < 10) e_s[tid] = emb2[n*10 + tid];
  __syncthreads();
  #pragma unroll
  for (int e=0;e<16;++e){
    int i = e*256 + tid;
    float a = 0.f;
    #pragma unroll
    for (int d=0;d<10;++d) a += e_s[d]*wpool[(size_t)d*4096 + i];
    Wn[(size_t)n*4096 + i] = a;
  }
  if (tid < 64){
    float a = 0.f;
    #pragma unroll
    for (int d=0;d<10;++d) a += e_s[d]*bpool[d*64 + tid];
    bn[n*64 + tid] = a;
  }
}

// ---------------- k_wf ----------------
__global__ __launch_bounds__(256) void k_wf(
    const float* __restrict__ Wn, const float* __restrict__ bn,
    const float* __restrict__ dw, const float* __restrict__ db,
    float* __restrict__ Wf, float* __restrict__ bf)
{
  int n = blockIdx.x; int tid = threadIdx.x;
  __shared__ float WnS[64*68];
  __shared__ float dwBT[64*68];
  __shared__ float bn_s[64];
  for (int idx = tid; idx < 4096; idx += 256) {
    int c = idx >> 6, r = idx & 63;
    WnS[c*68 + r] = Wn[(size_t)n*4096 + idx];
  }
  for (int idx = tid; idx < 4096; idx += 256) {
    int u = idx >> 6, r = idx & 63;
    dwBT[r*68 + u] = dw[u*128 + 64 + r];
  }
  if (tid < 64) bn_s[tid] = bn[n*64 + tid];
  __syncthreads();
  int u = tid & 63, cg = tid >> 6;
  #pragma unroll
  for (int j = 0; j < 16; ++j) {
    int c = cg*16 + j;
    float acc = 0.f;
    #pragma unroll 8
    for (int r = 0; r < 64; ++r) acc += WnS[c*68 + r] * dwBT[r*68 + u];
    Wf[(size_t)n*4096 + u*64 + c] = acc;
  }
  if (tid < 64) {
    float acc = db[tid];
    #pragma unroll 8
    for (int r = 0; r < 64; ++r) acc += bn_s[r] * dwBT[r*68 + tid];
    bf[n*64 + tid] = acc;
  }
}

// ---------------- k_wpackM ----------------
__global__ __launch_bounds__(256) void k_wpackM(
    const float* __restrict__ wih2, const float* __restrict__ whh2,
    const float* __restrict__ wih1, const float* __restrict__ whh1,
    unsigned* __restrict__ Wh2, unsigned* __restrict__ Wx2,
    unsigned* __restrict__ Wh1, unsigned* __restrict__ Wx1)
{
  int i = blockIdx.x*256 + threadIdx.x;
  if (i < 192*32) {
    int wr = i >> 5, p = i & 31;
    Wh2[i] = pkh(whh2[wr*64 + 2*p], whh2[wr*64 + 2*p + 1]);
    Wx2[i] = pkh(wih2[wr*64 + 2*p], wih2[wr*64 + 2*p + 1]);
    Wh1[i] = pkh(whh1[wr*64 + 2*p], whh1[wr*64 + 2*p + 1]);
  }
  int j = i - 192*32;
  if (j >= 0 && j < 192*16) {
    int wr = j >> 4, p = j & 15;
    Wx1[j] = (p < 5) ? pkh(wih1[wr*10 + 2*p], wih1[wr*10 + 2*p + 1]) : 0u;
  }
}

// ---------------- k_gruM: MFMA GRU scan ----------------
template<int DIN, bool WFIN>
__global__ __launch_bounds__(256, 3) void k_gruM(
    const float* __restrict__ xseq,
    const unsigned* __restrict__ Whf,
    const unsigned* __restrict__ Wxf,
    const float* __restrict__ bih, const float* __restrict__ bhh,
    float* __restrict__ o_out)
{
  constexpr int XPR = (DIN == 64) ? 32 : 16;
  constexpr int XKS = XPR / 16;
  constexpr int XST = XPR + 4;
  __shared__ __align__(16) unsigned Ah_s[16*36];
  __shared__ __align__(16) unsigned Ax_s[16*XST];
  const int tid = threadIdx.x;
  const int lane = tid & 63, w = tid >> 6;
  const int fr = lane & 15, fq = lane >> 4;
  const int row0 = blockIdx.x * 16;
  const int u = w*16 + fr;

  f16x8 bh_r[2], bh_z[2], bh_n[2];
  #pragma unroll
  for (int ks = 0; ks < 2; ++ks) {
    bh_r[ks] = *(const f16x8*)&Whf[(size_t)u*32        + ks*16 + fq*4];
    bh_z[ks] = *(const f16x8*)&Whf[(size_t)(64+u)*32   + ks*16 + fq*4];
    bh_n[ks] = *(const f16x8*)&Whf[(size_t)(128+u)*32  + ks*16 + fq*4];
  }
  f16x8 bx_r[XKS], bx_z[XKS], bx_n[XKS];
  #pragma unroll
  for (int ks = 0; ks < XKS; ++ks) {
    bx_r[ks] = *(const f16x8*)&Wxf[(size_t)u*XPR       + ks*16 + fq*4];
    bx_z[ks] = *(const f16x8*)&Wxf[(size_t)(64+u)*XPR  + ks*16 + fq*4];
    bx_n[ks] = *(const f16x8*)&Wxf[(size_t)(128+u)*XPR + ks*16 + fq*4];
  }

  const float brc = bih[u]     + bhh[u];
  const float bzc = bih[64+u]  + bhh[64+u];
  const float bxn = bih[128+u];
  const float bhn = bhh[128+u];

  for (int i = tid; i < 16*36;  i += 256) Ah_s[i] = 0u;
  for (int i = tid; i < 16*XST; i += 256) Ax_s[i] = 0u;
  __syncthreads();   // order zero-init before t=0 x staging (R11 race fix)

  size_t obase[4];
  #pragma unroll
  for (int reg = 0; reg < 4; ++reg) {
    int g = row0 + fq*4 + reg;
    if (WFIN) { int bb = g / N_, nn = g - bb*N_; obase[reg] = (((size_t)bb*T_)*N_ + nn)*64 + u; }
    else      { obase[reg] = (size_t)g*64 + u; }
  }
  const size_t tstep = WFIN ? (size_t)N_*64 : (size_t)M_*64;
  float hreg[4] = {0.f, 0.f, 0.f, 0.f};

  for (int t = 0; t < T_; ++t) {
    if (DIN == 64) {
      #pragma unroll
      for (int it = 0; it < 2; ++it) {
        int idx = tid + it*256;
        int row = idx >> 5, p = idx & 31;
        const float2 v = *(const float2*)&xseq[((size_t)t*M_ + row0 + row)*64 + 2*p];
        Ax_s[row*XST + p] = pkh(v.x, v.y);
      }
    } else {
      if (tid < 80) {
        int row = tid / 5, p = tid - (tid/5)*5;
        const float2 v = *(const float2*)&xseq[((size_t)t*M_ + row0 + row)*10 + 2*p];
        Ax_s[row*XST + p] = pkh(v.x, v.y);
      }
    }
    __syncthreads();

    f32x4 ar  = {0.f,0.f,0.f,0.f}, az  = {0.f,0.f,0.f,0.f};
    f32x4 anh = {0.f,0.f,0.f,0.f}, anx = {0.f,0.f,0.f,0.f};
    #pragma unroll
    for (int ks = 0; ks < 2; ++ks) {
      f16x8 ah = *(const f16x8*)&Ah_s[fr*36 + ks*16 + fq*4];
      ar  = __builtin_amdgcn_mfma_f32_16x16x32_f16(ah, bh_r[ks], ar,  0,0,0);
      az  = __builtin_amdgcn_mfma_f32_16x16x32_f16(ah, bh_z[ks], az,  0,0,0);
      anh = __builtin_amdgcn_mfma_f32_16x16x32_f16(ah, bh_n[ks], anh, 0,0,0);
    }
    #pragma unroll
    for (int ks = 0; ks < XKS; ++ks) {
      f16x8 ax = *(const f16x8*)&Ax_s[fr*XST + ks*16 + fq*4];
      ar  = __builtin_amdgcn_mfma_f32_16x16x32_f16(ax, bx_r[ks], ar,  0,0,0);
      az  = __builtin_amdgcn_mfma_f32_16x16x32_f16(ax, bx_z[ks], az,  0,0,0);
      anx = __builtin_amdgcn_mfma_f32_16x16x32_f16(ax, bx_n[ks], anx, 0,0,0);
    }

    float o_new[4];
    #pragma unroll
    for (int reg = 0; reg < 4; ++reg) {
      float rg = sigm(ar[reg] + brc);
      float zg = sigm(az[reg] + bzc);
      float ng = tanhf(anx[reg] + bxn + rg*(anh[reg] + bhn));
      o_new[reg] = (1.f - zg)*ng + zg*hreg[reg];
      hreg[reg] = o_new[reg];
    }
    #pragma unroll
    for (int reg = 0; reg < 4; ++reg)
      o_out[obase[reg] + (size_t)t*tstep] = o_new[reg];

    unsigned pk[4];
    #pragma unroll
    for (int reg = 0; reg < 4; ++reg) {
      float pr = __shfl_xor(o_new[reg], 1);
      pk[reg] = pkh(o_new[reg], pr);
    }
    __syncthreads();
    if ((fr & 1) == 0) {
      #pragma unroll
      for (int reg = 0; reg < 4; ++reg)
        Ah_s[(fq*4 + reg)*36 + w*8 + (fr >> 1)] = pk[reg];
    }
  }
}

// ---------------- stage C ----------------
__global__ __launch_bounds__(256) void k_stageC(
    const float* __restrict__ out1, const float* __restrict__ emb1,
    const float* __restrict__ w1, const float* __restrict__ b1,
    const float* __restrict__ w2, const float* __restrict__ b2,
    const float* __restrict__ w3, const float* __restrict__ b3,
    float* __restrict__ ndv)
{
  int idx = blockIdx.x*256 + threadIdx.x;
  int m = idx % M_;
  int n = m % N_;
  float rv[64];
  const float4* r4 = (const float4*)(out1 + (size_t)idx*64);
  #pragma unroll
  for (int q=0;q<16;++q){ float4 v=r4[q]; rv[q*4]=v.x; rv[q*4+1]=v.y; rv[q*4+2]=v.z; rv[q*4+3]=v.w; }
  float h1[16];
  for (int u=0;u<16;++u){
    float a = b1[u];
    const float* wr = w1 + u*64;
    #pragma unroll
    for (int c=0;c<64;++c) a += rv[c]*wr[c];
    h1[u] = sigm(a);
  }
  float h2[2];
  #pragma unroll
  for (int v=0;v<2;++v){
    float a = b2[v];
    #pragma unroll
    for (int u=0;u<16;++u) a += h1[u]*w2[v*16+u];
    h2[v] = sigm(a);
  }
  #pragma unroll
  for (int d=0;d<10;++d){
    float f = b3[d] + h2[0]*w3[d*2] + h2[1]*w3[d*2+1];
    ndv[(size_t)idx*10 + d] = tanhf(emb1[n*10+d]*f);
  }
}

// ---------------- stage D (full MFMA): S = relu(Vp@Vp^T) via MFMA1, PV via MFMA2 ----------------
__global__ __launch_bounds__(256, 2) void k_stageDM(
    const float* __restrict__ ndv, const float* __restrict__ out1, float* __restrict__ xg)
{
  int tb = blockIdx.x;
  const int tid = threadIdx.x;
  const int lane = tid & 63, wid = tid >> 6;
  const int fr = lane & 15, fq = lane >> 4;

  __shared__ __align__(16) unsigned Vp_s[320*20];   // f16 pairs of V, K=32 zero-padded
  __shared__ __align__(16) unsigned P_s[320*36];
  __shared__ __align__(16) unsigned O_s[64*36];

  // stage Vp: row n, 16 k-pairs (5 real), stride 20
  for (int i = tid; i < 320*20; i += 256) {
    int nn = i / 20, p = i - nn*20;
    float a = 0.f, b = 0.f;
    if (nn < N_ && p < 5) {
      const float2 v = *(const float2*)&ndv[((size_t)tb*N_ + nn)*10 + 2*p];
      a = v.x; b = v.y;
    }
    Vp_s[i] = pkh(a, b);
  }
  __syncthreads();

  f32x4 acc[5][4];
  #pragma unroll
  for (int a = 0; a < 5; ++a)
    #pragma unroll
    for (int c = 0; c < 4; ++c)
      acc[a][c] = (f32x4){0.f, 0.f, 0.f, 0.f};

  const float* ob = out1 + (size_t)tb*N_*64;

  for (int mc = 0; mc < 320; mc += 64) {
    // ---- stage O chunk transposed as f16 pairs: O_s[col][m-pair]
    for (int it = tid; it < 512; it += 256) {
      int p = it >> 4, cg = it & 15;
      int m0 = mc + 2*p;
      float4 a = make_float4(0.f,0.f,0.f,0.f), b = a;
      if (m0     < N_) a = *(const float4*)&ob[(size_t)m0*64 + cg*4];
      if (m0 + 1 < N_) b = *(const float4*)&ob[(size_t)(m0+1)*64 + cg*4];
      int c0 = cg*4;
      O_s[(c0+0)*36 + p] = pkh(a.x, b.x);
      O_s[(c0+1)*36 + p] = pkh(a.y, b.y);
      O_s[(c0+2)*36 + p] = pkh(a.z, b.z);
      O_s[(c0+3)*36 + p] = pkh(a.w, b.w);
    }
    // ---- MFMA1: S-chunk [rows n x 64 m] = Vp @ Vp^T, then relu + pair-pack into P_s
    f16x8 vb[4];
    #pragma unroll
    for (int ct = 0; ct < 4; ++ct)
      vb[ct] = *(const f16x8*)&Vp_s[(mc + ct*16 + fr)*20 + fq*4];
    #pragma unroll
    for (int a = 0; a < 5; ++a) {
      f16x8 va = *(const f16x8*)&Vp_s[((wid + 4*a)*16 + fr)*20 + fq*4];
      f32x4 s[4];
      #pragma unroll
      for (int ct = 0; ct < 4; ++ct)
        s[ct] = (f32x4){0.f,0.f,0.f,0.f};
      #pragma unroll
      for (int ct = 0; ct < 4; ++ct)
        s[ct] = __builtin_amdgcn_mfma_f32_16x16x32_f16(va, vb[ct], s[ct], 0, 0, 0);
      // C: m-col = ct*16+fr, n-row = (wid+4a)*16 + fq*4+reg. Pack (m even, m+1) via lane^1.
      #pragma unroll
      for (int ct = 0; ct < 4; ++ct) {
        #pragma unroll
        for (int reg = 0; reg < 4; ++reg) {
          float v0 = fmaxf(s[ct][reg], 0.f);
          float v1 = __shfl_xor(v0, 1);
          if ((fr & 1) == 0) {
            int nn = (wid + 4*a)*16 + fq*4 + reg;
            P_s[nn*36 + ct*8 + (fr >> 1)] = pkh(v0, v1);
          }
        }
      }
    }
    __syncthreads();

    // ---- MFMA2: acc += P (rows n) @ O (cols)
    #pragma unroll
    for (int ks = 0; ks < 2; ++ks) {
      int kd = ks*16 + fq*4;
      f16x8 bf[4];
      #pragma unroll
      for (int ct = 0; ct < 4; ++ct)
        bf[ct] = *(const f16x8*)&O_s[(ct*16 + fr)*36 + kd];
      #pragma unroll
      for (int a = 0; a < 5; ++a) {
        f16x8 af = *(const f16x8*)&P_s[((wid + 4*a)*16 + fr)*36 + kd];
        #pragma unroll
        for (int ct = 0; ct < 4; ++ct)
          acc[a][ct] = __builtin_amdgcn_mfma_f32_16x16x32_f16(af, bf[ct], acc[a][ct], 0, 0, 0);
      }
    }
    __syncthreads();
  }

  // ---- epilogue: xg = out1 + acc
  #pragma unroll
  for (int a = 0; a < 5; ++a) {
    #pragma unroll
    for (int ct = 0; ct < 4; ++ct) {
      int col = ct*16 + fr;
      #pragma unroll
      for (int reg = 0; reg < 4; ++reg) {
        int n = (wid + 4*a)*16 + fq*4 + reg;
        if (n < N_) {
          size_t base = (size_t)tb*N_*64 + (size_t)n*64 + col;
          xg[base] = out1[base] + acc[a][ct][reg];
        }
      }
    }
  }
}

// ---------------- stage E (MFMA): g2 = [o|x] @ [dwA|Wf[n]]^T + bf[n] ----------------
__global__ __launch_bounds__(256) void k_stageEM(
    const float* xg_in, const float* __restrict__ out1,
    const float* __restrict__ Wf, const float* __restrict__ dw,
    const float* __restrict__ bf,
    float* xg_out)
{
  int n = blockIdx.y;
  int tile = blockIdx.x;     // 12 tiles of 64 tb-rows
  const int tid = threadIdx.x;
  const int lane = tid & 63, w = tid >> 6;
  const int fr = lane & 15, fq = lane >> 4;
  __shared__ __align__(16) unsigned As[64*68];   // [row][64 k-pairs: o|x]
  __shared__ __align__(16) unsigned Bs[64*68];   // [u][64 k-pairs: dwA|Wf]
  __shared__ float bf_s[64];

  for (int idx = tid; idx < 1024; idx += 256) {
    int row = idx >> 4, c4 = idx & 15;
    size_t g = ((size_t)(tile*64 + row)*N_ + n)*64 + c4*4;
    float4 o  = *(const float4*)&out1[g];
    float4 xv = *(const float4*)&xg_in[g];
    As[row*68 + c4*2]          = pkh(o.x, o.y);
    As[row*68 + c4*2 + 1]      = pkh(o.z, o.w);
    As[row*68 + 32 + c4*2]     = pkh(xv.x, xv.y);
    As[row*68 + 32 + c4*2 + 1] = pkh(xv.z, xv.w);
    int u = row;
    float4 da = *(const float4*)&dw[u*128 + c4*4];
    float4 wf = *(const float4*)&Wf[(size_t)n*4096 + u*64 + c4*4];
    Bs[u*68 + c4*2]          = pkh(da.x, da.y);
    Bs[u*68 + c4*2 + 1]      = pkh(da.z, da.w);
    Bs[u*68 + 32 + c4*2]     = pkh(wf.x, wf.y);
    Bs[u*68 + 32 + c4*2 + 1] = pkh(wf.z, wf.w);
  }
  if (tid < 64) bf_s[tid] = bf[n*64 + tid];
  __syncthreads();

  f32x4 acc[4];
  #pragma unroll
  for (int ct = 0; ct < 4; ++ct) acc[ct] = (f32x4){0.f,0.f,0.f,0.f};

  #pragma unroll
  for (int ks = 0; ks < 4; ++ks) {
    f16x8 af = *(const f16x8*)&As[(w*16 + fr)*68 + ks*16 + fq*4];
    #pragma unroll
    for (int ct = 0; ct < 4; ++ct) {
      f16x8 bfr = *(const f16x8*)&Bs[(ct*16 + fr)*68 + ks*16 + fq*4];
      acc[ct] = __builtin_amdgcn_mfma_f32_16x16x32_f16(af, bfr, acc[ct], 0, 0, 0);
    }
  }

  #pragma unroll
  for (int ct = 0; ct < 4; ++ct) {
    int u = ct*16 + fr;
    float bfv = bf_s[u];
    #pragma unroll
    for (int reg = 0; reg < 4; ++reg) {
      int row = w*16 + fq*4 + reg;
      xg_out[((size_t)(tile*64 + row)*N_ + n)*64 + u] = acc[ct][reg] + bfv;
    }
  }
}

extern "C" void kernel_launch(void* const* d_in, const int* in_sizes, int n_in,
                              void* d_out, int out_size, void* d_ws, size_t ws_size,
                              hipStream_t stream)
{
  (void)in_sizes; (void)n_in; (void)out_size;
  const float* x    = (const float*)d_in[0];
  const float* emb1 = (const float*)d_in[1];
  const float* emb2 = (const float*)d_in[2];
  const float* xw1  = (const float*)d_in[3];
  const float* xb1  = (const float*)d_in[4];
  const float* xw2  = (const float*)d_in[5];
  const float* xb2  = (const float*)d_in[6];
  const float* xw3  = (const float*)d_in[7];
  const float* xb3  = (const float*)d_in[8];
  const float* fw1  = (const float*)d_in[9];
  const float* fb1  = (const float*)d_in[10];
  const float* fw2  = (const float*)d_in[11];
  const float* fb2  = (const float*)d_in[12];
  const float* fw3  = (const float*)d_in[13];
  const float* fb3  = (const float*)d_in[14];
  const float* c2w1 = (const float*)d_in[15];
  const float* c2b1 = (const float*)d_in[16];
  const float* c2w2 = (const float*)d_in[17];
  const float* c2b2 = (const float*)d_in[18];
  const float* c2w3 = (const float*)d_in[19];
  const float* c2b3 = (const float*)d_in[20];
  const float* g1wih= (const float*)d_in[21];
  const float* g1whh= (const float*)d_in[22];
  const float* g1bih= (const float*)d_in[23];
  const float* g1bhh= (const float*)d_in[24];
  const float* g2wih= (const float*)d_in[25];
  const float* g2whh= (const float*)d_in[26];
  const float* g2bih= (const float*)d_in[27];
  const float* g2bhh= (const float*)d_in[28];
  const float* wpool= (const float*)d_in[29];
  const float* bpool= (const float*)d_in[30];
  const float* dww  = (const float*)d_in[31];
  const float* dwb  = (const float*)d_in[32];
  float* out = (float*)d_out;

  float* ws = (float*)d_ws;
  float* g1_in = ws;                          // TM*10
  float* out1  = g1_in + (size_t)TM_*10;      // TM*64
  float* ndv   = out1 + (size_t)TM_*64;       // TM*10
  float* xg    = ndv + (size_t)TM_*10;        // TM*64
  float* Wn    = xg + (size_t)TM_*64;         // N*4096
  float* bn    = Wn + (size_t)N_*4096;        // N*64
  float* Wf    = bn + (size_t)N_*64;          // N*4096
  float* bf    = Wf + (size_t)N_*4096;        // N*64
  unsigned* Wh2f = (unsigned*)(bf + (size_t)N_*64);   // 192*32
  unsigned* Wx2f = Wh2f + 192*32;                     // 192*32
  unsigned* Wh1f = Wx2f + 192*32;                     // 192*32
  unsigned* Wx1f = Wh1f + 192*32;                     // 192*16
  size_t need = ((size_t)((char*)(Wx1f + 192*16) - (char*)ws));
  if (ws_size < need) return;

  k_stageA<<<TM_/256, 256, 0, stream>>>(x, xw1,xb1,xw2,xb2,xw3,xb3, fw1,fb1,fw2,fb2,fw3,fb3, g1_in);
  k_wn<<<N_, 256, 0, stream>>>(emb2, wpool, bpool, Wn, bn);
  k_wf<<<N_, 256, 0, stream>>>(Wn, bn, dww, dwb, Wf, bf);
  k_wpackM<<<(192*32 + 192*16 + 255)/256, 256, 0, stream>>>(
      g2wih, g2whh, g1wih, g1whh, Wh2f, Wx2f, Wh1f, Wx1f);

  // GRU1: x = g1_in (DIN=10), output out1 [T][M][64]
  k_gruM<10,false><<<M_/16, 256, 0, stream>>>(g1_in, Wh1f, Wx1f, g1bih, g1bhh, out1);

  k_stageC<<<TM_/256, 256, 0, stream>>>(out1, emb1, c2w1,c2b1,c2w2,c2b2,c2w3,c2b3, ndv);
  k_stageDM<<<T_*B_, 256, 0, stream>>>(ndv, out1, xg);
  k_stageEM<<<dim3(12, N_), 256, 0, stream>>>(xg, out1, Wf, dww, bf, xg);

  // GRU2: x = xg (DIN=64), output [B][T][N][64]
  k_gruM<64,true><<<M_/16, 256, 0, stream>>>(xg, Wh2f, Wx2f, g2bih, g2bhh, out);
}

// Round 14
// 258.870 us; speedup vs baseline: 58.9338x; 1.1340x over previous
//
#include <hip/hip_runtime.h>
#include <hip/hip_fp16.h>
#include <math.h>

#define B_ 64
#define T_ 12
#define N_ 307
#define I_ 3
#define R_ 64
#define D_ 10
#define M_ (B_*N_)      // 19648
#define TM_ (T_*M_)     // 235776

typedef _Float16 f16x8 __attribute__((ext_vector_type(8)));
typedef float f32x4 __attribute__((ext_vector_type(4)));

__device__ __forceinline__ float sigm(float x){ return 1.f/(1.f+__expf(-x)); }

// pack two f32 -> one dword of 2 f16 (RTZ)
__device__ __forceinline__ unsigned pkh(float a, float b){
  unsigned r;
  asm("v_cvt_pkrtz_f16_f32 %0, %1, %2" : "=v"(r) : "v"(a), "v"(b));
  return r;
}

// ---------------- stage A ----------------
__global__ __launch_bounds__(256) void k_stageA(
    const float* __restrict__ x,
    const float* __restrict__ xw1, const float* __restrict__ xb1,
    const float* __restrict__ xw2, const float* __restrict__ xb2,
    const float* __restrict__ xw3, const float* __restrict__ xb3,
    const float* __restrict__ fw1, const float* __restrict__ fb1,
    const float* __restrict__ fw2, const float* __restrict__ fb2,
    const float* __restrict__ fw3, const float* __restrict__ fb3,
    float* __restrict__ g1)
{
  int idx = blockIdx.x*256 + threadIdx.x;
  int t = idx / M_;
  int m = idx - t*M_;
  int b = m / N_;
  int n = m - b*N_;
  const float* xp = x + (((size_t)b*T_ + t)*N_ + n)*I_;
  float xv[3] = {xp[0], xp[1], xp[2]};
  float e[3][10];
  #pragma unroll
  for (int i=0;i<3;++i){
    float h1[16];
    #pragma unroll
    for (int u=0;u<16;++u) h1[u] = sigm(xv[i]*xw1[u] + xb1[u]);
    float h2[2];
    #pragma unroll
    for (int v=0;v<2;++v){
      float a = xb2[v];
      #pragma unroll
      for (int u=0;u<16;++u) a += h1[u]*xw2[v*16+u];
      h2[v] = sigm(a);
    }
    #pragma unroll
    for (int d=0;d<10;++d) e[i][d] = xb3[d] + h2[0]*xw3[d*2] + h2[1]*xw3[d*2+1];
  }
  float in1[3];
  #pragma unroll
  for (int j=0;j<3;++j){
    float acc = 0.f;
    #pragma unroll
    for (int i=0;i<3;++i){
      float s = 0.f;
      #pragma unroll
      for (int d=0;d<10;++d) s += e[j][d]*e[i][d];
      s = fmaxf(s, 0.f);
      acc += s*xv[i];
    }
    in1[j] = xv[j] + acc;
  }
  float h1[16];
  #pragma unroll
  for (int u=0;u<16;++u)
    h1[u] = sigm(fb1[u] + in1[0]*fw1[u*3] + in1[1]*fw1[u*3+1] + in1[2]*fw1[u*3+2]);
  float h2[2];
  #pragma unroll
  for (int v=0;v<2;++v){
    float a = fb2[v];
    #pragma unroll
    for (int u=0;u<16;++u) a += h1[u]*fw2[v*16+u];
    h2[v] = sigm(a);
  }
  float* gp = g1 + (size_t)idx*10;
  #pragma unroll
  for (int d=0;d<10;++d) gp[d] = fb3[d] + h2[0]*fw3[d*2] + h2[1]*fw3[d*2+1];
}

// ---------------- k_wn ----------------
__global__ __launch_bounds__(256) void k_wn(
    const float* __restrict__ emb2, const float* __restrict__ wpool,
    const float* __restrict__ bpool, float* __restrict__ Wn, float* __restrict__ bn)
{
  int n = blockIdx.x; int tid = threadIdx.x;
  __shared__ float e_s[10];
  if (tid < 10) e_s[tid] = emb2[n*10 + tid];
  __syncthreads();
  #pragma unroll
  for (int e=0;e<16;++e){
    int i = e*256 + tid;
    float a = 0.f;
    #pragma unroll
    for (int d=0;d<10;++d) a += e_s[d]*wpool[(size_t)d*4096 + i];
    Wn[(size_t)n*4096 + i] = a;
  }
  if (tid < 64){
    float a = 0.f;
    #pragma unroll
    for (int d=0;d<10;++d) a += e_s[d]*bpool[d*64 + tid];
    bn[n*64 + tid] = a;
  }
}

// ---------------- k_wf ----------------
__global__ __launch_bounds__(256) void k_wf(
    const float* __restrict__ Wn, const float* __restrict__ bn,
    const float* __restrict__ dw, const float* __restrict__ db,
    float* __restrict__ Wf, float* __restrict__ bf)
{
  int n = blockIdx.x; int tid = threadIdx.x;
  __shared__ float WnS[64*68];
  __shared__ float dwBT[64*68];
  __shared__ float bn_s[64];
  for (int idx = tid; idx < 4096; idx += 256) {
    int c = idx >> 6, r = idx & 63;
    WnS[c*68 + r] = Wn[(size_t)n*4096 + idx];
  }
  for (int idx = tid; idx < 4096; idx += 256) {
    int u = idx >> 6, r = idx & 63;
    dwBT[r*68 + u] = dw[u*128 + 64 + r];
  }
  if (tid < 64) bn_s[tid] = bn[n*64 + tid];
  __syncthreads();
  int u = tid & 63, cg = tid >> 6;
  #pragma unroll
  for (int j = 0; j < 16; ++j) {
    int c = cg*16 + j;
    float acc = 0.f;
    #pragma unroll 8
    for (int r = 0; r < 64; ++r) acc += WnS[c*68 + r] * dwBT[r*68 + u];
    Wf[(size_t)n*4096 + u*64 + c] = acc;
  }
  if (tid < 64) {
    float acc = db[tid];
    #pragma unroll 8
    for (int r = 0; r < 64; ++r) acc += bn_s[r] * dwBT[r*68 + tid];
    bf[n*64 + tid] = acc;
  }
}

// ---------------- k_wpackM ----------------
__global__ __launch_bounds__(256) void k_wpackM(
    const float* __restrict__ wih2, const float* __restrict__ whh2,
    const float* __restrict__ wih1, const float* __restrict__ whh1,
    unsigned* __restrict__ Wh2, unsigned* __restrict__ Wx2,
    unsigned* __restrict__ Wh1, unsigned* __restrict__ Wx1)
{
  int i = blockIdx.x*256 + threadIdx.x;
  if (i < 192*32) {
    int wr = i >> 5, p = i & 31;
    Wh2[i] = pkh(whh2[wr*64 + 2*p], whh2[wr*64 + 2*p + 1]);
    Wx2[i] = pkh(wih2[wr*64 + 2*p], wih2[wr*64 + 2*p + 1]);
    Wh1[i] = pkh(whh1[wr*64 + 2*p], whh1[wr*64 + 2*p + 1]);
  }
  int j = i - 192*32;
  if (j >= 0 && j < 192*16) {
    int wr = j >> 4, p = j & 15;
    Wx1[j] = (p < 5) ? pkh(wih1[wr*10 + 2*p], wih1[wr*10 + 2*p + 1]) : 0u;
  }
}

// ---------------- k_gruM: MFMA GRU scan ----------------
template<int DIN, bool WFIN>
__global__ __launch_bounds__(256, 3) void k_gruM(
    const float* __restrict__ xseq,
    const unsigned* __restrict__ Whf,
    const unsigned* __restrict__ Wxf,
    const float* __restrict__ bih, const float* __restrict__ bhh,
    float* __restrict__ o_out)
{
  constexpr int XPR = (DIN == 64) ? 32 : 16;
  constexpr int XKS = XPR / 16;
  constexpr int XST = XPR + 4;
  __shared__ __align__(16) unsigned Ah_s[16*36];
  __shared__ __align__(16) unsigned Ax_s[16*XST];
  const int tid = threadIdx.x;
  const int lane = tid & 63, w = tid >> 6;
  const int fr = lane & 15, fq = lane >> 4;
  const int row0 = blockIdx.x * 16;
  const int u = w*16 + fr;

  f16x8 bh_r[2], bh_z[2], bh_n[2];
  #pragma unroll
  for (int ks = 0; ks < 2; ++ks) {
    bh_r[ks] = *(const f16x8*)&Whf[(size_t)u*32        + ks*16 + fq*4];
    bh_z[ks] = *(const f16x8*)&Whf[(size_t)(64+u)*32   + ks*16 + fq*4];
    bh_n[ks] = *(const f16x8*)&Whf[(size_t)(128+u)*32  + ks*16 + fq*4];
  }
  f16x8 bx_r[XKS], bx_z[XKS], bx_n[XKS];
  #pragma unroll
  for (int ks = 0; ks < XKS; ++ks) {
    bx_r[ks] = *(const f16x8*)&Wxf[(size_t)u*XPR       + ks*16 + fq*4];
    bx_z[ks] = *(const f16x8*)&Wxf[(size_t)(64+u)*XPR  + ks*16 + fq*4];
    bx_n[ks] = *(const f16x8*)&Wxf[(size_t)(128+u)*XPR + ks*16 + fq*4];
  }

  const float brc = bih[u]     + bhh[u];
  const float bzc = bih[64+u]  + bhh[64+u];
  const float bxn = bih[128+u];
  const float bhn = bhh[128+u];

  for (int i = tid; i < 16*36;  i += 256) Ah_s[i] = 0u;
  for (int i = tid; i < 16*XST; i += 256) Ax_s[i] = 0u;
  __syncthreads();   // order zero-init before t=0 x staging (R11 race fix)

  size_t obase[4];
  #pragma unroll
  for (int reg = 0; reg < 4; ++reg) {
    int g = row0 + fq*4 + reg;
    if (WFIN) { int bb = g / N_, nn = g - bb*N_; obase[reg] = (((size_t)bb*T_)*N_ + nn)*64 + u; }
    else      { obase[reg] = (size_t)g*64 + u; }
  }
  const size_t tstep = WFIN ? (size_t)N_*64 : (size_t)M_*64;
  float hreg[4] = {0.f, 0.f, 0.f, 0.f};

  for (int t = 0; t < T_; ++t) {
    if (DIN == 64) {
      #pragma unroll
      for (int it = 0; it < 2; ++it) {
        int idx = tid + it*256;
        int row = idx >> 5, p = idx & 31;
        const float2 v = *(const float2*)&xseq[((size_t)t*M_ + row0 + row)*64 + 2*p];
        Ax_s[row*XST + p] = pkh(v.x, v.y);
      }
    } else {
      if (tid < 80) {
        int row = tid / 5, p = tid - (tid/5)*5;
        const float2 v = *(const float2*)&xseq[((size_t)t*M_ + row0 + row)*10 + 2*p];
        Ax_s[row*XST + p] = pkh(v.x, v.y);
      }
    }
    __syncthreads();

    f32x4 ar  = {0.f,0.f,0.f,0.f}, az  = {0.f,0.f,0.f,0.f};
    f32x4 anh = {0.f,0.f,0.f,0.f}, anx = {0.f,0.f,0.f,0.f};
    #pragma unroll
    for (int ks = 0; ks < 2; ++ks) {
      f16x8 ah = *(const f16x8*)&Ah_s[fr*36 + ks*16 + fq*4];
      ar  = __builtin_amdgcn_mfma_f32_16x16x32_f16(ah, bh_r[ks], ar,  0,0,0);
      az  = __builtin_amdgcn_mfma_f32_16x16x32_f16(ah, bh_z[ks], az,  0,0,0);
      anh = __builtin_amdgcn_mfma_f32_16x16x32_f16(ah, bh_n[ks], anh, 0,0,0);
    }
    #pragma unroll
    for (int ks = 0; ks < XKS; ++ks) {
      f16x8 ax = *(const f16x8*)&Ax_s[fr*XST + ks*16 + fq*4];
      ar  = __builtin_amdgcn_mfma_f32_16x16x32_f16(ax, bx_r[ks], ar,  0,0,0);
      az  = __builtin_amdgcn_mfma_f32_16x16x32_f16(ax, bx_z[ks], az,  0,0,0);
      anx = __builtin_amdgcn_mfma_f32_16x16x32_f16(ax, bx_n[ks], anx, 0,0,0);
    }

    float o_new[4];
    #pragma unroll
    for (int reg = 0; reg < 4; ++reg) {
      float rg = sigm(ar[reg] + brc);
      float zg = sigm(az[reg] + bzc);
      float ng = tanhf(anx[reg] + bxn + rg*(anh[reg] + bhn));
      o_new[reg] = (1.f - zg)*ng + zg*hreg[reg];
      hreg[reg] = o_new[reg];
    }
    #pragma unroll
    for (int reg = 0; reg < 4; ++reg)
      o_out[obase[reg] + (size_t)t*tstep] = o_new[reg];

    unsigned pk[4];
    #pragma unroll
    for (int reg = 0; reg < 4; ++reg) {
      float pr = __shfl_xor(o_new[reg], 1);
      pk[reg] = pkh(o_new[reg], pr);
    }
    __syncthreads();
    if ((fr & 1) == 0) {
      #pragma unroll
      for (int reg = 0; reg < 4; ++reg)
        Ah_s[(fq*4 + reg)*36 + w*8 + (fr >> 1)] = pk[reg];
    }
  }
}

// ---------------- stage C ----------------
__global__ __launch_bounds__(256) void k_stageC(
    const float* __restrict__ out1, const float* __restrict__ emb1,
    const float* __restrict__ w1, const float* __restrict__ b1,
    const float* __restrict__ w2, const float* __restrict__ b2,
    const float* __restrict__ w3, const float* __restrict__ b3,
    float* __restrict__ ndv)
{
  int idx = blockIdx.x*256 + threadIdx.x;
  int m = idx % M_;
  int n = m % N_;
  float rv[64];
  const float4* r4 = (const float4*)(out1 + (size_t)idx*64);
  #pragma unroll
  for (int q=0;q<16;++q){ float4 v=r4[q]; rv[q*4]=v.x; rv[q*4+1]=v.y; rv[q*4+2]=v.z; rv[q*4+3]=v.w; }
  float h1[16];
  for (int u=0;u<16;++u){
    float a = b1[u];
    const float* wr = w1 + u*64;
    #pragma unroll
    for (int c=0;c<64;++c) a += rv[c]*wr[c];
    h1[u] = sigm(a);
  }
  float h2[2];
  #pragma unroll
  for (int v=0;v<2;++v){
    float a = b2[v];
    #pragma unroll
    for (int u=0;u<16;++u) a += h1[u]*w2[v*16+u];
    h2[v] = sigm(a);
  }
  #pragma unroll
  for (int d=0;d<10;++d){
    float f = b3[d] + h2[0]*w3[d*2] + h2[1]*w3[d*2+1];
    ndv[(size_t)idx*10 + d] = tanhf(emb1[n*10+d]*f);
  }
}

// ---------------- stage D (full MFMA, symmetric-transposed S pack) ----------------
// MFMA1 computes the S-chunk TRANSPOSED (A = V m-rows, B = V n-cols) so each lane
// holds 4 consecutive m for fixed n -> pair-pack is lane-local (no shfl, no idle lanes).
__global__ __launch_bounds__(256, 2) void k_stageDM(
    const float* __restrict__ ndv, const float* __restrict__ out1, float* __restrict__ xg)
{
  int tb = blockIdx.x;
  const int tid = threadIdx.x;
  const int lane = tid & 63, wid = tid >> 6;
  const int fr = lane & 15, fq = lane >> 4;

  __shared__ __align__(16) unsigned Vp_s[320*20];   // f16 pairs of V, K=32 zero-padded
  __shared__ __align__(16) unsigned P_s[320*36];
  __shared__ __align__(16) unsigned O_s[64*36];

  for (int i = tid; i < 320*20; i += 256) {
    int nn = i / 20, p = i - nn*20;
    float a = 0.f, b = 0.f;
    if (nn < N_ && p < 5) {
      const float2 v = *(const float2*)&ndv[((size_t)tb*N_ + nn)*10 + 2*p];
      a = v.x; b = v.y;
    }
    Vp_s[i] = pkh(a, b);
  }
  __syncthreads();

  f32x4 acc[5][4];
  #pragma unroll
  for (int a = 0; a < 5; ++a)
    #pragma unroll
    for (int c = 0; c < 4; ++c)
      acc[a][c] = (f32x4){0.f, 0.f, 0.f, 0.f};

  const float* ob = out1 + (size_t)tb*N_*64;

  for (int mc = 0; mc < 320; mc += 64) {
    // ---- stage O chunk transposed as f16 pairs: O_s[col][m-pair]
    for (int it = tid; it < 512; it += 256) {
      int p = it >> 4, cg = it & 15;
      int m0 = mc + 2*p;
      float4 a = make_float4(0.f,0.f,0.f,0.f), b = a;
      if (m0     < N_) a = *(const float4*)&ob[(size_t)m0*64 + cg*4];
      if (m0 + 1 < N_) b = *(const float4*)&ob[(size_t)(m0+1)*64 + cg*4];
      int c0 = cg*4;
      O_s[(c0+0)*36 + p] = pkh(a.x, b.x);
      O_s[(c0+1)*36 + p] = pkh(a.y, b.y);
      O_s[(c0+2)*36 + p] = pkh(a.z, b.z);
      O_s[(c0+3)*36 + p] = pkh(a.w, b.w);
    }
    // ---- MFMA1 (transposed): per (nt, mt): lane holds S(m=mt*16+fq*4+reg, n=nt*16+fr).
    // ReLU + in-lane pair-pack along m -> P_s[n][m-pair]. Waves split the 20 n-tiles.
    {
      f16x8 va[4];
      #pragma unroll
      for (int mt = 0; mt < 4; ++mt)
        va[mt] = *(const f16x8*)&Vp_s[(mc + mt*16 + fr)*20 + fq*4];
      #pragma unroll
      for (int j = 0; j < 5; ++j) {
        int nt = wid + 4*j;
        f16x8 vb = *(const f16x8*)&Vp_s[(nt*16 + fr)*20 + fq*4];
        int nn = nt*16 + fr;
        #pragma unroll
        for (int mt = 0; mt < 4; ++mt) {
          f32x4 s = (f32x4){0.f,0.f,0.f,0.f};
          s = __builtin_amdgcn_mfma_f32_16x16x32_f16(va[mt], vb, s, 0, 0, 0);
          unsigned p0 = pkh(fmaxf(s[0],0.f), fmaxf(s[1],0.f));
          unsigned p1 = pkh(fmaxf(s[2],0.f), fmaxf(s[3],0.f));
          *(uint2*)&P_s[nn*36 + mt*8 + fq*2] = make_uint2(p0, p1);
        }
      }
    }
    __syncthreads();

    // ---- MFMA2: acc += P (rows n) @ O (cols)
    #pragma unroll
    for (int ks = 0; ks < 2; ++ks) {
      int kd = ks*16 + fq*4;
      f16x8 bf[4];
      #pragma unroll
      for (int ct = 0; ct < 4; ++ct)
        bf[ct] = *(const f16x8*)&O_s[(ct*16 + fr)*36 + kd];
      #pragma unroll
      for (int a = 0; a < 5; ++a) {
        f16x8 af = *(const f16x8*)&P_s[((wid + 4*a)*16 + fr)*36 + kd];
        #pragma unroll
        for (int ct = 0; ct < 4; ++ct)
          acc[a][ct] = __builtin_amdgcn_mfma_f32_16x16x32_f16(af, bf[ct], acc[a][ct], 0, 0, 0);
      }
    }
    __syncthreads();
  }

  // ---- epilogue: xg = out1 + acc
  #pragma unroll
  for (int a = 0; a < 5; ++a) {
    #pragma unroll
    for (int ct = 0; ct < 4; ++ct) {
      int col = ct*16 + fr;
      #pragma unroll
      for (int reg = 0; reg < 4; ++reg) {
        int n = (wid + 4*a)*16 + fq*4 + reg;
        if (n < N_) {
          size_t base = (size_t)tb*N_*64 + (size_t)n*64 + col;
          xg[base] = out1[base] + acc[a][ct][reg];
        }
      }
    }
  }
}

// ---------------- stage E (MFMA): g2 = [o|x] @ [dwA|Wf[n]]^T + bf[n] ----------------
__global__ __launch_bounds__(256) void k_stageEM(
    const float* xg_in, const float* __restrict__ out1,
    const float* __restrict__ Wf, const float* __restrict__ dw,
    const float* __restrict__ bf,
    float* xg_out)
{
  int n = blockIdx.y;
  int tile = blockIdx.x;     // 12 tiles of 64 tb-rows
  const int tid = threadIdx.x;
  const int lane = tid & 63, w = tid >> 6;
  const int fr = lane & 15, fq = lane >> 4;
  __shared__ __align__(16) unsigned As[64*68];   // [row][64 k-pairs: o|x]
  __shared__ __align__(16) unsigned Bs[64*68];   // [u][64 k-pairs: dwA|Wf]
  __shared__ float bf_s[64];

  for (int idx = tid; idx < 1024; idx += 256) {
    int row = idx >> 4, c4 = idx & 15;
    size_t g = ((size_t)(tile*64 + row)*N_ + n)*64 + c4*4;
    float4 o  = *(const float4*)&out1[g];
    float4 xv = *(const float4*)&xg_in[g];
    As[row*68 + c4*2]          = pkh(o.x, o.y);
    As[row*68 + c4*2 + 1]      = pkh(o.z, o.w);
    As[row*68 + 32 + c4*2]     = pkh(xv.x, xv.y);
    As[row*68 + 32 + c4*2 + 1] = pkh(xv.z, xv.w);
    int u = row;
    float4 da = *(const float4*)&dw[u*128 + c4*4];
    float4 wf = *(const float4*)&Wf[(size_t)n*4096 + u*64 + c4*4];
    Bs[u*68 + c4*2]          = pkh(da.x, da.y);
    Bs[u*68 + c4*2 + 1]      = pkh(da.z, da.w);
    Bs[u*68 + 32 + c4*2]     = pkh(wf.x, wf.y);
    Bs[u*68 + 32 + c4*2 + 1] = pkh(wf.z, wf.w);
  }
  if (tid < 64) bf_s[tid] = bf[n*64 + tid];
  __syncthreads();

  f32x4 acc[4];
  #pragma unroll
  for (int ct = 0; ct < 4; ++ct) acc[ct] = (f32x4){0.f,0.f,0.f,0.f};

  #pragma unroll
  for (int ks = 0; ks < 4; ++ks) {
    f16x8 af = *(const f16x8*)&As[(w*16 + fr)*68 + ks*16 + fq*4];
    #pragma unroll
    for (int ct = 0; ct < 4; ++ct) {
      f16x8 bfr = *(const f16x8*)&Bs[(ct*16 + fr)*68 + ks*16 + fq*4];
      acc[ct] = __builtin_amdgcn_mfma_f32_16x16x32_f16(af, bfr, acc[ct], 0, 0, 0);
    }
  }

  #pragma unroll
  for (int ct = 0; ct < 4; ++ct) {
    int u = ct*16 + fr;
    float bfv = bf_s[u];
    #pragma unroll
    for (int reg = 0; reg < 4; ++reg) {
      int row = w*16 + fq*4 + reg;
      xg_out[((size_t)(tile*64 + row)*N_ + n)*64 + u] = acc[ct][reg] + bfv;
    }
  }
}

extern "C" void kernel_launch(void* const* d_in, const int* in_sizes, int n_in,
                              void* d_out, int out_size, void* d_ws, size_t ws_size,
                              hipStream_t stream)
{
  (void)in_sizes; (void)n_in; (void)out_size;
  const float* x    = (const float*)d_in[0];
  const float* emb1 = (const float*)d_in[1];
  const float* emb2 = (const float*)d_in[2];
  const float* xw1  = (const float*)d_in[3];
  const float* xb1  = (const float*)d_in[4];
  const float* xw2  = (const float*)d_in[5];
  const float* xb2  = (const float*)d_in[6];
  const float* xw3  = (const float*)d_in[7];
  const float* xb3  = (const float*)d_in[8];
  const float* fw1  = (const float*)d_in[9];
  const float* fb1  = (const float*)d_in[10];
  const float* fw2  = (const float*)d_in[11];
  const float* fb2  = (const float*)d_in[12];
  const float* fw3  = (const float*)d_in[13];
  const float* fb3  = (const float*)d_in[14];
  const float* c2w1 = (const float*)d_in[15];
  const float* c2b1 = (const float*)d_in[16];
  const float* c2w2 = (const float*)d_in[17];
  const float* c2b2 = (const float*)d_in[18];
  const float* c2w3 = (const float*)d_in[19];
  const float* c2b3 = (const float*)d_in[20];
  const float* g1wih= (const float*)d_in[21];
  const float* g1whh= (const float*)d_in[22];
  const float* g1bih= (const float*)d_in[23];
  const float* g1bhh= (const float*)d_in[24];
  const float* g2wih= (const float*)d_in[25];
  const float* g2whh= (const float*)d_in[26];
  const float* g2bih= (const float*)d_in[27];
  const float* g2bhh= (const float*)d_in[28];
  const float* wpool= (const float*)d_in[29];
  const float* bpool= (const float*)d_in[30];
  const float* dww  = (const float*)d_in[31];
  const float* dwb  = (const float*)d_in[32];
  float* out = (float*)d_out;

  float* ws = (float*)d_ws;
  float* g1_in = ws;                          // TM*10
  float* out1  = g1_in + (size_t)TM_*10;      // TM*64
  float* ndv   = out1 + (size_t)TM_*64;       // TM*10
  float* xg    = ndv + (size_t)TM_*10;        // TM*64
  float* Wn    = xg + (size_t)TM_*64;         // N*4096
  float* bn    = Wn + (size_t)N_*4096;        // N*64
  float* Wf    = bn + (size_t)N_*64;          // N*4096
  float* bf    = Wf + (size_t)N_*4096;        // N*64
  unsigned* Wh2f = (unsigned*)(bf + (size_t)N_*64);   // 192*32
  unsigned* Wx2f = Wh2f + 192*32;                     // 192*32
  unsigned* Wh1f = Wx2f + 192*32;                     // 192*32
  unsigned* Wx1f = Wh1f + 192*32;                     // 192*16
  size_t need = ((size_t)((char*)(Wx1f + 192*16) - (char*)ws));
  if (ws_size < need) return;

  k_stageA<<<TM_/256, 256, 0, stream>>>(x, xw1,xb1,xw2,xb2,xw3,xb3, fw1,fb1,fw2,fb2,fw3,fb3, g1_in);
  k_wn<<<N_, 256, 0, stream>>>(emb2, wpool, bpool, Wn, bn);
  k_wf<<<N_, 256, 0, stream>>>(Wn, bn, dww, dwb, Wf, bf);
  k_wpackM<<<(192*32 + 192*16 + 255)/256, 256, 0, stream>>>(
      g2wih, g2whh, g1wih, g1whh, Wh2f, Wx2f, Wh1f, Wx1f);

  // GRU1: x = g1_in (DIN=10), output out1 [T][M][64]
  k_gruM<10,false><<<M_/16, 256, 0, stream>>>(g1_in, Wh1f, Wx1f, g1bih, g1bhh, out1);

  k_stageC<<<TM_/256, 256, 0, stream>>>(out1, emb1, c2w1,c2b1,c2w2,c2b2,c2w3,c2b3, ndv);
  k_stageDM<<<T_*B_, 256, 0, stream>>>(ndv, out1, xg);
  k_stageEM<<<dim3(12, N_), 256, 0, stream>>>(xg, out1, Wf, dww, bf, xg);

  // GRU2: x = xg (DIN=64), output [B][T][N][64]
  k_gruM<64,true><<<M_/16, 256, 0, stream>>>(xg, Wh2f, Wx2f, g2bih, g2bhh, out);
}